// Round 1
// baseline (608.586 us; speedup 1.0000x reference)
//
#include <hip/hip_runtime.h>
#include <math.h>

#define TARLEN 263680
#define POWEXP 2.302585092994046f  // ln(10)

__device__ __forceinline__ float norm_lrelu(float a, float m, float rs, float g, float b) {
    float x = (a - m) * rs * g + b;
    return x >= 0.f ? x : 0.2f * x;
}

// ---------------- GEMM: C = f(A) @ B + bias, optional BN+LeakyReLU on A-load,
// optional mod_sigmoid epilogue. Tile 128x64, 256 threads, 8x4 per thread. ----
template<bool NORM, bool SIG>
__global__ __launch_bounds__(256) void gemm_k(
    const float* __restrict__ A, const float* __restrict__ B,
    const float* __restrict__ bias,
    const float* __restrict__ mean, const float* __restrict__ rstd,
    const float* __restrict__ gamma, const float* __restrict__ beta,
    float* __restrict__ C, int M, int N, int K)
{
    __shared__ float As[16][132];
    __shared__ float Bs[16][68];
    const int tid = threadIdx.x;
    const int n0 = blockIdx.x * 64;
    const int m0 = blockIdx.y * 128;
    const int tn = tid & 15, tm = tid >> 4;
    const int lr = tid >> 2;          // 0..63 (A rows)
    const int lk = (tid & 3) * 4;     // 0,4,8,12 (A k-offset)
    const int lkb = tid >> 4;         // 0..15 (B k-row)
    const int lnb = (tid & 15) * 4;   // 0..60 (B n-offset)
    const bool nvec = ((N & 3) == 0);

    float acc[8][4];
#pragma unroll
    for (int i = 0; i < 8; ++i)
#pragma unroll
        for (int j = 0; j < 4; ++j) acc[i][j] = 0.f;

    for (int k0 = 0; k0 < K; k0 += 16) {
#pragma unroll
        for (int h = 0; h < 2; ++h) {
            int row = m0 + lr + h * 64;
            float4 a = *reinterpret_cast<const float4*>(&A[(size_t)row * K + k0 + lk]);
            if (NORM) {
                float4 mm = *reinterpret_cast<const float4*>(&mean[k0 + lk]);
                float4 rs = *reinterpret_cast<const float4*>(&rstd[k0 + lk]);
                float4 gg = *reinterpret_cast<const float4*>(&gamma[k0 + lk]);
                float4 bb = *reinterpret_cast<const float4*>(&beta[k0 + lk]);
                a.x = norm_lrelu(a.x, mm.x, rs.x, gg.x, bb.x);
                a.y = norm_lrelu(a.y, mm.y, rs.y, gg.y, bb.y);
                a.z = norm_lrelu(a.z, mm.z, rs.z, gg.z, bb.z);
                a.w = norm_lrelu(a.w, mm.w, rs.w, gg.w, bb.w);
            }
            As[lk + 0][lr + h * 64] = a.x;
            As[lk + 1][lr + h * 64] = a.y;
            As[lk + 2][lr + h * 64] = a.z;
            As[lk + 3][lr + h * 64] = a.w;
        }
        {
            int krow = k0 + lkb;
            if (nvec) {
                float4 b = *reinterpret_cast<const float4*>(&B[(size_t)krow * N + n0 + lnb]);
                Bs[lkb][lnb + 0] = b.x;
                Bs[lkb][lnb + 1] = b.y;
                Bs[lkb][lnb + 2] = b.z;
                Bs[lkb][lnb + 3] = b.w;
            } else {
#pragma unroll
                for (int e = 0; e < 4; ++e) {
                    int n = n0 + lnb + e;
                    Bs[lkb][lnb + e] = (n < N) ? B[(size_t)krow * N + n] : 0.f;
                }
            }
        }
        __syncthreads();
#pragma unroll
        for (int kk = 0; kk < 16; ++kk) {
            float4 b4 = *reinterpret_cast<const float4*>(&Bs[kk][tn * 4]);
            float4 a0 = *reinterpret_cast<const float4*>(&As[kk][tm * 8]);
            float4 a1 = *reinterpret_cast<const float4*>(&As[kk][tm * 8 + 4]);
            float av[8] = {a0.x, a0.y, a0.z, a0.w, a1.x, a1.y, a1.z, a1.w};
            float bv[4] = {b4.x, b4.y, b4.z, b4.w};
#pragma unroll
            for (int i = 0; i < 8; ++i)
#pragma unroll
                for (int j = 0; j < 4; ++j)
                    acc[i][j] = fmaf(av[i], bv[j], acc[i][j]);
        }
        __syncthreads();
    }
#pragma unroll
    for (int i = 0; i < 8; ++i) {
        int row = m0 + tm * 8 + i;
#pragma unroll
        for (int j = 0; j < 4; ++j) {
            int n = n0 + tn * 4 + j;
            if (n < N) {
                float v = acc[i][j] + bias[n];
                if (SIG) {
                    float sg = 1.f / (1.f + __expf(-v));
                    v = 2.f * __expf(POWEXP * __logf(sg)) + 1e-7f;  // 2*sigmoid^ln(10)+1e-7
                }
                C[(size_t)row * N + n] = v;
            }
        }
    }
}

// ---------------- BatchNorm column stats (two-stage deterministic reduce) ----
__global__ __launch_bounds__(256) void colstats_partial(
    const float* __restrict__ H, float* __restrict__ ps, float* __restrict__ pq)
{
    // grid (8 colgroups, 32 rowgroups); block 256 = 4 rows x 64 cols
    int cg = blockIdx.x, rg = blockIdx.y;
    int c = threadIdx.x & 63;
    int rr = threadIdx.x >> 6;
    int col = cg * 64 + c;
    float s = 0.f, q = 0.f;
    size_t base = (size_t)(rg * 256 + rr) * 512 + col;
#pragma unroll 4
    for (int it = 0; it < 64; ++it) {
        float v = H[base + (size_t)it * 4 * 512];
        s += v; q += v * v;
    }
    __shared__ float ls[256], lq[256];
    ls[threadIdx.x] = s; lq[threadIdx.x] = q;
    __syncthreads();
    if (threadIdx.x < 64) {
        s = ls[c] + ls[c + 64] + ls[c + 128] + ls[c + 192];
        q = lq[c] + lq[c + 64] + lq[c + 128] + lq[c + 192];
        ps[rg * 512 + col] = s;
        pq[rg * 512 + col] = q;
    }
}

__global__ __launch_bounds__(256) void colstats_final(
    const float* __restrict__ ps, const float* __restrict__ pq,
    float* __restrict__ mean, float* __restrict__ rstd)
{
    int c = blockIdx.x * 256 + threadIdx.x;  // 512 columns
    float s = 0.f, q = 0.f;
    for (int rg = 0; rg < 32; ++rg) { s += ps[rg * 512 + c]; q += pq[rg * 512 + c]; }
    float m = s * (1.f / 8192.f);
    float v = q * (1.f / 8192.f) - m * m;  // biased var (train-mode BN)
    mean[c] = m;
    rstd[c] = rsqrtf(v + 1e-5f);
}

// ---------------- FFT filter kernel: one row (grain) per block. -------------
// audio = irfft( rfft(noise_row) * H ), H[k] = (-1)^k*(0.5 fc[k]+0.25 fc[k-1]+0.25 fc[k+1])
// (analytic collapse of rfft(fftshift(irfft(fc)*FW))). Then apply OLA window.
__device__ __forceinline__ void fft1024_lds(
    float* Ar, float* Ai, const float* Tr, const float* Ti, int tid, bool inverse)
{
    // bit-reversal permute (10 bits)
    for (int i = tid; i < 1024; i += 256) {
        int j = __brev((unsigned)i) >> 22;
        if (j > i) {
            float tr = Ar[i]; Ar[i] = Ar[j]; Ar[j] = tr;
            float t2 = Ai[i]; Ai[i] = Ai[j]; Ai[j] = t2;
        }
    }
    __syncthreads();
    for (int s = 0; s < 10; ++s) {
        int half = 1 << s;
        for (int t = tid; t < 512; t += 256) {
            int j = t & (half - 1);
            int i0 = ((t >> s) << (s + 1)) + j;
            int i1 = i0 + half;
            int tix = j << (9 - s);
            float wr = Tr[tix];
            float wi = inverse ? -Ti[tix] : Ti[tix];
            float xr = Ar[i1], xi = Ai[i1];
            float tr = xr * wr - xi * wi;
            float t2 = xr * wi + xi * wr;
            float ur = Ar[i0], ui = Ai[i0];
            Ar[i1] = ur - tr; Ai[i1] = ui - t2;
            Ar[i0] = ur + tr; Ai[i0] = ui + t2;
        }
        __syncthreads();
    }
}

__global__ __launch_bounds__(256) void fft_filter_kernel(
    const float* __restrict__ noise, const float* __restrict__ fcs, float* __restrict__ aw)
{
    __shared__ float Ar[1024], Ai[1024], F[1025], Tr[512], Ti[512];
    const int tid = threadIdx.x;
    const int r = blockIdx.x;

    const float2* nrow = reinterpret_cast<const float2*>(noise + ((size_t)r << 11));
    for (int i = tid; i < 1024; i += 256) {
        float2 v = nrow[i];
        Ar[i] = v.x; Ai[i] = v.y;  // pack: z[n] = x[2n] + i x[2n+1]
    }
    for (int i = tid; i < 1025; i += 256) F[i] = fcs[(size_t)r * 1025 + i];
    for (int t = tid; t < 512; t += 256) {
        float s, c;
        __sincosf((float)(-M_PI / 512.0) * t, &s, &c);  // e^{-2pi i t/1024}
        Tr[t] = c; Ti[t] = s;
    }
    __syncthreads();

    fft1024_lds(Ar, Ai, Tr, Ti, tid, false);  // forward

    // unpack real-FFT, multiply by H, repack for inverse real-FFT (pairs closed)
    for (int k = tid; k < 513; k += 256) {
        int k2 = (1024 - k) & 1023;
        float zar = Ar[k], zai = Ai[k];
        float zbr = Ar[k2], zbi = Ai[k2];
        float Fer = 0.5f * (zar + zbr), Fei = 0.5f * (zai - zbi);
        float For = 0.5f * (zai + zbi), Foi = 0.5f * (zbr - zar);
        float s, c;
        __sincosf((float)(-M_PI / 1024.0) * k, &s, &c);  // w = e^{-i pi k/1024} = (c, s)
        float wFr = c * For - s * Foi;
        float wFi = c * Foi + s * For;
        float Xr = Fer + wFr, Xi = Fei + wFi;        // X[k]
        float Xbr = Fer - wFr, Xbi = wFi - Fei;      // X[1024-k] = conj(Fe - w Fo)
        // H values
        float Hk, Hb;
        {
            float cl = (k == 0) ? F[1] : F[k - 1];
            float cr = (k == 1024) ? F[1023] : F[k + 1];
            float h = 0.5f * F[k] + 0.25f * (cl + cr);
            Hk = (k & 1) ? -h : h;
        }
        {
            int kb = 1024 - k;
            float cl = (kb == 0) ? F[1] : F[kb - 1];
            float cr = (kb == 1024) ? F[1023] : F[kb + 1];
            float h = 0.5f * F[kb] + 0.25f * (cl + cr);
            Hb = (kb & 1) ? -h : h;
        }
        float Yr = Hk * Xr, Yi = Hk * Xi;
        float Ybr = Hb * Xbr, Ybi = Hb * Xbi;
        if (k == 0) {
            // Z'[0] = ((Y0 + Y1024)/2, (Y0 - Y1024)/2); both Y real here
            Ar[0] = 0.5f * (Yr + Ybr);
            Ai[0] = 0.5f * (Yr - Ybr);
        } else {
            float Ger = 0.5f * (Yr + Ybr), Gei = 0.5f * (Yi - Ybi);
            float Sgr = 0.5f * (Yr - Ybr), Sgi = 0.5f * (Yi + Ybi);
            float wpr = c, wpi = -s;  // e^{+i pi k/1024}
            float Gor = wpr * Sgr - wpi * Sgi;
            float Goi = wpr * Sgi + wpi * Sgr;
            Ar[k] = Ger - Goi; Ai[k] = Gei + Gor;       // Z'[k]
            Ar[k2] = Ger + Goi; Ai[k2] = Gor - Gei;     // Z'[1024-k]
        }
    }
    __syncthreads();

    fft1024_lds(Ar, Ai, Tr, Ti, tid, true);  // inverse (scale 1/1024 in epilogue)

    // epilogue: y[2i]=Ar[i]/1024, y[2i+1]=Ai[i]/1024; apply OLA window; store
    const int g = r & 511;
    const float inv = 1.0f / 1024.0f;
    float2* awrow = reinterpret_cast<float2*>(aw + ((size_t)r << 11));
    for (int i = tid; i < 1024; i += 256) {
        float y0 = Ar[i] * inv, y1 = Ai[i] * inv;
        int n0 = 2 * i, n1 = n0 + 1;
        float w0 = 0.5f - 0.5f * __cosf((float)(M_PI / 1024.0) * n0);
        float w1 = 0.5f - 0.5f * __cosf((float)(M_PI / 1024.0) * n1);
        if (g == 0) { if (n0 < 1024) w0 = 1.f; if (n1 < 1024) w1 = 1.f; }
        if (g == 511) { if (n0 >= 1024) w0 = 1.f; if (n1 >= 1024) w1 = 1.f; }
        float2 o; o.x = y0 * w0; o.y = y1 * w1;
        awrow[i] = o;
    }
}

// ---------------- OLA gather (deterministic; divisor in closed form) --------
__global__ __launch_bounds__(256) void ola_kernel(
    const float* __restrict__ aw, float* __restrict__ asum)
{
    int t = blockIdx.x * 256 + threadIdx.x;  // 0..263679
    int b = blockIdx.y;
    int g_hi = min(511, t >> 9);
    int g_lo = max(0, (t - 1536) >> 9);  // ceil((t-2047)/512), arithmetic shift = floor
    float s = 0.f;
    for (int g = g_lo; g <= g_hi; ++g) {
        int n = t - (g << 9);
        s += aw[((size_t)(b * 512 + g) << 11) + n];
    }
    asum[(size_t)b * TARLEN + t] = s / (float)(g_hi - g_lo + 1);
}

// ---------------- 65-tap conv (channels collapse to one kernel) + softsign --
__global__ __launch_bounds__(256) void ppconv_kernel(
    const float* __restrict__ asum, const float* __restrict__ ppw,
    const float* __restrict__ ppb, float* __restrict__ out)
{
    __shared__ float tile[320];
    __shared__ float Ksh[65];
    int t0 = blockIdx.x * 256;
    int b = blockIdx.y;
    const float* arow = asum + (size_t)b * TARLEN;
    for (int i = threadIdx.x; i < 320; i += 256) {
        int tt = t0 - 32 + i;
        tile[i] = (tt >= 0 && tt < TARLEN) ? arow[tt] : 0.f;
    }
    if (threadIdx.x < 65) {
        float k = 0.f;
#pragma unroll
        for (int c = 0; c < 5; ++c) k += ppw[c * 65 + threadIdx.x];
        Ksh[threadIdx.x] = k;
    }
    __syncthreads();
    float y = ppb[0];
#pragma unroll
    for (int j = 0; j < 65; ++j) y = fmaf(Ksh[j], tile[threadIdx.x + j], y);
    int t = t0 + threadIdx.x;
    out[(size_t)b * TARLEN + t] = y / (1.f + fabsf(y));
}

// ---------------- launch --------------------------------------------------
extern "C" void kernel_launch(void* const* d_in, const int* in_sizes, int n_in,
                              void* d_out, int out_size, void* d_ws, size_t ws_size,
                              hipStream_t stream) {
    const float* z    = (const float*)d_in[0];
    const float* w0   = (const float*)d_in[1];
    const float* b0   = (const float*)d_in[2];
    const float* g0   = (const float*)d_in[3];
    const float* be0  = (const float*)d_in[4];
    const float* w1   = (const float*)d_in[5];
    const float* b1   = (const float*)d_in[6];
    const float* g1   = (const float*)d_in[7];
    const float* be1  = (const float*)d_in[8];
    const float* w2   = (const float*)d_in[9];
    const float* b2   = (const float*)d_in[10];
    const float* g2   = (const float*)d_in[11];
    const float* be2  = (const float*)d_in[12];
    const float* w3   = (const float*)d_in[13];
    const float* b3   = (const float*)d_in[14];
    const float* ppw  = (const float*)d_in[15];
    const float* ppb  = (const float*)d_in[16];
    const float* noise= (const float*)d_in[17];
    float* out = (float*)d_out;
    float* ws = (float*)d_ws;

    // workspace layout (floats); total 33,628,160 floats = 128.3 MiB
    float* h0   = ws;                    // 8192*512
    float* h1   = ws + 4194304;          // 8192*512
    float* ps   = ws + 8388608;          // 32*512
    float* pq   = ps + 16384;            // 32*512
    float* mean = pq + 16384;            // 512
    float* rstd = mean + 512;            // 512
    float* fcs  = ws + 8454144;          // 8192*1025
    float* aw   = ws + 16850944;         // 8192*2048
    float* h2   = h0;                    // reuse (h0 dead after GEMM1)
    float* asum = h0;                    // reuse (h0/h1 dead after GEMM3)

    dim3 blk(256);
    // layer 0: h0 = z @ w0 + b0
    gemm_k<false, false><<<dim3(8, 64), blk, 0, stream>>>(
        z, w0, b0, nullptr, nullptr, nullptr, nullptr, h0, 8192, 512, 128);
    colstats_partial<<<dim3(8, 32), blk, 0, stream>>>(h0, ps, pq);
    colstats_final<<<dim3(2), blk, 0, stream>>>(ps, pq, mean, rstd);
    // layer 1: h1 = BNLRelu(h0) @ w1 + b1
    gemm_k<true, false><<<dim3(8, 64), blk, 0, stream>>>(
        h0, w1, b1, mean, rstd, g0, be0, h1, 8192, 512, 512);
    colstats_partial<<<dim3(8, 32), blk, 0, stream>>>(h1, ps, pq);
    colstats_final<<<dim3(2), blk, 0, stream>>>(ps, pq, mean, rstd);
    // layer 2: h2 = BNLRelu(h1) @ w2 + b2
    gemm_k<true, false><<<dim3(8, 64), blk, 0, stream>>>(
        h1, w2, b2, mean, rstd, g1, be1, h2, 8192, 512, 512);
    colstats_partial<<<dim3(8, 32), blk, 0, stream>>>(h2, ps, pq);
    colstats_final<<<dim3(2), blk, 0, stream>>>(ps, pq, mean, rstd);
    // final: fcs = mod_sigmoid(BNLRelu(h2) @ w3 + b3)
    gemm_k<true, true><<<dim3(17, 64), blk, 0, stream>>>(
        h2, w3, b3, mean, rstd, g2, be2, fcs, 8192, 1025, 512);
    // spectral filtering + OLA window
    fft_filter_kernel<<<dim3(8192), blk, 0, stream>>>(noise, fcs, aw);
    // overlap-add + normalize
    ola_kernel<<<dim3(1030, 16), blk, 0, stream>>>(aw, asum);
    // post conv + softsign
    ppconv_kernel<<<dim3(1030, 16), blk, 0, stream>>>(asum, ppw, ppb, out);
    (void)in_sizes; (void)n_in; (void)out_size; (void)ws_size;
}

// Round 2
// 358.273 us; speedup vs baseline: 1.6987x; 1.6987x over previous
//
#include <hip/hip_runtime.h>
#include <hip/hip_bf16.h>
#include <math.h>

#define TARLEN 263680
#define POWEXP 2.302585092994046f  // ln(10)
#define P(i) ((i) + ((i) >> 5))    // LDS anti-bank-conflict padding

typedef __attribute__((ext_vector_type(8))) short bf16x8;
typedef __attribute__((ext_vector_type(4))) float f32x4;

__device__ __forceinline__ void gload16(const void* g, void* l) {
    __builtin_amdgcn_global_load_lds((const __attribute__((address_space(1))) void*)g,
                                     (__attribute__((address_space(3))) void*)l, 16, 0, 0);
}

__device__ __forceinline__ float norm_lrelu(float a, float m, float rs, float g, float b) {
    float x = (a - m) * rs * g + b;
    return x >= 0.f ? x : 0.2f * x;
}

__device__ __forceinline__ void split_bf16(float x, ushort& hi, ushort& lo) {
    __hip_bfloat16 h = __float2bfloat16(x);
    hi = *reinterpret_cast<ushort*>(&h);
    float rem = x - __bfloat162float(h);
    __hip_bfloat16 l = __float2bfloat16(rem);
    lo = *reinterpret_cast<ushort*>(&l);
}

// ---------------- split-bf16 MFMA GEMM ------------------------------------
// C = A @ B (+bias, optional mod_sigmoid). A2 = [Ahi | Alo] ([M][2K] bf16),
// B3t = [N][3K] bf16 rows = [Bhi Bhi Blo]. K' = 3K loop: A col map k'<2K -> k',
// else k'-2K, giving Ahi*Bhi + Alo*Bhi + Ahi*Blo. Tile 128x64, 4 waves of
// 64x32, BK=32, double-buffered global_load_lds(16B).
template<int EPI>
__global__ __launch_bounds__(256) void mfma_gemm(
    const ushort* __restrict__ A2, const ushort* __restrict__ B3t,
    const float* __restrict__ bias, float* __restrict__ C,
    int K3, int K2, int Nvalid, int ldc)
{
    __shared__ ushort As[2][4096];  // [128][32]
    __shared__ ushort Bs[2][2048];  // [64][32]
    const int tid = threadIdx.x;
    const int lane = tid & 63;
    const int wid = tid >> 6;
    const int m0 = blockIdx.y * 128;
    const int n0 = blockIdx.x * 64;
    const int NT = K3 >> 5;

    f32x4 acc[4][2];
#pragma unroll
    for (int m = 0; m < 4; ++m)
#pragma unroll
        for (int n = 0; n < 2; ++n)
            acc[m][n] = (f32x4){0.f, 0.f, 0.f, 0.f};

    auto stage = [&](int t, int buf) {
        const int k0 = t << 5;
        const int ka = (k0 < K2) ? k0 : (k0 - K2);
#pragma unroll
        for (int i = 0; i < 2; ++i) {
            int c = wid * 2 + i;
            int g = c * 64 + lane;
            int row = g >> 2, col = (g & 3) << 3;
            gload16(A2 + (size_t)(m0 + row) * K2 + ka + col, &As[buf][c * 512]);
        }
        {
            int g = wid * 64 + lane;
            int row = g >> 2, col = (g & 3) << 3;
            gload16(B3t + (size_t)(n0 + row) * K3 + k0 + col, &Bs[buf][wid * 512]);
        }
    };

    const int lr = lane & 15;
    const int lk = (lane >> 4) << 3;
    const int wm0 = (wid >> 1) * 64;
    const int wn0 = (wid & 1) * 32;

    stage(0, 0);
    __syncthreads();
    for (int t = 0; t < NT; ++t) {
        int cur = t & 1;
        if (t + 1 < NT) stage(t + 1, cur ^ 1);
        const ushort* as = As[cur];
        const ushort* bs = Bs[cur];
        bf16x8 af[4], bfv[2];
#pragma unroll
        for (int m = 0; m < 4; ++m)
            af[m] = *reinterpret_cast<const bf16x8*>(&as[(wm0 + m * 16 + lr) * 32 + lk]);
#pragma unroll
        for (int n = 0; n < 2; ++n)
            bfv[n] = *reinterpret_cast<const bf16x8*>(&bs[(wn0 + n * 16 + lr) * 32 + lk]);
#pragma unroll
        for (int m = 0; m < 4; ++m)
#pragma unroll
            for (int n = 0; n < 2; ++n)
                acc[m][n] = __builtin_amdgcn_mfma_f32_16x16x32_bf16(af[m], bfv[n], acc[m][n], 0, 0, 0);
        __syncthreads();
    }

    // epilogue: C/D layout col=lane&15, row=(lane>>4)*4+reg
    const int cr = (lane >> 4) << 2;
    const int cc = lane & 15;
#pragma unroll
    for (int m = 0; m < 4; ++m) {
#pragma unroll
        for (int n = 0; n < 2; ++n) {
            int gcol = n0 + wn0 + n * 16 + cc;
            if (gcol < Nvalid) {
                float bv = bias[gcol];
                int grow = m0 + wm0 + m * 16 + cr;
#pragma unroll
                for (int j = 0; j < 4; ++j) {
                    float v = acc[m][n][j] + bv;
                    if (EPI == 1) {
                        float sg = 1.f / (1.f + __expf(-v));
                        v = 2.f * __expf(POWEXP * __logf(sg)) + 1e-7f;
                    }
                    C[(size_t)(grow + j) * ldc + gcol] = v;
                }
            }
        }
    }
}

// ---------------- prep: activations -> BN+LeakyReLU -> hi/lo bf16 ---------
template<int KSH, bool NORM>
__global__ __launch_bounds__(256) void prep_act_k(
    const float* __restrict__ H, const float* __restrict__ mean,
    const float* __restrict__ rstd, const float* __restrict__ gamma,
    const float* __restrict__ beta, ushort* __restrict__ A2)
{
    const int K = 1 << KSH;
    int idx = (blockIdx.x * 256 + threadIdx.x) << 2;
    int col = idx & (K - 1);
    int row = idx >> KSH;
    float4 h = *reinterpret_cast<const float4*>(&H[idx]);
    float x[4] = {h.x, h.y, h.z, h.w};
    if (NORM) {
        float4 mm = *reinterpret_cast<const float4*>(&mean[col]);
        float4 rs = *reinterpret_cast<const float4*>(&rstd[col]);
        float4 gg = *reinterpret_cast<const float4*>(&gamma[col]);
        float4 bb = *reinterpret_cast<const float4*>(&beta[col]);
        x[0] = norm_lrelu(x[0], mm.x, rs.x, gg.x, bb.x);
        x[1] = norm_lrelu(x[1], mm.y, rs.y, gg.y, bb.y);
        x[2] = norm_lrelu(x[2], mm.z, rs.z, gg.z, bb.z);
        x[3] = norm_lrelu(x[3], mm.w, rs.w, gg.w, bb.w);
    }
    ushort4 hv, lv;
    split_bf16(x[0], hv.x, lv.x);
    split_bf16(x[1], hv.y, lv.y);
    split_bf16(x[2], hv.z, lv.z);
    split_bf16(x[3], hv.w, lv.w);
    ushort* dst = &A2[(size_t)row * (2 * K) + col];
    *reinterpret_cast<ushort4*>(dst) = hv;
    *reinterpret_cast<ushort4*>(dst + K) = lv;
}

// ---------------- prep: weights -> transpose + hi/lo split ----------------
// w [K][N] row-major -> B3t [Npad][3K]: row n = [hi(w[:,n]) hi(w[:,n]) lo(w[:,n])]
__global__ __launch_bounds__(256) void prepw_k(
    const float* __restrict__ w, ushort* __restrict__ B3t, int K, int N, int K3)
{
    __shared__ float tile[32][33];
    int k0 = blockIdx.x * 32, n0 = blockIdx.y * 32;
    int tx = threadIdx.x & 31, ty = threadIdx.x >> 5;  // 32 x 8
#pragma unroll
    for (int r = 0; r < 4; ++r) {
        int k = k0 + ty + r * 8;
        int n = n0 + tx;
        tile[ty + r * 8][tx] = (n < N) ? w[(size_t)k * N + n] : 0.f;
    }
    __syncthreads();
#pragma unroll
    for (int r = 0; r < 4; ++r) {
        int n = n0 + ty + r * 8;
        int k = k0 + tx;
        float x = tile[tx][ty + r * 8];
        ushort hi, lo;
        split_bf16(x, hi, lo);
        size_t base = (size_t)n * K3;
        B3t[base + k] = hi;
        B3t[base + K + k] = hi;
        B3t[base + 2 * K + k] = lo;
    }
}

// ---------------- BatchNorm column stats (two-stage deterministic) --------
__global__ __launch_bounds__(256) void colstats_partial(
    const float* __restrict__ H, float* __restrict__ ps, float* __restrict__ pq)
{
    int cg = blockIdx.x, rg = blockIdx.y;
    int c = threadIdx.x & 63;
    int rr = threadIdx.x >> 6;
    int col = cg * 64 + c;
    float s = 0.f, q = 0.f;
    size_t base = (size_t)(rg * 256 + rr) * 512 + col;
#pragma unroll 4
    for (int it = 0; it < 64; ++it) {
        float v = H[base + (size_t)it * 4 * 512];
        s += v; q += v * v;
    }
    __shared__ float ls[256], lq[256];
    ls[threadIdx.x] = s; lq[threadIdx.x] = q;
    __syncthreads();
    if (threadIdx.x < 64) {
        s = ls[c] + ls[c + 64] + ls[c + 128] + ls[c + 192];
        q = lq[c] + lq[c + 64] + lq[c + 128] + lq[c + 192];
        ps[rg * 512 + col] = s;
        pq[rg * 512 + col] = q;
    }
}

__global__ __launch_bounds__(256) void colstats_final(
    const float* __restrict__ ps, const float* __restrict__ pq,
    float* __restrict__ mean, float* __restrict__ rstd)
{
    int c = blockIdx.x * 256 + threadIdx.x;
    float s = 0.f, q = 0.f;
    for (int rg = 0; rg < 32; ++rg) { s += ps[rg * 512 + c]; q += pq[rg * 512 + c]; }
    float m = s * (1.f / 8192.f);
    float v = q * (1.f / 8192.f) - m * m;
    mean[c] = m;
    rstd[c] = rsqrtf(v + 1e-5f);
}

// ---------------- FFT filter kernel (LDS-padded indices) ------------------
__device__ __forceinline__ void fft1024_lds(
    float* Ar, float* Ai, const float* Tr, const float* Ti, int tid, bool inverse)
{
    for (int i = tid; i < 1024; i += 256) {
        int j = __brev((unsigned)i) >> 22;
        if (j > i) {
            float tr = Ar[P(i)]; Ar[P(i)] = Ar[P(j)]; Ar[P(j)] = tr;
            float t2 = Ai[P(i)]; Ai[P(i)] = Ai[P(j)]; Ai[P(j)] = t2;
        }
    }
    __syncthreads();
    for (int s = 0; s < 10; ++s) {
        int half = 1 << s;
        for (int t = tid; t < 512; t += 256) {
            int j = t & (half - 1);
            int i0 = ((t >> s) << (s + 1)) + j;
            int i1 = i0 + half;
            int tix = j << (9 - s);
            float wr = Tr[P(tix)];
            float wi = inverse ? -Ti[P(tix)] : Ti[P(tix)];
            float xr = Ar[P(i1)], xi = Ai[P(i1)];
            float tr = xr * wr - xi * wi;
            float t2 = xr * wi + xi * wr;
            float ur = Ar[P(i0)], ui = Ai[P(i0)];
            Ar[P(i1)] = ur - tr; Ai[P(i1)] = ui - t2;
            Ar[P(i0)] = ur + tr; Ai[P(i0)] = ui + t2;
        }
        __syncthreads();
    }
}

__global__ __launch_bounds__(256) void fft_filter_kernel(
    const float* __restrict__ noise, const float* __restrict__ fcs, float* __restrict__ aw)
{
    __shared__ float Ar[1056], Ai[1056], F[1025], Tr[528], Ti[528];
    const int tid = threadIdx.x;
    const int r = blockIdx.x;

    const float2* nrow = reinterpret_cast<const float2*>(noise + ((size_t)r << 11));
    for (int i = tid; i < 1024; i += 256) {
        float2 v = nrow[i];
        Ar[P(i)] = v.x; Ai[P(i)] = v.y;  // pack z[n] = x[2n] + i x[2n+1]
    }
    for (int i = tid; i < 1025; i += 256) F[i] = fcs[(size_t)r * 1040 + i];
    for (int t = tid; t < 512; t += 256) {
        float s, c;
        __sincosf((float)(-M_PI / 512.0) * t, &s, &c);
        Tr[P(t)] = c; Ti[P(t)] = s;
    }
    __syncthreads();

    fft1024_lds(Ar, Ai, Tr, Ti, tid, false);

    // unpack real FFT, apply H[k] = (-1)^k*(0.5 fc[k]+0.25 fc[k-1]+0.25 fc[k+1]), repack
    for (int k = tid; k < 513; k += 256) {
        int k2 = (1024 - k) & 1023;
        float zar = Ar[P(k)], zai = Ai[P(k)];
        float zbr = Ar[P(k2)], zbi = Ai[P(k2)];
        float Fer = 0.5f * (zar + zbr), Fei = 0.5f * (zai - zbi);
        float For = 0.5f * (zai + zbi), Foi = 0.5f * (zbr - zar);
        float s, c;
        __sincosf((float)(-M_PI / 1024.0) * k, &s, &c);
        float wFr = c * For - s * Foi;
        float wFi = c * Foi + s * For;
        float Xr = Fer + wFr, Xi = Fei + wFi;
        float Xbr = Fer - wFr, Xbi = wFi - Fei;
        float Hk, Hb;
        {
            float cl = (k == 0) ? F[1] : F[k - 1];
            float crr = (k == 1024) ? F[1023] : F[k + 1];
            float h = 0.5f * F[k] + 0.25f * (cl + crr);
            Hk = (k & 1) ? -h : h;
        }
        {
            int kb = 1024 - k;
            float cl = (kb == 0) ? F[1] : F[kb - 1];
            float crr = (kb == 1024) ? F[1023] : F[kb + 1];
            float h = 0.5f * F[kb] + 0.25f * (cl + crr);
            Hb = (kb & 1) ? -h : h;
        }
        float Yr = Hk * Xr, Yi = Hk * Xi;
        float Ybr = Hb * Xbr, Ybi = Hb * Xbi;
        if (k == 0) {
            Ar[P(0)] = 0.5f * (Yr + Ybr);
            Ai[P(0)] = 0.5f * (Yr - Ybr);
        } else {
            float Ger = 0.5f * (Yr + Ybr), Gei = 0.5f * (Yi - Ybi);
            float Sgr = 0.5f * (Yr - Ybr), Sgi = 0.5f * (Yi + Ybi);
            float wpr = c, wpi = -s;
            float Gor = wpr * Sgr - wpi * Sgi;
            float Goi = wpr * Sgi + wpi * Sgr;
            Ar[P(k)] = Ger - Goi; Ai[P(k)] = Gei + Gor;
            Ar[P(k2)] = Ger + Goi; Ai[P(k2)] = Gor - Gei;
        }
    }
    __syncthreads();

    fft1024_lds(Ar, Ai, Tr, Ti, tid, true);

    const int g = r & 511;
    const float inv = 1.0f / 1024.0f;
    float2* awrow = reinterpret_cast<float2*>(aw + ((size_t)r << 11));
    for (int i = tid; i < 1024; i += 256) {
        float y0 = Ar[P(i)] * inv, y1 = Ai[P(i)] * inv;
        int n0 = 2 * i, n1 = n0 + 1;
        float w0 = 0.5f - 0.5f * __cosf((float)(M_PI / 1024.0) * n0);
        float w1 = 0.5f - 0.5f * __cosf((float)(M_PI / 1024.0) * n1);
        if (g == 0) { if (n0 < 1024) w0 = 1.f; if (n1 < 1024) w1 = 1.f; }
        if (g == 511) { if (n0 >= 1024) w0 = 1.f; if (n1 >= 1024) w1 = 1.f; }
        float2 o; o.x = y0 * w0; o.y = y1 * w1;
        awrow[i] = o;
    }
}

// ---------------- fused OLA gather + 65-tap conv + softsign ---------------
__global__ __launch_bounds__(256) void ola_ppconv_kernel(
    const float* __restrict__ aw, const float* __restrict__ ppw,
    const float* __restrict__ ppb, float* __restrict__ out)
{
    __shared__ float tile[320];
    __shared__ float Ksh[65];
    int t0 = blockIdx.x * 256;
    int b = blockIdx.y;
    for (int i = threadIdx.x; i < 320; i += 256) {
        int tt = t0 - 32 + i;
        float v = 0.f;
        if (tt >= 0 && tt < TARLEN) {
            int ghi = min(511, tt >> 9);
            int glo = max(0, (tt - 1536) >> 9);
            float s = 0.f;
            for (int g = glo; g <= ghi; ++g) {
                int n = tt - (g << 9);
                s += aw[((size_t)(b * 512 + g) << 11) + n];
            }
            v = s / (float)(ghi - glo + 1);
        }
        tile[i] = v;
    }
    if (threadIdx.x < 65) {
        float k = 0.f;
#pragma unroll
        for (int c = 0; c < 5; ++c) k += ppw[c * 65 + threadIdx.x];
        Ksh[threadIdx.x] = k;
    }
    __syncthreads();
    float y = ppb[0];
#pragma unroll
    for (int j = 0; j < 65; ++j) y = fmaf(Ksh[j], tile[threadIdx.x + j], y);
    int t = t0 + threadIdx.x;
    out[(size_t)b * TARLEN + t] = y / (1.f + fabsf(y));
}

// ---------------- launch --------------------------------------------------
extern "C" void kernel_launch(void* const* d_in, const int* in_sizes, int n_in,
                              void* d_out, int out_size, void* d_ws, size_t ws_size,
                              hipStream_t stream) {
    const float* z    = (const float*)d_in[0];
    const float* w0   = (const float*)d_in[1];
    const float* b0   = (const float*)d_in[2];
    const float* g0   = (const float*)d_in[3];
    const float* be0  = (const float*)d_in[4];
    const float* w1   = (const float*)d_in[5];
    const float* b1   = (const float*)d_in[6];
    const float* g1   = (const float*)d_in[7];
    const float* be1  = (const float*)d_in[8];
    const float* w2   = (const float*)d_in[9];
    const float* b2   = (const float*)d_in[10];
    const float* g2   = (const float*)d_in[11];
    const float* be2  = (const float*)d_in[12];
    const float* w3   = (const float*)d_in[13];
    const float* b3   = (const float*)d_in[14];
    const float* ppw  = (const float*)d_in[15];
    const float* ppb  = (const float*)d_in[16];
    const float* noise= (const float*)d_in[17];
    float* out = (float*)d_out;
    float* ws = (float*)d_ws;

    // workspace (floats), total 30,409,728 = 121.7 MiB
    float* h0   = ws;                  // 8192*512
    float* ps   = ws + 4194304;        // 32*512
    float* pq   = ps + 16384;          // 32*512
    float* mean = pq + 16384;          // 512
    float* rstd = mean + 512;          // 512
    float* B3tf = rstd + 512;          // 1152*1536 bf16 = 884736 f
    float* fcs  = B3tf + 884736;       // 8192*1040 f (h1 aliases start)
    float* awf  = fcs + 8519680;       // 8192*2048 f (A2 aliases start)
    ushort* B3t = (ushort*)B3tf;
    ushort* A2  = (ushort*)awf;
    float* h1 = fcs;   // dead before fcs written
    float* h2 = h0;    // h0 dead after its prep
    float* aw = awf;   // A2 dead before fft writes

    dim3 blk(256);
    // layer 0: h0 = z @ w0 + b0
    prep_act_k<7, false><<<dim3(1024), blk, 0, stream>>>(z, nullptr, nullptr, nullptr, nullptr, A2);
    prepw_k<<<dim3(4, 16), blk, 0, stream>>>(w0, B3t, 128, 512, 384);
    mfma_gemm<0><<<dim3(8, 64), blk, 0, stream>>>(A2, B3t, b0, h0, 384, 256, 512, 512);
    colstats_partial<<<dim3(8, 32), blk, 0, stream>>>(h0, ps, pq);
    colstats_final<<<dim3(2), blk, 0, stream>>>(ps, pq, mean, rstd);
    // layer 1
    prep_act_k<9, true><<<dim3(4096), blk, 0, stream>>>(h0, mean, rstd, g0, be0, A2);
    prepw_k<<<dim3(16, 16), blk, 0, stream>>>(w1, B3t, 512, 512, 1536);
    mfma_gemm<0><<<dim3(8, 64), blk, 0, stream>>>(A2, B3t, b1, h1, 1536, 1024, 512, 512);
    colstats_partial<<<dim3(8, 32), blk, 0, stream>>>(h1, ps, pq);
    colstats_final<<<dim3(2), blk, 0, stream>>>(ps, pq, mean, rstd);
    // layer 2
    prep_act_k<9, true><<<dim3(4096), blk, 0, stream>>>(h1, mean, rstd, g1, be1, A2);
    prepw_k<<<dim3(16, 16), blk, 0, stream>>>(w2, B3t, 512, 512, 1536);
    mfma_gemm<0><<<dim3(8, 64), blk, 0, stream>>>(A2, B3t, b2, h2, 1536, 1024, 512, 512);
    colstats_partial<<<dim3(8, 32), blk, 0, stream>>>(h2, ps, pq);
    colstats_final<<<dim3(2), blk, 0, stream>>>(ps, pq, mean, rstd);
    // layer 3: fcs = mod_sigmoid(...) [8192][1040], valid cols 1025
    prep_act_k<9, true><<<dim3(4096), blk, 0, stream>>>(h2, mean, rstd, g2, be2, A2);
    prepw_k<<<dim3(16, 36), blk, 0, stream>>>(w3, B3t, 512, 1025, 1536);
    mfma_gemm<1><<<dim3(17, 64), blk, 0, stream>>>(A2, B3t, b3, fcs, 1536, 1024, 1025, 1040);
    // spectral filtering + window
    fft_filter_kernel<<<dim3(8192), blk, 0, stream>>>(noise, fcs, aw);
    // fused OLA + post conv + softsign
    ola_ppconv_kernel<<<dim3(1030, 16), blk, 0, stream>>>(aw, ppw, ppb, out);
    (void)in_sizes; (void)n_in; (void)out_size; (void)ws_size;
}

// Round 3
// 283.134 us; speedup vs baseline: 2.1495x; 1.2654x over previous
//
#include <hip/hip_runtime.h>
#include <hip/hip_bf16.h>
#include <math.h>

#define TARLEN 263680
#define POWEXP 2.302585092994046f  // ln(10)
#define P(i) ((i) + ((i) >> 5))    // LDS anti-bank-conflict padding

typedef __attribute__((ext_vector_type(8))) short bf16x8;
typedef __attribute__((ext_vector_type(4))) float f32x4;

__device__ __forceinline__ void gload16(const void* g, void* l) {
    __builtin_amdgcn_global_load_lds((const __attribute__((address_space(1))) void*)g,
                                     (__attribute__((address_space(3))) void*)l, 16, 0, 0);
}

__device__ __forceinline__ float norm_lrelu(float a, float m, float rs, float g, float b) {
    float x = (a - m) * rs * g + b;
    return x >= 0.f ? x : 0.2f * x;
}

__device__ __forceinline__ void split_bf16(float x, ushort& hi, ushort& lo) {
    __hip_bfloat16 h = __float2bfloat16(x);
    hi = *reinterpret_cast<ushort*>(&h);
    float rem = x - __bfloat162float(h);
    __hip_bfloat16 l = __float2bfloat16(rem);
    lo = *reinterpret_cast<ushort*>(&l);
}

// ---------------- split-bf16 MFMA GEMM, 128x128 tile, 512 thr (8 waves 2x2 of 64x32)
// A2 = [Ahi | Alo] ([M][2K] bf16), B3t = [N][3K] bf16 rows = [Bhi Bhi Blo].
// K'=3K loop: A col map k'<2K -> k', else k'-2K => Ahi*Bhi + Alo*Bhi + Ahi*Blo.
// EPI==0: also emit per-block column sum/sumsq partials (BN stats fusion).
template<int EPI>
__global__ __launch_bounds__(512) void mfma_gemm(
    const ushort* __restrict__ A2, const ushort* __restrict__ B3t,
    const float* __restrict__ bias, float* __restrict__ C,
    int K3, int K2, int Nvalid, int ldc,
    float* __restrict__ ps, float* __restrict__ pq)
{
    __shared__ ushort As[2][4096];  // [128][32]
    __shared__ ushort Bs[2][4096];  // [128][32]
    __shared__ float sred[8][2][16];
    __shared__ float qred[8][2][16];
    const int tid = threadIdx.x;
    const int lane = tid & 63;
    const int wid = tid >> 6;
    const int wm = wid >> 2;        // 0..1
    const int wn = wid & 3;         // 0..3
    const int m0 = blockIdx.y * 128;
    const int n0 = blockIdx.x * 128;
    const int NT = K3 >> 5;

    f32x4 acc[4][2];
#pragma unroll
    for (int m = 0; m < 4; ++m)
#pragma unroll
        for (int n = 0; n < 2; ++n)
            acc[m][n] = (f32x4){0.f, 0.f, 0.f, 0.f};

    const int srow = wid * 16 + (lane >> 2);   // 0..127
    const int scol = (lane & 3) << 3;          // 0,8,16,24

    auto stage = [&](int t, int buf) {
        const int k0 = t << 5;
        const int ka = (k0 < K2) ? k0 : (k0 - K2);
        gload16(A2 + (size_t)(m0 + srow) * K2 + ka + scol, &As[buf][wid * 512]);
        gload16(B3t + (size_t)(n0 + srow) * K3 + k0 + scol, &Bs[buf][wid * 512]);
    };

    const int lr = lane & 15;
    const int lk = (lane >> 4) << 3;
    const int wm0 = wm * 64;
    const int wn0 = wn * 32;

    stage(0, 0);
    __syncthreads();
    for (int t = 0; t < NT; ++t) {
        int cur = t & 1;
        if (t + 1 < NT) stage(t + 1, cur ^ 1);
        const ushort* as = As[cur];
        const ushort* bs = Bs[cur];
        bf16x8 af[4], bfv[2];
#pragma unroll
        for (int m = 0; m < 4; ++m)
            af[m] = *reinterpret_cast<const bf16x8*>(&as[(wm0 + m * 16 + lr) * 32 + lk]);
#pragma unroll
        for (int n = 0; n < 2; ++n)
            bfv[n] = *reinterpret_cast<const bf16x8*>(&bs[(wn0 + n * 16 + lr) * 32 + lk]);
#pragma unroll
        for (int m = 0; m < 4; ++m)
#pragma unroll
            for (int n = 0; n < 2; ++n)
                acc[m][n] = __builtin_amdgcn_mfma_f32_16x16x32_bf16(af[m], bfv[n], acc[m][n], 0, 0, 0);
        __syncthreads();
    }

    // epilogue: C/D layout col=lane&15, row=(lane>>4)*4+reg
    const int cr = (lane >> 4) << 2;
    const int cc = lane & 15;
    float sacc[2] = {0.f, 0.f}, qacc[2] = {0.f, 0.f};
#pragma unroll
    for (int m = 0; m < 4; ++m) {
#pragma unroll
        for (int n = 0; n < 2; ++n) {
            int gcol = n0 + wn0 + n * 16 + cc;
            if (gcol < Nvalid) {
                float bv = bias[gcol];
                int grow = m0 + wm0 + m * 16 + cr;
#pragma unroll
                for (int j = 0; j < 4; ++j) {
                    float v = acc[m][n][j] + bv;
                    if (EPI == 1) {
                        float sg = 1.f / (1.f + __expf(-v));
                        v = 2.f * __expf(POWEXP * __logf(sg)) + 1e-7f;
                    } else {
                        sacc[n] += v;
                        qacc[n] += v * v;
                    }
                    C[(size_t)(grow + j) * ldc + gcol] = v;
                }
            }
        }
    }
    if (EPI == 0) {
#pragma unroll
        for (int n = 0; n < 2; ++n) {
            float s = sacc[n], q = qacc[n];
            s += __shfl_xor(s, 16); q += __shfl_xor(q, 16);
            s += __shfl_xor(s, 32); q += __shfl_xor(q, 32);
            if (lane < 16) { sred[wid][n][lane] = s; qred[wid][n][lane] = q; }
        }
        __syncthreads();
        if (tid < 128) {
            int wn_ = tid >> 5, n_ = (tid >> 4) & 1, cc_ = tid & 15;
            float s = sred[wn_][n_][cc_] + sred[4 + wn_][n_][cc_];
            float q = qred[wn_][n_][cc_] + qred[4 + wn_][n_][cc_];
            int col = n0 + wn_ * 32 + n_ * 16 + cc_;
            ps[(size_t)blockIdx.y * 512 + col] = s;
            pq[(size_t)blockIdx.y * 512 + col] = q;
        }
    }
}

// ---------------- prep: activations -> BN+LeakyReLU -> hi/lo bf16 ---------
template<int KSH, bool NORM>
__global__ __launch_bounds__(256) void prep_act_k(
    const float* __restrict__ H, const float* __restrict__ mean,
    const float* __restrict__ rstd, const float* __restrict__ gamma,
    const float* __restrict__ beta, ushort* __restrict__ A2)
{
    const int K = 1 << KSH;
    int idx = (blockIdx.x * 256 + threadIdx.x) << 2;
    int col = idx & (K - 1);
    int row = idx >> KSH;
    float4 h = *reinterpret_cast<const float4*>(&H[idx]);
    float x[4] = {h.x, h.y, h.z, h.w};
    if (NORM) {
        float4 mm = *reinterpret_cast<const float4*>(&mean[col]);
        float4 rs = *reinterpret_cast<const float4*>(&rstd[col]);
        float4 gg = *reinterpret_cast<const float4*>(&gamma[col]);
        float4 bb = *reinterpret_cast<const float4*>(&beta[col]);
        x[0] = norm_lrelu(x[0], mm.x, rs.x, gg.x, bb.x);
        x[1] = norm_lrelu(x[1], mm.y, rs.y, gg.y, bb.y);
        x[2] = norm_lrelu(x[2], mm.z, rs.z, gg.z, bb.z);
        x[3] = norm_lrelu(x[3], mm.w, rs.w, gg.w, bb.w);
    }
    ushort4 hv, lv;
    split_bf16(x[0], hv.x, lv.x);
    split_bf16(x[1], hv.y, lv.y);
    split_bf16(x[2], hv.z, lv.z);
    split_bf16(x[3], hv.w, lv.w);
    ushort* dst = &A2[(size_t)row * (2 * K) + col];
    *reinterpret_cast<ushort4*>(dst) = hv;
    *reinterpret_cast<ushort4*>(dst + K) = lv;
}

// ---------------- prep: weights -> transpose + hi/lo split ----------------
__global__ __launch_bounds__(256) void prepw_k(
    const float* __restrict__ w, ushort* __restrict__ B3t, int K, int N, int K3)
{
    __shared__ float tile[32][33];
    int k0 = blockIdx.x * 32, n0 = blockIdx.y * 32;
    int tx = threadIdx.x & 31, ty = threadIdx.x >> 5;  // 32 x 8
#pragma unroll
    for (int r = 0; r < 4; ++r) {
        int k = k0 + ty + r * 8;
        int n = n0 + tx;
        tile[ty + r * 8][tx] = (n < N) ? w[(size_t)k * N + n] : 0.f;
    }
    __syncthreads();
#pragma unroll
    for (int r = 0; r < 4; ++r) {
        int n = n0 + ty + r * 8;
        int k = k0 + tx;
        float x = tile[tx][ty + r * 8];
        ushort hi, lo;
        split_bf16(x, hi, lo);
        size_t base = (size_t)n * K3;
        B3t[base + k] = hi;
        B3t[base + K + k] = hi;
        B3t[base + 2 * K + k] = lo;
    }
}

// ---------------- BN stats final reduce (64 row-block partials) -----------
__global__ __launch_bounds__(256) void colstats_final(
    const float* __restrict__ ps, const float* __restrict__ pq,
    float* __restrict__ mean, float* __restrict__ rstd)
{
    int c = blockIdx.x * 256 + threadIdx.x;
    float s = 0.f, q = 0.f;
    for (int rg = 0; rg < 64; ++rg) { s += ps[rg * 512 + c]; q += pq[rg * 512 + c]; }
    float m = s * (1.f / 8192.f);
    float v = q * (1.f / 8192.f) - m * m;
    mean[c] = m;
    rstd[c] = rsqrtf(v + 1e-5f);
}

// ---------------- Stockham radix-4 FFT (1024-pt complex), 256 threads -----
// Stage L=4^s: k = t mod L; read src[t + 256q]; twiddle e^{-+2pi i qk/(4L)};
// radix-4 DFT; write dst[4(t-k)+k+qL]. Natural order in/out, no bit-reverse.
template<bool INV>
__device__ __forceinline__ void stk_stage(
    const float* __restrict__ sr, const float* __restrict__ si,
    float* __restrict__ dr, float* __restrict__ di, int t, int L)
{
    int k = t & (L - 1);
    float x0r = sr[P(t)],       x0i = si[P(t)];
    float x1r = sr[P(t + 256)], x1i = si[P(t + 256)];
    float x2r = sr[P(t + 512)], x2i = si[P(t + 512)];
    float x3r = sr[P(t + 768)], x3i = si[P(t + 768)];
    if (L > 1) {
        float th = (INV ? 2.0f : -2.0f) * (float)M_PI * (float)k / (float)(4 * L);
        float s1, c1; __sincosf(th, &s1, &c1);
        float c2 = c1 * c1 - s1 * s1, s2 = 2.f * c1 * s1;
        float c3 = c2 * c1 - s2 * s1, s3 = s2 * c1 + c2 * s1;
        float r;
        r = x1r * c1 - x1i * s1; x1i = x1r * s1 + x1i * c1; x1r = r;
        r = x2r * c2 - x2i * s2; x2i = x2r * s2 + x2i * c2; x2r = r;
        r = x3r * c3 - x3i * s3; x3i = x3r * s3 + x3i * c3; x3r = r;
    }
    float ar = x0r + x2r, ai = x0i + x2i;
    float br = x0r - x2r, bi = x0i - x2i;
    float cr = x1r + x3r, ci = x1i + x3i;
    float dr_ = x1r - x3r, di_ = x1i - x3i;
    int db = ((t - k) << 2) + k;
    dr[P(db)] = ar + cr;          di[P(db)] = ai + ci;
    dr[P(db + 2 * L)] = ar - cr;  di[P(db + 2 * L)] = ai - ci;
    if (!INV) {
        dr[P(db + L)] = br + di_;     di[P(db + L)] = bi - dr_;
        dr[P(db + 3 * L)] = br - di_; di[P(db + 3 * L)] = bi + dr_;
    } else {
        dr[P(db + L)] = br - di_;     di[P(db + L)] = bi + dr_;
        dr[P(db + 3 * L)] = br + di_; di[P(db + 3 * L)] = bi - dr_;
    }
}

template<bool INV>
__device__ __forceinline__ void fft1024_stk(
    float* Xr, float* Xi, float* Yr, float* Yi, int t)
{
    stk_stage<INV>(Xr, Xi, Yr, Yi, t, 1);   __syncthreads();
    stk_stage<INV>(Yr, Yi, Xr, Xi, t, 4);   __syncthreads();
    stk_stage<INV>(Xr, Xi, Yr, Yi, t, 16);  __syncthreads();
    stk_stage<INV>(Yr, Yi, Xr, Xi, t, 64);  __syncthreads();
    stk_stage<INV>(Xr, Xi, Yr, Yi, t, 256); __syncthreads();
}

// audio = irfft( rfft(noise_row) * H ), H[k] = (-1)^k*(0.5 fc[k]+0.25 fc[k-1]+0.25 fc[k+1])
// (analytic collapse of rfft(fftshift(irfft(fc)*FW))). Then apply OLA window.
__global__ __launch_bounds__(256) void fft_filter_kernel(
    const float* __restrict__ noise, const float* __restrict__ fcs, float* __restrict__ aw)
{
    __shared__ float Xr[1056], Xi[1056], Yr[1056], Yi[1056], F[1025];
    const int tid = threadIdx.x;
    const int r = blockIdx.x;

    const float2* nrow = reinterpret_cast<const float2*>(noise + ((size_t)r << 11));
    for (int i = tid; i < 1024; i += 256) {
        float2 v = nrow[i];
        Xr[P(i)] = v.x; Xi[P(i)] = v.y;  // pack z[n] = x[2n] + i x[2n+1]
    }
    for (int i = tid; i < 1025; i += 256) F[i] = fcs[(size_t)r * 1040 + i];
    __syncthreads();

    fft1024_stk<false>(Xr, Xi, Yr, Yi, tid);  // forward; result in Y (natural order)

    // unpack real FFT, apply H, repack for inverse real FFT; read Y, write X
    for (int k = tid; k < 513; k += 256) {
        int k2 = (1024 - k) & 1023;
        float zar = Yr[P(k)], zai = Yi[P(k)];
        float zbr = Yr[P(k2)], zbi = Yi[P(k2)];
        float Fer = 0.5f * (zar + zbr), Fei = 0.5f * (zai - zbi);
        float For = 0.5f * (zai + zbi), Foi = 0.5f * (zbr - zar);
        float s, c;
        __sincosf((float)(-M_PI / 1024.0) * k, &s, &c);
        float wFr = c * For - s * Foi;
        float wFi = c * Foi + s * For;
        float Xkr = Fer + wFr, Xki = Fei + wFi;
        float Xbr = Fer - wFr, Xbi = wFi - Fei;
        float Hk, Hb;
        {
            float cl = (k == 0) ? F[1] : F[k - 1];
            float crr = (k == 1024) ? F[1023] : F[k + 1];
            float h = 0.5f * F[k] + 0.25f * (cl + crr);
            Hk = (k & 1) ? -h : h;
        }
        {
            int kb = 1024 - k;
            float cl = (kb == 0) ? F[1] : F[kb - 1];
            float crr = (kb == 1024) ? F[1023] : F[kb + 1];
            float h = 0.5f * F[kb] + 0.25f * (cl + crr);
            Hb = (kb & 1) ? -h : h;
        }
        float Ykr = Hk * Xkr, Yki = Hk * Xki;
        float Ybr = Hb * Xbr, Ybi = Hb * Xbi;
        if (k == 0) {
            Xr[P(0)] = 0.5f * (Ykr + Ybr);
            Xi[P(0)] = 0.5f * (Ykr - Ybr);
        } else {
            float Ger = 0.5f * (Ykr + Ybr), Gei = 0.5f * (Yki - Ybi);
            float Sgr = 0.5f * (Ykr - Ybr), Sgi = 0.5f * (Yki + Ybi);
            float wpr = c, wpi = -s;
            float Gor = wpr * Sgr - wpi * Sgi;
            float Goi = wpr * Sgi + wpi * Sgr;
            Xr[P(k)] = Ger - Goi;  Xi[P(k)] = Gei + Gor;
            Xr[P(k2)] = Ger + Goi; Xi[P(k2)] = Gor - Gei;
        }
    }
    __syncthreads();

    fft1024_stk<true>(Xr, Xi, Yr, Yi, tid);  // inverse; result in Y (scale 1/1024 below)

    const int g = r & 511;
    const float inv = 1.0f / 1024.0f;
    float2* awrow = reinterpret_cast<float2*>(aw + ((size_t)r << 11));
    for (int i = tid; i < 1024; i += 256) {
        float y0 = Yr[P(i)] * inv, y1 = Yi[P(i)] * inv;
        int n0 = 2 * i, n1 = n0 + 1;
        float w0 = 0.5f - 0.5f * __cosf((float)(M_PI / 1024.0) * n0);
        float w1 = 0.5f - 0.5f * __cosf((float)(M_PI / 1024.0) * n1);
        if (g == 0) { if (n0 < 1024) w0 = 1.f; if (n1 < 1024) w1 = 1.f; }
        if (g == 511) { if (n0 >= 1024) w0 = 1.f; if (n1 >= 1024) w1 = 1.f; }
        float2 o; o.x = y0 * w0; o.y = y1 * w1;
        awrow[i] = o;
    }
}

// ---------------- fused OLA gather + 65-tap conv + softsign ---------------
__global__ __launch_bounds__(256) void ola_ppconv_kernel(
    const float* __restrict__ aw, const float* __restrict__ ppw,
    const float* __restrict__ ppb, float* __restrict__ out)
{
    __shared__ float tile[320];
    __shared__ float Ksh[65];
    int t0 = blockIdx.x * 256;
    int b = blockIdx.y;
    for (int i = threadIdx.x; i < 320; i += 256) {
        int tt = t0 - 32 + i;
        float v = 0.f;
        if (tt >= 0 && tt < TARLEN) {
            int ghi = min(511, tt >> 9);
            int glo = max(0, (tt - 1536) >> 9);
            float s = 0.f;
            for (int g = glo; g <= ghi; ++g) {
                int n = tt - (g << 9);
                s += aw[((size_t)(b * 512 + g) << 11) + n];
            }
            v = s / (float)(ghi - glo + 1);
        }
        tile[i] = v;
    }
    if (threadIdx.x < 65) {
        float k = 0.f;
#pragma unroll
        for (int c = 0; c < 5; ++c) k += ppw[c * 65 + threadIdx.x];
        Ksh[threadIdx.x] = k;
    }
    __syncthreads();
    float y = ppb[0];
#pragma unroll
    for (int j = 0; j < 65; ++j) y = fmaf(Ksh[j], tile[threadIdx.x + j], y);
    int t = t0 + threadIdx.x;
    out[(size_t)b * TARLEN + t] = y / (1.f + fabsf(y));
}

// ---------------- launch --------------------------------------------------
extern "C" void kernel_launch(void* const* d_in, const int* in_sizes, int n_in,
                              void* d_out, int out_size, void* d_ws, size_t ws_size,
                              hipStream_t stream) {
    const float* z    = (const float*)d_in[0];
    const float* w0   = (const float*)d_in[1];
    const float* b0   = (const float*)d_in[2];
    const float* g0   = (const float*)d_in[3];
    const float* be0  = (const float*)d_in[4];
    const float* w1   = (const float*)d_in[5];
    const float* b1   = (const float*)d_in[6];
    const float* g1   = (const float*)d_in[7];
    const float* be1  = (const float*)d_in[8];
    const float* w2   = (const float*)d_in[9];
    const float* b2   = (const float*)d_in[10];
    const float* g2   = (const float*)d_in[11];
    const float* be2  = (const float*)d_in[12];
    const float* w3   = (const float*)d_in[13];
    const float* b3   = (const float*)d_in[14];
    const float* ppw  = (const float*)d_in[15];
    const float* ppb  = (const float*)d_in[16];
    const float* noise= (const float*)d_in[17];
    float* out = (float*)d_out;
    float* ws = (float*)d_ws;

    // workspace (floats), total ~30.44M = 121.8 MiB
    float* h0   = ws;                  // 8192*512
    float* ps   = ws + 4194304;        // 64*512
    float* pq   = ps + 32768;          // 64*512
    float* mean = pq + 32768;          // 512
    float* rstd = mean + 512;          // 512
    float* B3tf = rstd + 512;          // 1152*1536 bf16 = 884736 f
    float* fcs  = B3tf + 884736;       // 8192*1040 f (h1 aliases start)
    float* awf  = fcs + 8519680;       // 8192*2048 f (A2 aliases start)
    ushort* B3t = (ushort*)B3tf;
    ushort* A2  = (ushort*)awf;
    float* h1 = fcs;   // dead before fcs written
    float* h2 = h0;    // h0 dead after its prep
    float* aw = awf;   // A2 dead before fft writes

    dim3 blk(256);
    dim3 gblk(512);
    // layer 0: h0 = z @ w0 + b0 (+ fused col stats)
    prep_act_k<7, false><<<dim3(1024), blk, 0, stream>>>(z, nullptr, nullptr, nullptr, nullptr, A2);
    prepw_k<<<dim3(4, 16), blk, 0, stream>>>(w0, B3t, 128, 512, 384);
    mfma_gemm<0><<<dim3(4, 64), gblk, 0, stream>>>(A2, B3t, b0, h0, 384, 256, 512, 512, ps, pq);
    colstats_final<<<dim3(2), blk, 0, stream>>>(ps, pq, mean, rstd);
    // layer 1
    prep_act_k<9, true><<<dim3(4096), blk, 0, stream>>>(h0, mean, rstd, g0, be0, A2);
    prepw_k<<<dim3(16, 16), blk, 0, stream>>>(w1, B3t, 512, 512, 1536);
    mfma_gemm<0><<<dim3(4, 64), gblk, 0, stream>>>(A2, B3t, b1, h1, 1536, 1024, 512, 512, ps, pq);
    colstats_final<<<dim3(2), blk, 0, stream>>>(ps, pq, mean, rstd);
    // layer 2
    prep_act_k<9, true><<<dim3(4096), blk, 0, stream>>>(h1, mean, rstd, g1, be1, A2);
    prepw_k<<<dim3(16, 16), blk, 0, stream>>>(w2, B3t, 512, 512, 1536);
    mfma_gemm<0><<<dim3(4, 64), gblk, 0, stream>>>(A2, B3t, b2, h2, 1536, 1024, 512, 512, ps, pq);
    colstats_final<<<dim3(2), blk, 0, stream>>>(ps, pq, mean, rstd);
    // layer 3: fcs = mod_sigmoid(...) [8192][1040], valid cols 1025
    prep_act_k<9, true><<<dim3(4096), blk, 0, stream>>>(h2, mean, rstd, g2, be2, A2);
    prepw_k<<<dim3(16, 36), blk, 0, stream>>>(w3, B3t, 512, 1025, 1536);
    mfma_gemm<1><<<dim3(9, 64), gblk, 0, stream>>>(A2, B3t, b3, fcs, 1536, 1024, 1025, 1040, nullptr, nullptr);
    // spectral filtering + window
    fft_filter_kernel<<<dim3(8192), blk, 0, stream>>>(noise, fcs, aw);
    // fused OLA + post conv + softsign
    ola_ppconv_kernel<<<dim3(1030, 16), blk, 0, stream>>>(aw, ppw, ppb, out);
    (void)in_sizes; (void)n_in; (void)out_size; (void)ws_size;
}

// Round 4
// 268.303 us; speedup vs baseline: 2.2683x; 1.0553x over previous
//
#include <hip/hip_runtime.h>
#include <hip/hip_bf16.h>
#include <math.h>

#define TARLEN 263680
#define POWEXP 2.302585092994046f  // ln(10)
#define PC(i) ((i) + ((i) >> 3))   // complex-unit LDS padding (1 per 8)

typedef __attribute__((ext_vector_type(8))) short bf16x8;
typedef __attribute__((ext_vector_type(4))) float f32x4;

__device__ __forceinline__ void gload16(const void* g, void* l) {
    __builtin_amdgcn_global_load_lds((const __attribute__((address_space(1))) void*)g,
                                     (__attribute__((address_space(3))) void*)l, 16, 0, 0);
}

__device__ __forceinline__ float norm_lrelu(float a, float m, float rs, float g, float b) {
    float x = (a - m) * rs * g + b;
    return x >= 0.f ? x : 0.2f * x;
}

__device__ __forceinline__ void split_bf16(float x, ushort& hi, ushort& lo) {
    __hip_bfloat16 h = __float2bfloat16(x);
    hi = *reinterpret_cast<ushort*>(&h);
    float rem = x - __bfloat162float(h);
    __hip_bfloat16 l = __float2bfloat16(rem);
    lo = *reinterpret_cast<ushort*>(&l);
}

// ---------------- split-bf16 MFMA GEMM, 128x128 tile, 512 thr (8 waves 2x2 of 64x32)
// A2 = [Ahi | Alo] ([M][2K] bf16), B3t = [N][3K] bf16 rows = [Bhi Bhi Blo].
// K'=3K loop => Ahi*Bhi + Alo*Bhi + Ahi*Blo. XCD-chunked block swizzle.
template<int EPI>
__global__ __launch_bounds__(512, 4) void mfma_gemm(
    const ushort* __restrict__ A2, const ushort* __restrict__ B3t,
    const float* __restrict__ bias, float* __restrict__ C,
    int K3, int K2, int Nvalid, int ldc,
    float* __restrict__ ps, float* __restrict__ pq)
{
    __shared__ ushort As[2][4096];  // [128][32]
    __shared__ ushort Bs[2][4096];  // [128][32]
    __shared__ float sred[8][2][16];
    __shared__ float qred[8][2][16];
    const int tid = threadIdx.x;
    const int lane = tid & 63;
    const int wid = tid >> 6;
    const int wm = wid >> 2;        // 0..1
    const int wn = wid & 3;         // 0..3
    // bijective XCD swizzle (nwg % 8 == 0 for all our grids)
    const int nwg = gridDim.x * gridDim.y;
    const int bid = blockIdx.y * gridDim.x + blockIdx.x;
    const int q8 = nwg >> 3;
    const int swz = (bid & 7) * q8 + (bid >> 3);
    const int bx = swz % gridDim.x;
    const int by = swz / gridDim.x;
    const int m0 = by * 128;
    const int n0 = bx * 128;
    const int NT = K3 >> 5;

    f32x4 acc[4][2];
#pragma unroll
    for (int m = 0; m < 4; ++m)
#pragma unroll
        for (int n = 0; n < 2; ++n)
            acc[m][n] = (f32x4){0.f, 0.f, 0.f, 0.f};

    const int srow = wid * 16 + (lane >> 2);   // 0..127
    const int scol = (lane & 3) << 3;          // 0,8,16,24

    auto stage = [&](int t, int buf) {
        const int k0 = t << 5;
        const int ka = (k0 < K2) ? k0 : (k0 - K2);
        gload16(A2 + (size_t)(m0 + srow) * K2 + ka + scol, &As[buf][wid * 512]);
        gload16(B3t + (size_t)(n0 + srow) * K3 + k0 + scol, &Bs[buf][wid * 512]);
    };

    const int lr = lane & 15;
    const int lk = (lane >> 4) << 3;
    const int wm0 = wm * 64;
    const int wn0 = wn * 32;

    stage(0, 0);
    __syncthreads();
    for (int t = 0; t < NT; ++t) {
        int cur = t & 1;
        if (t + 1 < NT) stage(t + 1, cur ^ 1);
        const ushort* as = As[cur];
        const ushort* bs = Bs[cur];
        bf16x8 af[4], bfv[2];
#pragma unroll
        for (int m = 0; m < 4; ++m)
            af[m] = *reinterpret_cast<const bf16x8*>(&as[(wm0 + m * 16 + lr) * 32 + lk]);
#pragma unroll
        for (int n = 0; n < 2; ++n)
            bfv[n] = *reinterpret_cast<const bf16x8*>(&bs[(wn0 + n * 16 + lr) * 32 + lk]);
#pragma unroll
        for (int m = 0; m < 4; ++m)
#pragma unroll
            for (int n = 0; n < 2; ++n)
                acc[m][n] = __builtin_amdgcn_mfma_f32_16x16x32_bf16(af[m], bfv[n], acc[m][n], 0, 0, 0);
        __syncthreads();
    }

    // epilogue: C/D layout col=lane&15, row=(lane>>4)*4+reg
    const int cr = (lane >> 4) << 2;
    const int cc = lane & 15;
    float sacc[2] = {0.f, 0.f}, qacc[2] = {0.f, 0.f};
#pragma unroll
    for (int m = 0; m < 4; ++m) {
#pragma unroll
        for (int n = 0; n < 2; ++n) {
            int gcol = n0 + wn0 + n * 16 + cc;
            if (gcol < Nvalid) {
                float bv = bias[gcol];
                int grow = m0 + wm0 + m * 16 + cr;
#pragma unroll
                for (int j = 0; j < 4; ++j) {
                    float v = acc[m][n][j] + bv;
                    if (EPI == 1) {
                        float sg = 1.f / (1.f + __expf(-v));
                        v = 2.f * __expf(POWEXP * __logf(sg)) + 1e-7f;
                    } else {
                        sacc[n] += v;
                        qacc[n] += v * v;
                    }
                    C[(size_t)(grow + j) * ldc + gcol] = v;
                }
            }
        }
    }
    if (EPI == 0) {
#pragma unroll
        for (int n = 0; n < 2; ++n) {
            float s = sacc[n], q = qacc[n];
            s += __shfl_xor(s, 16); q += __shfl_xor(q, 16);
            s += __shfl_xor(s, 32); q += __shfl_xor(q, 32);
            if (lane < 16) { sred[wid][n][lane] = s; qred[wid][n][lane] = q; }
        }
        __syncthreads();
        if (tid < 128) {
            int wn_ = tid >> 5, n_ = (tid >> 4) & 1, cc_ = tid & 15;
            float s = sred[wn_][n_][cc_] + sred[4 + wn_][n_][cc_];
            float q = qred[wn_][n_][cc_] + qred[4 + wn_][n_][cc_];
            int col = n0 + wn_ * 32 + n_ * 16 + cc_;
            ps[(size_t)by * 512 + col] = s;
            pq[(size_t)by * 512 + col] = q;
        }
    }
}

// ---------------- prep: activations -> BN+LeakyReLU -> hi/lo bf16 ---------
template<int KSH, bool NORM>
__global__ __launch_bounds__(256) void prep_act_k(
    const float* __restrict__ H, const float* __restrict__ mean,
    const float* __restrict__ rstd, const float* __restrict__ gamma,
    const float* __restrict__ beta, ushort* __restrict__ A2)
{
    const int K = 1 << KSH;
    int idx = (blockIdx.x * 256 + threadIdx.x) << 2;
    int col = idx & (K - 1);
    int row = idx >> KSH;
    float4 h = *reinterpret_cast<const float4*>(&H[idx]);
    float x[4] = {h.x, h.y, h.z, h.w};
    if (NORM) {
        float4 mm = *reinterpret_cast<const float4*>(&mean[col]);
        float4 rs = *reinterpret_cast<const float4*>(&rstd[col]);
        float4 gg = *reinterpret_cast<const float4*>(&gamma[col]);
        float4 bb = *reinterpret_cast<const float4*>(&beta[col]);
        x[0] = norm_lrelu(x[0], mm.x, rs.x, gg.x, bb.x);
        x[1] = norm_lrelu(x[1], mm.y, rs.y, gg.y, bb.y);
        x[2] = norm_lrelu(x[2], mm.z, rs.z, gg.z, bb.z);
        x[3] = norm_lrelu(x[3], mm.w, rs.w, gg.w, bb.w);
    }
    ushort4 hv, lv;
    split_bf16(x[0], hv.x, lv.x);
    split_bf16(x[1], hv.y, lv.y);
    split_bf16(x[2], hv.z, lv.z);
    split_bf16(x[3], hv.w, lv.w);
    ushort* dst = &A2[(size_t)row * (2 * K) + col];
    *reinterpret_cast<ushort4*>(dst) = hv;
    *reinterpret_cast<ushort4*>(dst + K) = lv;
}

// ---------------- prep: weights -> transpose + hi/lo split ----------------
__global__ __launch_bounds__(256) void prepw_k(
    const float* __restrict__ w, ushort* __restrict__ B3t, int K, int N, int K3)
{
    __shared__ float tile[32][33];
    int k0 = blockIdx.x * 32, n0 = blockIdx.y * 32;
    int tx = threadIdx.x & 31, ty = threadIdx.x >> 5;  // 32 x 8
#pragma unroll
    for (int r = 0; r < 4; ++r) {
        int k = k0 + ty + r * 8;
        int n = n0 + tx;
        tile[ty + r * 8][tx] = (n < N) ? w[(size_t)k * N + n] : 0.f;
    }
    __syncthreads();
#pragma unroll
    for (int r = 0; r < 4; ++r) {
        int n = n0 + ty + r * 8;
        int k = k0 + tx;
        float x = tile[tx][ty + r * 8];
        ushort hi, lo;
        split_bf16(x, hi, lo);
        size_t base = (size_t)n * K3;
        B3t[base + k] = hi;
        B3t[base + K + k] = hi;
        B3t[base + 2 * K + k] = lo;
    }
}

// ---------------- BN stats final reduce (64 row-block partials) -----------
__global__ __launch_bounds__(256) void colstats_final(
    const float* __restrict__ ps, const float* __restrict__ pq,
    float* __restrict__ mean, float* __restrict__ rstd)
{
    int c = blockIdx.x * 256 + threadIdx.x;
    float s = 0.f, q = 0.f;
    for (int rg = 0; rg < 64; ++rg) { s += ps[rg * 512 + c]; q += pq[rg * 512 + c]; }
    float m = s * (1.f / 8192.f);
    float v = q * (1.f / 8192.f) - m * m;
    mean[c] = m;
    rstd[c] = rsqrtf(v + 1e-5f);
}

// ---------------- Stockham radix-4 FFT, float2 LDS, 256 threads -----------
__device__ __forceinline__ float2 cmul(float2 a, float c, float s) {
    return make_float2(a.x * c - a.y * s, a.x * s + a.y * c);
}

template<bool INV, int L>
__device__ __forceinline__ void stk_stage(
    const float2* __restrict__ s, float2* __restrict__ d, int t)
{
    int k = t & (L - 1);
    float2 x0 = s[PC(t)];
    float2 x1 = s[PC(t + 256)];
    float2 x2 = s[PC(t + 512)];
    float2 x3 = s[PC(t + 768)];
    if (L > 1) {
        float th = (INV ? 2.0f : -2.0f) * (float)M_PI * (float)k / (float)(4 * L);
        float s1, c1; __sincosf(th, &s1, &c1);
        float c2 = c1 * c1 - s1 * s1, s2 = 2.f * c1 * s1;
        float c3 = c2 * c1 - s2 * s1, s3 = s2 * c1 + c2 * s1;
        x1 = cmul(x1, c1, s1);
        x2 = cmul(x2, c2, s2);
        x3 = cmul(x3, c3, s3);
    }
    float2 a = make_float2(x0.x + x2.x, x0.y + x2.y);
    float2 b = make_float2(x0.x - x2.x, x0.y - x2.y);
    float2 c = make_float2(x1.x + x3.x, x1.y + x3.y);
    float2 e = make_float2(x1.x - x3.x, x1.y - x3.y);
    int db = ((t - k) << 2) + k;
    d[PC(db)]         = make_float2(a.x + c.x, a.y + c.y);
    d[PC(db + 2 * L)] = make_float2(a.x - c.x, a.y - c.y);
    if (!INV) {
        d[PC(db + L)]     = make_float2(b.x + e.y, b.y - e.x);
        d[PC(db + 3 * L)] = make_float2(b.x - e.y, b.y + e.x);
    } else {
        d[PC(db + L)]     = make_float2(b.x - e.y, b.y + e.x);
        d[PC(db + 3 * L)] = make_float2(b.x + e.y, b.y - e.x);
    }
}

// audio = irfft( rfft(noise_row) * H ), H[k] = (-1)^k*(0.5 fc[k]+0.25 fc[k-1]+0.25 fc[k+1])
// (analytic collapse of rfft(fftshift(irfft(fc)*FW))). OLA window fused in store.
__global__ __launch_bounds__(256) void fft_filter_kernel(
    const float* __restrict__ noise, const float* __restrict__ fcs, float* __restrict__ aw)
{
    __shared__ float2 X[1152], Y[1152];
    __shared__ float F[1025];
    const int tid = threadIdx.x;
    const int r = blockIdx.x;

    const float2* nrow = reinterpret_cast<const float2*>(noise + ((size_t)r << 11));
    for (int i = tid; i < 1025; i += 256) F[i] = fcs[(size_t)r * 1040 + i];
    {
        // forward stage L=1 fused with global load (pack z[n]=x[2n]+i x[2n+1])
        float2 x0 = nrow[tid], x1 = nrow[tid + 256], x2 = nrow[tid + 512], x3 = nrow[tid + 768];
        float2 a = make_float2(x0.x + x2.x, x0.y + x2.y);
        float2 b = make_float2(x0.x - x2.x, x0.y - x2.y);
        float2 c = make_float2(x1.x + x3.x, x1.y + x3.y);
        float2 e = make_float2(x1.x - x3.x, x1.y - x3.y);
        int db = tid << 2;
        Y[PC(db)]     = make_float2(a.x + c.x, a.y + c.y);
        Y[PC(db + 1)] = make_float2(b.x + e.y, b.y - e.x);
        Y[PC(db + 2)] = make_float2(a.x - c.x, a.y - c.y);
        Y[PC(db + 3)] = make_float2(b.x - e.y, b.y + e.x);
    }
    __syncthreads();
    stk_stage<false, 4>(Y, X, tid);   __syncthreads();
    stk_stage<false, 16>(X, Y, tid);  __syncthreads();
    stk_stage<false, 64>(Y, X, tid);  __syncthreads();
    stk_stage<false, 256>(X, Y, tid); __syncthreads();
    // forward result in Y (natural order)

    // unpack real FFT, apply H, repack for inverse real FFT; read Y, write X
    for (int k = tid; k < 513; k += 256) {
        int k2 = (1024 - k) & 1023;
        float2 za = Y[PC(k)], zb = Y[PC(k2)];
        float Fer = 0.5f * (za.x + zb.x), Fei = 0.5f * (za.y - zb.y);
        float For = 0.5f * (za.y + zb.y), Foi = 0.5f * (zb.x - za.x);
        float s, c;
        __sincosf((float)(-M_PI / 1024.0) * k, &s, &c);
        float wFr = c * For - s * Foi;
        float wFi = c * Foi + s * For;
        float Xkr = Fer + wFr, Xki = Fei + wFi;
        float Xbr = Fer - wFr, Xbi = wFi - Fei;
        float Hk, Hb;
        {
            float cl = (k == 0) ? F[1] : F[k - 1];
            float crr = (k == 1024) ? F[1023] : F[k + 1];
            float h = 0.5f * F[k] + 0.25f * (cl + crr);
            Hk = (k & 1) ? -h : h;
        }
        {
            int kb = 1024 - k;
            float cl = (kb == 0) ? F[1] : F[kb - 1];
            float crr = (kb == 1024) ? F[1023] : F[kb + 1];
            float h = 0.5f * F[kb] + 0.25f * (cl + crr);
            Hb = (kb & 1) ? -h : h;
        }
        float Ykr = Hk * Xkr, Yki = Hk * Xki;
        float Ybr = Hb * Xbr, Ybi = Hb * Xbi;
        if (k == 0) {
            X[PC(0)] = make_float2(0.5f * (Ykr + Ybr), 0.5f * (Ykr - Ybr));
        } else {
            float Ger = 0.5f * (Ykr + Ybr), Gei = 0.5f * (Yki - Ybi);
            float Sgr = 0.5f * (Ykr - Ybr), Sgi = 0.5f * (Yki + Ybi);
            float wpr = c, wpi = -s;
            float Gor = wpr * Sgr - wpi * Sgi;
            float Goi = wpr * Sgi + wpi * Sgr;
            X[PC(k)]  = make_float2(Ger - Goi, Gei + Gor);
            X[PC(k2)] = make_float2(Ger + Goi, Gor - Gei);
        }
    }
    __syncthreads();

    stk_stage<true, 1>(X, Y, tid);  __syncthreads();
    stk_stage<true, 4>(Y, X, tid);  __syncthreads();
    stk_stage<true, 16>(X, Y, tid); __syncthreads();
    stk_stage<true, 64>(Y, X, tid); __syncthreads();

    // inverse final stage (L=256) fused with scale + OLA window + store
    {
        const int g = r & 511;
        const float inv = 1.0f / 1024.0f;
        float2* awrow = reinterpret_cast<float2*>(aw + ((size_t)r << 11));
        int t = tid;
        float2 x0 = X[PC(t)], x1 = X[PC(t + 256)], x2 = X[PC(t + 512)], x3 = X[PC(t + 768)];
        float th = (float)(2.0 * M_PI / 1024.0) * t;
        float s1, c1; __sincosf(th, &s1, &c1);
        float c2 = c1 * c1 - s1 * s1, s2 = 2.f * c1 * s1;
        float c3 = c2 * c1 - s2 * s1, s3 = s2 * c1 + c2 * s1;
        x1 = cmul(x1, c1, s1);
        x2 = cmul(x2, c2, s2);
        x3 = cmul(x3, c3, s3);
        float2 a = make_float2(x0.x + x2.x, x0.y + x2.y);
        float2 b = make_float2(x0.x - x2.x, x0.y - x2.y);
        float2 c = make_float2(x1.x + x3.x, x1.y + x3.y);
        float2 e = make_float2(x1.x - x3.x, x1.y - x3.y);
        float2 o[4];
        int nn[4];
        o[0] = make_float2(a.x + c.x, a.y + c.y); nn[0] = t;
        o[1] = make_float2(b.x - e.y, b.y + e.x); nn[1] = t + 256;
        o[2] = make_float2(a.x - c.x, a.y - c.y); nn[2] = t + 512;
        o[3] = make_float2(b.x + e.y, b.y - e.x); nn[3] = t + 768;
        const float COSD = 0.99999529380958f;   // cos(pi/1024)
        const float SIND = 0.00306795676296f;   // sin(pi/1024)
#pragma unroll
        for (int q = 0; q < 4; ++q) {
            int n = nn[q];
            float y0 = o[q].x * inv, y1 = o[q].y * inv;
            float w0, w1;
            bool edge = (g == 0 && n < 512) || (g == 511 && n >= 512);
            if (edge) { w0 = 1.f; w1 = 1.f; }
            else {
                float sa, ca;
                __sincosf((float)(M_PI / 512.0) * n, &sa, &ca);
                w0 = 0.5f - 0.5f * ca;
                float cb = ca * COSD - sa * SIND;
                w1 = 0.5f - 0.5f * cb;
            }
            awrow[n] = make_float2(y0 * w0, y1 * w1);
        }
    }
}

// ---------------- fused OLA gather + 65-tap conv + softsign ---------------
__global__ __launch_bounds__(256) void ola_ppconv_kernel(
    const float* __restrict__ aw, const float* __restrict__ ppw,
    const float* __restrict__ ppb, float* __restrict__ out)
{
    __shared__ float tile[320];
    __shared__ float Ksh[65];
    int t0 = blockIdx.x * 256;
    int b = blockIdx.y;
    for (int i = threadIdx.x; i < 320; i += 256) {
        int tt = t0 - 32 + i;
        float v = 0.f;
        if (tt >= 0 && tt < TARLEN) {
            int ghi = min(511, tt >> 9);
            int glo = max(0, (tt - 1536) >> 9);
            float s = 0.f;
            for (int g = glo; g <= ghi; ++g) {
                int n = tt - (g << 9);
                s += aw[((size_t)(b * 512 + g) << 11) + n];
            }
            v = s / (float)(ghi - glo + 1);
        }
        tile[i] = v;
    }
    if (threadIdx.x < 65) {
        float k = 0.f;
#pragma unroll
        for (int c = 0; c < 5; ++c) k += ppw[c * 65 + threadIdx.x];
        Ksh[threadIdx.x] = k;
    }
    __syncthreads();
    float y = ppb[0];
#pragma unroll
    for (int j = 0; j < 65; ++j) y = fmaf(Ksh[j], tile[threadIdx.x + j], y);
    int t = t0 + threadIdx.x;
    out[(size_t)b * TARLEN + t] = y / (1.f + fabsf(y));
}

// ---------------- launch --------------------------------------------------
extern "C" void kernel_launch(void* const* d_in, const int* in_sizes, int n_in,
                              void* d_out, int out_size, void* d_ws, size_t ws_size,
                              hipStream_t stream) {
    const float* z    = (const float*)d_in[0];
    const float* w0   = (const float*)d_in[1];
    const float* b0   = (const float*)d_in[2];
    const float* g0   = (const float*)d_in[3];
    const float* be0  = (const float*)d_in[4];
    const float* w1   = (const float*)d_in[5];
    const float* b1   = (const float*)d_in[6];
    const float* g1   = (const float*)d_in[7];
    const float* be1  = (const float*)d_in[8];
    const float* w2   = (const float*)d_in[9];
    const float* b2   = (const float*)d_in[10];
    const float* g2   = (const float*)d_in[11];
    const float* be2  = (const float*)d_in[12];
    const float* w3   = (const float*)d_in[13];
    const float* b3   = (const float*)d_in[14];
    const float* ppw  = (const float*)d_in[15];
    const float* ppb  = (const float*)d_in[16];
    const float* noise= (const float*)d_in[17];
    float* out = (float*)d_out;
    float* ws = (float*)d_ws;

    // workspace (floats), total ~30.44M = 121.8 MiB
    float* h0   = ws;                  // 8192*512
    float* ps   = ws + 4194304;        // 64*512
    float* pq   = ps + 32768;          // 64*512
    float* mean = pq + 32768;          // 512
    float* rstd = mean + 512;          // 512
    float* B3tf = rstd + 512;          // 1152*1536 bf16 = 884736 f
    float* fcs  = B3tf + 884736;       // 8192*1040 f (h1 aliases start)
    float* awf  = fcs + 8519680;       // 8192*2048 f (A2 aliases start)
    ushort* B3t = (ushort*)B3tf;
    ushort* A2  = (ushort*)awf;
    float* h1 = fcs;   // dead before fcs written
    float* h2 = h0;    // h0 dead after its prep
    float* aw = awf;   // A2 dead before fft writes

    dim3 blk(256);
    dim3 gblk(512);
    // layer 0: h0 = z @ w0 + b0 (+ fused col stats)
    prep_act_k<7, false><<<dim3(1024), blk, 0, stream>>>(z, nullptr, nullptr, nullptr, nullptr, A2);
    prepw_k<<<dim3(4, 16), blk, 0, stream>>>(w0, B3t, 128, 512, 384);
    mfma_gemm<0><<<dim3(4, 64), gblk, 0, stream>>>(A2, B3t, b0, h0, 384, 256, 512, 512, ps, pq);
    colstats_final<<<dim3(2), blk, 0, stream>>>(ps, pq, mean, rstd);
    // layer 1
    prep_act_k<9, true><<<dim3(4096), blk, 0, stream>>>(h0, mean, rstd, g0, be0, A2);
    prepw_k<<<dim3(16, 16), blk, 0, stream>>>(w1, B3t, 512, 512, 1536);
    mfma_gemm<0><<<dim3(4, 64), gblk, 0, stream>>>(A2, B3t, b1, h1, 1536, 1024, 512, 512, ps, pq);
    colstats_final<<<dim3(2), blk, 0, stream>>>(ps, pq, mean, rstd);
    // layer 2
    prep_act_k<9, true><<<dim3(4096), blk, 0, stream>>>(h1, mean, rstd, g1, be1, A2);
    prepw_k<<<dim3(16, 16), blk, 0, stream>>>(w2, B3t, 512, 512, 1536);
    mfma_gemm<0><<<dim3(4, 64), gblk, 0, stream>>>(A2, B3t, b2, h2, 1536, 1024, 512, 512, ps, pq);
    colstats_final<<<dim3(2), blk, 0, stream>>>(ps, pq, mean, rstd);
    // layer 3: fcs = mod_sigmoid(...) [8192][1040], valid cols 1025
    prep_act_k<9, true><<<dim3(4096), blk, 0, stream>>>(h2, mean, rstd, g2, be2, A2);
    prepw_k<<<dim3(16, 36), blk, 0, stream>>>(w3, B3t, 512, 1025, 1536);
    mfma_gemm<1><<<dim3(9, 64), gblk, 0, stream>>>(A2, B3t, b3, fcs, 1536, 1024, 1025, 1040, nullptr, nullptr);
    // spectral filtering + window (fused)
    fft_filter_kernel<<<dim3(8192), blk, 0, stream>>>(noise, fcs, aw);
    // fused OLA + post conv + softsign
    ola_ppconv_kernel<<<dim3(1030, 16), blk, 0, stream>>>(aw, ppw, ppb, out);
    (void)in_sizes; (void)n_in; (void)out_size; (void)ws_size;
}

// Round 5
// 243.714 us; speedup vs baseline: 2.4971x; 1.1009x over previous
//
#include <hip/hip_runtime.h>
#include <hip/hip_bf16.h>
#include <math.h>

#define TARLEN 263680
#define POWEXP 2.302585092994046f  // ln(10)
#define PC(i) ((i) + ((i) >> 3))   // complex-unit LDS padding (1 per 8)

typedef __attribute__((ext_vector_type(8))) short bf16x8;
typedef __attribute__((ext_vector_type(4))) float f32x4;

__device__ __forceinline__ void gload16(const void* g, void* l) {
    __builtin_amdgcn_global_load_lds((const __attribute__((address_space(1))) void*)g,
                                     (__attribute__((address_space(3))) void*)l, 16, 0, 0);
}

__device__ __forceinline__ float norm_lrelu(float a, float m, float rs, float g, float b) {
    float x = (a - m) * rs * g + b;
    return x >= 0.f ? x : 0.2f * x;
}

__device__ __forceinline__ void split_bf16(float x, ushort& hi, ushort& lo) {
    __hip_bfloat16 h = __float2bfloat16(x);
    hi = *reinterpret_cast<ushort*>(&h);
    float rem = x - __bfloat162float(h);
    __hip_bfloat16 l = __float2bfloat16(rem);
    lo = *reinterpret_cast<ushort*>(&l);
}

// ============ GEMM shape A: 128x128 tile, 512 thr, 8 waves of 64x32 =========
// 2-term split: C = (Ahi+Alo) @ Bhi. A2=[Ahi|Alo] ([M][K2] bf16), B2t=[N][K2]
// rows=[Bhi Bhi]. LDS k-chunk XOR swizzle: phys = log ^ ((row>>1)&3), applied
// on the global source (linear LDS dest, rule both-sides-or-neither) and on
// the ds_read chunk (folds into per-lane constant). Fused BN column stats.
__global__ __launch_bounds__(512) void gemm8(
    const ushort* __restrict__ A2, const ushort* __restrict__ B2t,
    const float* __restrict__ bias, float* __restrict__ C,
    int K2, float* __restrict__ ps, float* __restrict__ pq)
{
    __shared__ ushort As[2][4096];  // [128][32]
    __shared__ ushort Bs[2][4096];  // [128][32]
    __shared__ float sred[8][2][16];
    __shared__ float qred[8][2][16];
    const int tid = threadIdx.x;
    const int lane = tid & 63;
    const int wid = tid >> 6;
    // bijective XCD swizzle (nwg % 8 == 0)
    const int nwg = gridDim.x * gridDim.y;
    const int bid = blockIdx.y * gridDim.x + blockIdx.x;
    const int q8 = nwg >> 3;
    const int swzb = (bid & 7) * q8 + (bid >> 3);
    const int bx = swzb % gridDim.x;
    const int by = swzb / gridDim.x;
    const int m0 = by * 128;
    const int n0 = bx * 128;
    const int NT = K2 >> 5;

    f32x4 acc[4][2];
#pragma unroll
    for (int m = 0; m < 4; ++m)
#pragma unroll
        for (int n = 0; n < 2; ++n)
            acc[m][n] = (f32x4){0.f, 0.f, 0.f, 0.f};

    const int srow = tid >> 2;                              // 0..127
    const int scol = (((tid & 3) ^ ((tid >> 3) & 3)) << 3); // swizzled src chunk

    auto stage = [&](int t, int buf) {
        const int k0 = t << 5;
        gload16(A2 + (size_t)(m0 + srow) * K2 + k0 + scol, &As[buf][tid * 8]);
        gload16(B2t + (size_t)(n0 + srow) * K2 + k0 + scol, &Bs[buf][tid * 8]);
    };

    const int lr = lane & 15;
    const int sw8 = (((lane >> 4) ^ ((lane >> 1) & 3)) << 3);  // swizzled read chunk
    const int wm0 = (wid >> 2) * 64;
    const int wn0 = (wid & 3) * 32;

    stage(0, 0);
    __syncthreads();
    for (int t = 0; t < NT; ++t) {
        int cur = t & 1;
        if (t + 1 < NT) stage(t + 1, cur ^ 1);
        const ushort* as = As[cur];
        const ushort* bs = Bs[cur];
        bf16x8 af[4], bfv[2];
#pragma unroll
        for (int m = 0; m < 4; ++m)
            af[m] = *reinterpret_cast<const bf16x8*>(&as[(wm0 + m * 16 + lr) * 32 + sw8]);
#pragma unroll
        for (int n = 0; n < 2; ++n)
            bfv[n] = *reinterpret_cast<const bf16x8*>(&bs[(wn0 + n * 16 + lr) * 32 + sw8]);
#pragma unroll
        for (int m = 0; m < 4; ++m)
#pragma unroll
            for (int n = 0; n < 2; ++n)
                acc[m][n] = __builtin_amdgcn_mfma_f32_16x16x32_bf16(af[m], bfv[n], acc[m][n], 0, 0, 0);
        __syncthreads();
    }

    // epilogue: C/D layout col=lane&15, row=(lane>>4)*4+reg. All cols valid (N=512).
    const int cr = (lane >> 4) << 2;
    const int cc = lane & 15;
    float sacc[2] = {0.f, 0.f}, qacc[2] = {0.f, 0.f};
#pragma unroll
    for (int m = 0; m < 4; ++m) {
#pragma unroll
        for (int n = 0; n < 2; ++n) {
            int gcol = n0 + wn0 + n * 16 + cc;
            float bv = bias[gcol];
            int grow = m0 + wm0 + m * 16 + cr;
#pragma unroll
            for (int j = 0; j < 4; ++j) {
                float v = acc[m][n][j] + bv;
                sacc[n] += v;
                qacc[n] += v * v;
                C[(size_t)(grow + j) * 512 + gcol] = v;
            }
        }
    }
#pragma unroll
    for (int n = 0; n < 2; ++n) {
        float s = sacc[n], q = qacc[n];
        s += __shfl_xor(s, 16); q += __shfl_xor(q, 16);
        s += __shfl_xor(s, 32); q += __shfl_xor(q, 32);
        if (lane < 16) { sred[wid][n][lane] = s; qred[wid][n][lane] = q; }
    }
    __syncthreads();
    if (tid < 128) {
        int wn_ = tid >> 5, n_ = (tid >> 4) & 1, cc_ = tid & 15;
        float s = sred[wn_][n_][cc_] + sred[4 + wn_][n_][cc_];
        float q = qred[wn_][n_][cc_] + qred[4 + wn_][n_][cc_];
        int col = n0 + wn_ * 32 + n_ * 16 + cc_;
        ps[(size_t)by * 512 + col] = s;
        pq[(size_t)by * 512 + col] = q;
    }
}

// ============ GEMM shape B (m97): 128x128, 256 thr, 4 waves of 64x64 ========
// 3-term split: Ahi*Bhi + Alo*Bhi + Ahi*Blo. B3t=[N][3K] rows=[Bhi Bhi Blo].
// mod_sigmoid epilogue. Same LDS swizzle scheme.
__global__ __launch_bounds__(256) void gemm4(
    const ushort* __restrict__ A2, const ushort* __restrict__ B3t,
    const float* __restrict__ bias, float* __restrict__ C,
    int K3, int K2, int Nvalid, int ldc)
{
    __shared__ ushort As[2][4096];  // [128][32]
    __shared__ ushort Bs[2][4096];  // [128][32]
    const int tid = threadIdx.x;
    const int lane = tid & 63;
    const int wid = tid >> 6;
    const int nwg = gridDim.x * gridDim.y;
    const int bid = blockIdx.y * gridDim.x + blockIdx.x;
    const int q8 = nwg >> 3;
    const int swzb = (bid & 7) * q8 + (bid >> 3);
    const int bx = swzb % gridDim.x;
    const int by = swzb / gridDim.x;
    const int m0 = by * 128;
    const int n0 = bx * 128;
    const int NT = K3 >> 5;

    f32x4 acc[4][4];
#pragma unroll
    for (int m = 0; m < 4; ++m)
#pragma unroll
        for (int n = 0; n < 4; ++n)
            acc[m][n] = (f32x4){0.f, 0.f, 0.f, 0.f};

    auto stage = [&](int t, int buf) {
        const int k0 = t << 5;
        const int ka = (k0 < K2) ? k0 : (k0 - K2);
#pragma unroll
        for (int i = 0; i < 2; ++i) {
            int g = i * 256 + tid;
            int row = g >> 2;
            int sc = (((g & 3) ^ ((g >> 3) & 3)) << 3);
            gload16(A2 + (size_t)(m0 + row) * K2 + ka + sc, &As[buf][g * 8]);
            gload16(B3t + (size_t)(n0 + row) * K3 + k0 + sc, &Bs[buf][g * 8]);
        }
    };

    const int lr = lane & 15;
    const int sw8 = (((lane >> 4) ^ ((lane >> 1) & 3)) << 3);
    const int wm0 = (wid >> 1) * 64;
    const int wn0 = (wid & 1) * 64;

    stage(0, 0);
    __syncthreads();
    for (int t = 0; t < NT; ++t) {
        int cur = t & 1;
        if (t + 1 < NT) stage(t + 1, cur ^ 1);
        const ushort* as = As[cur];
        const ushort* bs = Bs[cur];
        bf16x8 af[4], bfv[4];
#pragma unroll
        for (int m = 0; m < 4; ++m)
            af[m] = *reinterpret_cast<const bf16x8*>(&as[(wm0 + m * 16 + lr) * 32 + sw8]);
#pragma unroll
        for (int n = 0; n < 4; ++n)
            bfv[n] = *reinterpret_cast<const bf16x8*>(&bs[(wn0 + n * 16 + lr) * 32 + sw8]);
#pragma unroll
        for (int m = 0; m < 4; ++m)
#pragma unroll
            for (int n = 0; n < 4; ++n)
                acc[m][n] = __builtin_amdgcn_mfma_f32_16x16x32_bf16(af[m], bfv[n], acc[m][n], 0, 0, 0);
        __syncthreads();
    }

    const int cr = (lane >> 4) << 2;
    const int cc = lane & 15;
#pragma unroll
    for (int m = 0; m < 4; ++m) {
#pragma unroll
        for (int n = 0; n < 4; ++n) {
            int gcol = n0 + wn0 + n * 16 + cc;
            if (gcol < Nvalid) {
                float bv = bias[gcol];
                int grow = m0 + wm0 + m * 16 + cr;
#pragma unroll
                for (int j = 0; j < 4; ++j) {
                    float v = acc[m][n][j] + bv;
                    float sg = 1.f / (1.f + __expf(-v));
                    v = 2.f * __expf(POWEXP * __logf(sg)) + 1e-7f;
                    C[(size_t)(grow + j) * ldc + gcol] = v;
                }
            }
        }
    }
}

// ---------------- prep: activations -> BN+LeakyReLU -> hi/lo bf16 ---------
template<int KSH, bool NORM>
__global__ __launch_bounds__(256) void prep_act_k(
    const float* __restrict__ H, const float* __restrict__ mean,
    const float* __restrict__ rstd, const float* __restrict__ gamma,
    const float* __restrict__ beta, ushort* __restrict__ A2)
{
    const int K = 1 << KSH;
    int idx = (blockIdx.x * 256 + threadIdx.x) << 2;
    int col = idx & (K - 1);
    int row = idx >> KSH;
    float4 h = *reinterpret_cast<const float4*>(&H[idx]);
    float x[4] = {h.x, h.y, h.z, h.w};
    if (NORM) {
        float4 mm = *reinterpret_cast<const float4*>(&mean[col]);
        float4 rs = *reinterpret_cast<const float4*>(&rstd[col]);
        float4 gg = *reinterpret_cast<const float4*>(&gamma[col]);
        float4 bb = *reinterpret_cast<const float4*>(&beta[col]);
        x[0] = norm_lrelu(x[0], mm.x, rs.x, gg.x, bb.x);
        x[1] = norm_lrelu(x[1], mm.y, rs.y, gg.y, bb.y);
        x[2] = norm_lrelu(x[2], mm.z, rs.z, gg.z, bb.z);
        x[3] = norm_lrelu(x[3], mm.w, rs.w, gg.w, bb.w);
    }
    ushort4 hv, lv;
    split_bf16(x[0], hv.x, lv.x);
    split_bf16(x[1], hv.y, lv.y);
    split_bf16(x[2], hv.z, lv.z);
    split_bf16(x[3], hv.w, lv.w);
    ushort* dst = &A2[(size_t)row * (2 * K) + col];
    *reinterpret_cast<ushort4*>(dst) = hv;
    *reinterpret_cast<ushort4*>(dst + K) = lv;
}

// ---------------- prep: weights -> transpose + hi(/lo) split --------------
// Bt row n = [hi(w[:,n]) hi(w[:,n]) (lo(w[:,n]) if writeLo)], row stride K3.
__global__ __launch_bounds__(256) void prepw_k(
    const float* __restrict__ w, ushort* __restrict__ Bt, int K, int N, int K3,
    int writeLo)
{
    __shared__ float tile[32][33];
    int k0 = blockIdx.x * 32, n0 = blockIdx.y * 32;
    int tx = threadIdx.x & 31, ty = threadIdx.x >> 5;  // 32 x 8
#pragma unroll
    for (int r = 0; r < 4; ++r) {
        int k = k0 + ty + r * 8;
        int n = n0 + tx;
        tile[ty + r * 8][tx] = (n < N) ? w[(size_t)k * N + n] : 0.f;
    }
    __syncthreads();
#pragma unroll
    for (int r = 0; r < 4; ++r) {
        int n = n0 + ty + r * 8;
        int k = k0 + tx;
        float x = tile[tx][ty + r * 8];
        ushort hi, lo;
        split_bf16(x, hi, lo);
        size_t base = (size_t)n * K3;
        Bt[base + k] = hi;
        Bt[base + K + k] = hi;
        if (writeLo) Bt[base + 2 * K + k] = lo;
    }
}

// ---------------- BN stats final reduce (64 row-block partials) -----------
__global__ __launch_bounds__(256) void colstats_final(
    const float* __restrict__ ps, const float* __restrict__ pq,
    float* __restrict__ mean, float* __restrict__ rstd)
{
    int c = blockIdx.x * 256 + threadIdx.x;
    float s = 0.f, q = 0.f;
    for (int rg = 0; rg < 64; ++rg) { s += ps[rg * 512 + c]; q += pq[rg * 512 + c]; }
    float m = s * (1.f / 8192.f);
    float v = q * (1.f / 8192.f) - m * m;
    mean[c] = m;
    rstd[c] = rsqrtf(v + 1e-5f);
}

// ---------------- Stockham radix-4 FFT, float2 LDS, 256 threads -----------
__device__ __forceinline__ float2 cmul(float2 a, float c, float s) {
    return make_float2(a.x * c - a.y * s, a.x * s + a.y * c);
}

template<bool INV, int L>
__device__ __forceinline__ void stk_stage(
    const float2* __restrict__ s, float2* __restrict__ d, int t)
{
    int k = t & (L - 1);
    float2 x0 = s[PC(t)];
    float2 x1 = s[PC(t + 256)];
    float2 x2 = s[PC(t + 512)];
    float2 x3 = s[PC(t + 768)];
    if (L > 1) {
        float th = (INV ? 2.0f : -2.0f) * (float)M_PI * (float)k / (float)(4 * L);
        float s1, c1; __sincosf(th, &s1, &c1);
        float c2 = c1 * c1 - s1 * s1, s2 = 2.f * c1 * s1;
        float c3 = c2 * c1 - s2 * s1, s3 = s2 * c1 + c2 * s1;
        x1 = cmul(x1, c1, s1);
        x2 = cmul(x2, c2, s2);
        x3 = cmul(x3, c3, s3);
    }
    float2 a = make_float2(x0.x + x2.x, x0.y + x2.y);
    float2 b = make_float2(x0.x - x2.x, x0.y - x2.y);
    float2 c = make_float2(x1.x + x3.x, x1.y + x3.y);
    float2 e = make_float2(x1.x - x3.x, x1.y - x3.y);
    int db = ((t - k) << 2) + k;
    d[PC(db)]         = make_float2(a.x + c.x, a.y + c.y);
    d[PC(db + 2 * L)] = make_float2(a.x - c.x, a.y - c.y);
    if (!INV) {
        d[PC(db + L)]     = make_float2(b.x + e.y, b.y - e.x);
        d[PC(db + 3 * L)] = make_float2(b.x - e.y, b.y + e.x);
    } else {
        d[PC(db + L)]     = make_float2(b.x - e.y, b.y + e.x);
        d[PC(db + 3 * L)] = make_float2(b.x + e.y, b.y - e.x);
    }
}

// audio = irfft( rfft(noise_row) * H ), H[k] = (-1)^k*(0.5 fc[k]+0.25 fc[k-1]+0.25 fc[k+1])
// (analytic collapse of rfft(fftshift(irfft(fc)*FW))). 1/1024 folded into H.
// OLA window derived from the final-stage twiddle (no extra sincos).
__global__ __launch_bounds__(256) void fft_filter_kernel(
    const float* __restrict__ noise, const float* __restrict__ fcs, float* __restrict__ aw)
{
    __shared__ float2 X[1152], Y[1152];
    __shared__ float F[1025];
    const int tid = threadIdx.x;
    const int r = blockIdx.x;

    const float2* nrow = reinterpret_cast<const float2*>(noise + ((size_t)r << 11));
    for (int i = tid; i < 1025; i += 256) F[i] = fcs[(size_t)r * 1040 + i];
    {
        // forward stage L=1 fused with global load (pack z[n]=x[2n]+i x[2n+1])
        float2 x0 = nrow[tid], x1 = nrow[tid + 256], x2 = nrow[tid + 512], x3 = nrow[tid + 768];
        float2 a = make_float2(x0.x + x2.x, x0.y + x2.y);
        float2 b = make_float2(x0.x - x2.x, x0.y - x2.y);
        float2 c = make_float2(x1.x + x3.x, x1.y + x3.y);
        float2 e = make_float2(x1.x - x3.x, x1.y - x3.y);
        int db = tid << 2;
        Y[PC(db)]     = make_float2(a.x + c.x, a.y + c.y);
        Y[PC(db + 1)] = make_float2(b.x + e.y, b.y - e.x);
        Y[PC(db + 2)] = make_float2(a.x - c.x, a.y - c.y);
        Y[PC(db + 3)] = make_float2(b.x - e.y, b.y + e.x);
    }
    __syncthreads();
    stk_stage<false, 4>(Y, X, tid);   __syncthreads();
    stk_stage<false, 16>(X, Y, tid);  __syncthreads();
    stk_stage<false, 64>(Y, X, tid);  __syncthreads();
    stk_stage<false, 256>(X, Y, tid); __syncthreads();
    // forward result in Y (natural order)

    // unpack real FFT, apply H (scaled by 1/1024), repack; read Y, write X
    const float INV1024 = 1.0f / 1024.0f;
    auto proc = [&](int k, float c, float s) {
        int k2 = (1024 - k) & 1023;
        float2 za = Y[PC(k)], zb = Y[PC(k2)];
        float Fer = 0.5f * (za.x + zb.x), Fei = 0.5f * (za.y - zb.y);
        float For = 0.5f * (za.y + zb.y), Foi = 0.5f * (zb.x - za.x);
        float wFr = c * For - s * Foi;
        float wFi = c * Foi + s * For;
        float Xkr = Fer + wFr, Xki = Fei + wFi;
        float Xbr = Fer - wFr, Xbi = wFi - Fei;
        float Hk, Hb;
        {
            float cl = (k == 0) ? F[1] : F[k - 1];
            float crr = (k == 1024) ? F[1023] : F[k + 1];
            float h = 0.5f * F[k] + 0.25f * (cl + crr);
            Hk = ((k & 1) ? -h : h) * INV1024;
        }
        {
            int kb = 1024 - k;
            float cl = (kb == 0) ? F[1] : F[kb - 1];
            float crr = (kb == 1024) ? F[1023] : F[kb + 1];
            float h = 0.5f * F[kb] + 0.25f * (cl + crr);
            Hb = ((kb & 1) ? -h : h) * INV1024;
        }
        float Ykr = Hk * Xkr, Yki = Hk * Xki;
        float Ybr = Hb * Xbr, Ybi = Hb * Xbi;
        if (k == 0) {
            X[PC(0)] = make_float2(0.5f * (Ykr + Ybr), 0.5f * (Ykr - Ybr));
        } else {
            float Ger = 0.5f * (Ykr + Ybr), Gei = 0.5f * (Yki - Ybi);
            float Sgr = 0.5f * (Ykr - Ybr), Sgi = 0.5f * (Yki + Ybi);
            float wpr = c, wpi = -s;
            float Gor = wpr * Sgr - wpi * Sgi;
            float Goi = wpr * Sgi + wpi * Sgr;
            X[PC(k)]  = make_float2(Ger - Goi, Gei + Gor);
            X[PC(k2)] = make_float2(Ger + Goi, Gor - Gei);
        }
    };
    {
        float s0, c0;
        __sincosf((float)(-M_PI / 1024.0) * tid, &s0, &c0);
        proc(tid, c0, s0);
        const float RT = 0.70710678118654752f;  // e^{-i pi/4}
        float c1 = (c0 + s0) * RT, s1 = (s0 - c0) * RT;
        proc(tid + 256, c1, s1);
        if (tid == 0) proc(512, 0.f, -1.f);
    }
    __syncthreads();

    stk_stage<true, 1>(X, Y, tid);  __syncthreads();
    stk_stage<true, 4>(Y, X, tid);  __syncthreads();
    stk_stage<true, 16>(X, Y, tid); __syncthreads();
    stk_stage<true, 64>(Y, X, tid); __syncthreads();

    // inverse final stage (L=256) fused with OLA window + store;
    // window cos(2*pi*n/1024) at n=t+256q derived from the twiddle (c1,s1).
    {
        const int g = r & 511;
        float2* awrow = reinterpret_cast<float2*>(aw + ((size_t)r << 11));
        int t = tid;
        float2 x0 = X[PC(t)], x1 = X[PC(t + 256)], x2 = X[PC(t + 512)], x3 = X[PC(t + 768)];
        float th = (float)(2.0 * M_PI / 1024.0) * t;
        float s1, c1; __sincosf(th, &s1, &c1);
        float c2 = c1 * c1 - s1 * s1, s2 = 2.f * c1 * s1;
        float c3 = c2 * c1 - s2 * s1, s3 = s2 * c1 + c2 * s1;
        x1 = cmul(x1, c1, s1);
        x2 = cmul(x2, c2, s2);
        x3 = cmul(x3, c3, s3);
        float2 a = make_float2(x0.x + x2.x, x0.y + x2.y);
        float2 b = make_float2(x0.x - x2.x, x0.y - x2.y);
        float2 c = make_float2(x1.x + x3.x, x1.y + x3.y);
        float2 e = make_float2(x1.x - x3.x, x1.y - x3.y);
        float2 o[4];
        o[0] = make_float2(a.x + c.x, a.y + c.y);
        o[1] = make_float2(b.x - e.y, b.y + e.x);
        o[2] = make_float2(a.x - c.x, a.y - c.y);
        o[3] = make_float2(b.x + e.y, b.y - e.x);
        float cq[4] = {c1, -s1, -c1, s1};
        float sq[4] = {s1, c1, -s1, -c1};
        const float COSD = 0.99999529380958f;   // cos(pi/1024)
        const float SIND = 0.00306795676296f;   // sin(pi/1024)
#pragma unroll
        for (int q = 0; q < 4; ++q) {
            int n = t + 256 * q;
            float w0, w1;
            bool edge = (g == 0 && q < 2) || (g == 511 && q >= 2);
            if (edge) { w0 = 1.f; w1 = 1.f; }
            else {
                w0 = 0.5f - 0.5f * cq[q];
                w1 = 0.5f - 0.5f * (cq[q] * COSD - sq[q] * SIND);
            }
            awrow[n] = make_float2(o[q].x * w0, o[q].y * w1);
        }
    }
}

// ---------------- fused OLA gather + 65-tap conv + softsign ---------------
__global__ __launch_bounds__(256) void ola_ppconv_kernel(
    const float* __restrict__ aw, const float* __restrict__ ppw,
    const float* __restrict__ ppb, float* __restrict__ out)
{
    __shared__ float tile[320];
    __shared__ float Ksh[65];
    int t0 = blockIdx.x * 256;
    int b = blockIdx.y;
    for (int i = threadIdx.x; i < 320; i += 256) {
        int tt = t0 - 32 + i;
        float v = 0.f;
        if (tt >= 0 && tt < TARLEN) {
            int ghi = min(511, tt >> 9);
            int glo = max(0, (tt - 1536) >> 9);
            float s = 0.f;
            for (int g = glo; g <= ghi; ++g) {
                int n = tt - (g << 9);
                s += aw[((size_t)(b * 512 + g) << 11) + n];
            }
            v = s / (float)(ghi - glo + 1);
        }
        tile[i] = v;
    }
    if (threadIdx.x < 65) {
        float k = 0.f;
#pragma unroll
        for (int c = 0; c < 5; ++c) k += ppw[c * 65 + threadIdx.x];
        Ksh[threadIdx.x] = k;
    }
    __syncthreads();
    float y = ppb[0];
#pragma unroll
    for (int j = 0; j < 65; ++j) y = fmaf(Ksh[j], tile[threadIdx.x + j], y);
    int t = t0 + threadIdx.x;
    out[(size_t)b * TARLEN + t] = y / (1.f + fabsf(y));
}

// ---------------- launch --------------------------------------------------
extern "C" void kernel_launch(void* const* d_in, const int* in_sizes, int n_in,
                              void* d_out, int out_size, void* d_ws, size_t ws_size,
                              hipStream_t stream) {
    const float* z    = (const float*)d_in[0];
    const float* w0   = (const float*)d_in[1];
    const float* b0   = (const float*)d_in[2];
    const float* g0   = (const float*)d_in[3];
    const float* be0  = (const float*)d_in[4];
    const float* w1   = (const float*)d_in[5];
    const float* b1   = (const float*)d_in[6];
    const float* g1   = (const float*)d_in[7];
    const float* be1  = (const float*)d_in[8];
    const float* w2   = (const float*)d_in[9];
    const float* b2   = (const float*)d_in[10];
    const float* g2   = (const float*)d_in[11];
    const float* be2  = (const float*)d_in[12];
    const float* w3   = (const float*)d_in[13];
    const float* b3   = (const float*)d_in[14];
    const float* ppw  = (const float*)d_in[15];
    const float* ppb  = (const float*)d_in[16];
    const float* noise= (const float*)d_in[17];
    float* out = (float*)d_out;
    float* ws = (float*)d_ws;

    // workspace (floats)
    float* h0   = ws;                  // 8192*512
    float* ps   = ws + 4194304;        // 64*512
    float* pq   = ps + 32768;          // 64*512
    float* mean = pq + 32768;          // 512
    float* rstd = mean + 512;          // 512
    float* Btf  = rstd + 512;          // up to 1152*1536 bf16 = 884736 f
    float* fcs  = Btf + 884736;        // 8192*1040 f (h1 aliases start)
    float* awf  = fcs + 8519680;       // 8192*2048 f (A2 aliases start)
    ushort* Bt  = (ushort*)Btf;
    ushort* A2  = (ushort*)awf;
    float* h1 = fcs;   // dead before fcs written
    float* h2 = h0;    // h0 dead after its prep
    float* aw = awf;   // A2 dead before fft writes

    dim3 blk(256);
    dim3 gblk(512);
    // layer 0: h0 = z @ w0 + b0 (+ fused col stats); 2-term, K2=256
    prep_act_k<7, false><<<dim3(1024), blk, 0, stream>>>(z, nullptr, nullptr, nullptr, nullptr, A2);
    prepw_k<<<dim3(4, 16), blk, 0, stream>>>(w0, Bt, 128, 512, 256, 0);
    gemm8<<<dim3(4, 64), gblk, 0, stream>>>(A2, Bt, b0, h0, 256, ps, pq);
    colstats_final<<<dim3(2), blk, 0, stream>>>(ps, pq, mean, rstd);
    // layer 1: 2-term, K2=1024
    prep_act_k<9, true><<<dim3(4096), blk, 0, stream>>>(h0, mean, rstd, g0, be0, A2);
    prepw_k<<<dim3(16, 16), blk, 0, stream>>>(w1, Bt, 512, 512, 1024, 0);
    gemm8<<<dim3(4, 64), gblk, 0, stream>>>(A2, Bt, b1, h1, 1024, ps, pq);
    colstats_final<<<dim3(2), blk, 0, stream>>>(ps, pq, mean, rstd);
    // layer 2: 2-term
    prep_act_k<9, true><<<dim3(4096), blk, 0, stream>>>(h1, mean, rstd, g1, be1, A2);
    prepw_k<<<dim3(16, 16), blk, 0, stream>>>(w2, Bt, 512, 512, 1024, 0);
    gemm8<<<dim3(4, 64), gblk, 0, stream>>>(A2, Bt, b2, h2, 1024, ps, pq);
    colstats_final<<<dim3(2), blk, 0, stream>>>(ps, pq, mean, rstd);
    // layer 3: 3-term (K3=1536), fcs = mod_sigmoid(...) [8192][1040], 1025 valid
    prep_act_k<9, true><<<dim3(4096), blk, 0, stream>>>(h2, mean, rstd, g2, be2, A2);
    prepw_k<<<dim3(16, 36), blk, 0, stream>>>(w3, Bt, 512, 1025, 1536, 1);
    gemm4<<<dim3(9, 64), blk, 0, stream>>>(A2, Bt, b3, fcs, 1536, 1024, 1025, 1040);
    // spectral filtering + window (fused)
    fft_filter_kernel<<<dim3(8192), blk, 0, stream>>>(noise, fcs, aw);
    // fused OLA + post conv + softsign
    ola_ppconv_kernel<<<dim3(1030, 16), blk, 0, stream>>>(aw, ppw, ppb, out);
    (void)in_sizes; (void)n_in; (void)out_size; (void)ws_size;
}

// Round 6
// 229.567 us; speedup vs baseline: 2.6510x; 1.0616x over previous
//
#include <hip/hip_runtime.h>
#include <hip/hip_bf16.h>
#include <math.h>

#define TARLEN 263680
#define POWEXP 2.302585092994046f  // ln(10)
#define PC(i) ((i) + ((i) >> 3))   // complex-unit LDS padding (1 per 8)

typedef __attribute__((ext_vector_type(8))) short bf16x8;
typedef __attribute__((ext_vector_type(4))) float f32x4;

__device__ __forceinline__ void gload16(const void* g, void* l) {
    __builtin_amdgcn_global_load_lds((const __attribute__((address_space(1))) void*)g,
                                     (__attribute__((address_space(3))) void*)l, 16, 0, 0);
}

__device__ __forceinline__ float norm_lrelu(float a, float m, float rs, float g, float b) {
    float x = (a - m) * rs * g + b;
    return x >= 0.f ? x : 0.2f * x;
}

__device__ __forceinline__ void split_bf16(float x, ushort& hi, ushort& lo) {
    __hip_bfloat16 h = __float2bfloat16(x);
    hi = *reinterpret_cast<ushort*>(&h);
    float rem = x - __bfloat162float(h);
    __hip_bfloat16 l = __float2bfloat16(rem);
    lo = *reinterpret_cast<ushort*>(&l);
}

// ============ unified GEMM: 128x128 tile, 512 thr, 8 waves of 64x32 =========
// 2-term split: C = (Ahi+Alo) @ Bhi. A2=[Ahi|Alo] ([M][K2] bf16), B2t=[N][K2]
// rows=[Bhi Bhi]. LDS k-chunk XOR swizzle on both sides (conflict-free,
// verified r5: SQ_LDS_BANK_CONFLICT=0). 3-buffer deep pipeline with counted
// vmcnt(2) + raw s_barrier (T3/T4-lite): two K-steps of global_load_lds in
// flight; stage(t+2) issued AFTER barrier(t) so it can't race readers of the
// buffer it overwrites (last read at iter t-1, before barrier(t)).
// EPI==0: fused BN column stats partials. EPI==1: mod_sigmoid epilogue.
template<int EPI>
__global__ __launch_bounds__(512) void gemm8(
    const ushort* __restrict__ A2, const ushort* __restrict__ B2t,
    const float* __restrict__ bias, float* __restrict__ C,
    int K2, int Nvalid, int ldc,
    float* __restrict__ ps, float* __restrict__ pq)
{
    __shared__ ushort As[3][4096];  // [128][32] each
    __shared__ ushort Bs[3][4096];
    __shared__ float sred[8][2][16];
    __shared__ float qred[8][2][16];
    const int tid = threadIdx.x;
    const int lane = tid & 63;
    const int wid = tid >> 6;
    // bijective XCD swizzle (nwg % 8 == 0 for all our grids)
    const int nwg = gridDim.x * gridDim.y;
    const int bid = blockIdx.y * gridDim.x + blockIdx.x;
    const int q8 = nwg >> 3;
    const int swzb = (bid & 7) * q8 + (bid >> 3);
    const int bx = swzb % gridDim.x;
    const int by = swzb / gridDim.x;
    const int m0 = by * 128;
    const int n0 = bx * 128;
    const int NT = K2 >> 5;

    f32x4 acc[4][2];
#pragma unroll
    for (int m = 0; m < 4; ++m)
#pragma unroll
        for (int n = 0; n < 2; ++n)
            acc[m][n] = (f32x4){0.f, 0.f, 0.f, 0.f};

    const int srow = tid >> 2;                              // 0..127
    const int scol = (((tid & 3) ^ ((tid >> 3) & 3)) << 3); // swizzled src chunk

    auto stage = [&](int t, int buf) {
        const int k0 = t << 5;
        gload16(A2 + (size_t)(m0 + srow) * K2 + k0 + scol, &As[buf][tid * 8]);
        gload16(B2t + (size_t)(n0 + srow) * K2 + k0 + scol, &Bs[buf][tid * 8]);
    };

    const int lr = lane & 15;
    const int sw8 = (((lane >> 4) ^ ((lane >> 1) & 3)) << 3);  // swizzled read chunk
    const int wm0 = (wid >> 2) * 64;
    const int wn0 = (wid & 3) * 32;

    stage(0, 0);
    stage(1, 1);
    for (int t = 0; t < NT; ++t) {
        const int cur = t % 3;
        if (t + 2 < NT) {
            asm volatile("s_waitcnt vmcnt(2)" ::: "memory");  // own stage(t) landed
            __builtin_amdgcn_s_barrier();                     // all waves' stage(t) landed
            stage(t + 2, (t + 2) % 3);
        } else {
            asm volatile("s_waitcnt vmcnt(0)" ::: "memory");
            __builtin_amdgcn_s_barrier();
        }
        const ushort* as = As[cur];
        const ushort* bs = Bs[cur];
        bf16x8 af[4], bfv[2];
#pragma unroll
        for (int m = 0; m < 4; ++m)
            af[m] = *reinterpret_cast<const bf16x8*>(&as[(wm0 + m * 16 + lr) * 32 + sw8]);
#pragma unroll
        for (int n = 0; n < 2; ++n)
            bfv[n] = *reinterpret_cast<const bf16x8*>(&bs[(wn0 + n * 16 + lr) * 32 + sw8]);
#pragma unroll
        for (int m = 0; m < 4; ++m)
#pragma unroll
            for (int n = 0; n < 2; ++n)
                acc[m][n] = __builtin_amdgcn_mfma_f32_16x16x32_bf16(af[m], bfv[n], acc[m][n], 0, 0, 0);
    }
    __syncthreads();

    // epilogue: C/D layout col=lane&15, row=(lane>>4)*4+reg
    const int cr = (lane >> 4) << 2;
    const int cc = lane & 15;
    float sacc[2] = {0.f, 0.f}, qacc[2] = {0.f, 0.f};
#pragma unroll
    for (int m = 0; m < 4; ++m) {
#pragma unroll
        for (int n = 0; n < 2; ++n) {
            int gcol = n0 + wn0 + n * 16 + cc;
            if (EPI == 0 || gcol < Nvalid) {
                float bv = bias[gcol];
                int grow = m0 + wm0 + m * 16 + cr;
#pragma unroll
                for (int j = 0; j < 4; ++j) {
                    float v = acc[m][n][j] + bv;
                    if (EPI == 1) {
                        float sg = 1.f / (1.f + __expf(-v));
                        v = 2.f * __expf(POWEXP * __logf(sg)) + 1e-7f;
                    } else {
                        sacc[n] += v;
                        qacc[n] += v * v;
                    }
                    C[(size_t)(grow + j) * ldc + gcol] = v;
                }
            }
        }
    }
    if (EPI == 0) {
#pragma unroll
        for (int n = 0; n < 2; ++n) {
            float s = sacc[n], q = qacc[n];
            s += __shfl_xor(s, 16); q += __shfl_xor(q, 16);
            s += __shfl_xor(s, 32); q += __shfl_xor(q, 32);
            if (lane < 16) { sred[wid][n][lane] = s; qred[wid][n][lane] = q; }
        }
        __syncthreads();
        if (tid < 128) {
            int wn_ = tid >> 5, n_ = (tid >> 4) & 1, cc_ = tid & 15;
            float s = sred[wn_][n_][cc_] + sred[4 + wn_][n_][cc_];
            float q = qred[wn_][n_][cc_] + qred[4 + wn_][n_][cc_];
            int col = n0 + wn_ * 32 + n_ * 16 + cc_;
            ps[(size_t)by * 512 + col] = s;
            pq[(size_t)by * 512 + col] = q;
        }
    }
}

// ---------------- prep: activations -> BN+LeakyReLU -> hi/lo bf16 ---------
template<int KSH, bool NORM>
__global__ __launch_bounds__(256) void prep_act_k(
    const float* __restrict__ H, const float* __restrict__ mean,
    const float* __restrict__ rstd, const float* __restrict__ gamma,
    const float* __restrict__ beta, ushort* __restrict__ A2)
{
    const int K = 1 << KSH;
    int idx = (blockIdx.x * 256 + threadIdx.x) << 2;
    int col = idx & (K - 1);
    int row = idx >> KSH;
    float4 h = *reinterpret_cast<const float4*>(&H[idx]);
    float x[4] = {h.x, h.y, h.z, h.w};
    if (NORM) {
        float4 mm = *reinterpret_cast<const float4*>(&mean[col]);
        float4 rs = *reinterpret_cast<const float4*>(&rstd[col]);
        float4 gg = *reinterpret_cast<const float4*>(&gamma[col]);
        float4 bb = *reinterpret_cast<const float4*>(&beta[col]);
        x[0] = norm_lrelu(x[0], mm.x, rs.x, gg.x, bb.x);
        x[1] = norm_lrelu(x[1], mm.y, rs.y, gg.y, bb.y);
        x[2] = norm_lrelu(x[2], mm.z, rs.z, gg.z, bb.z);
        x[3] = norm_lrelu(x[3], mm.w, rs.w, gg.w, bb.w);
    }
    ushort4 hv, lv;
    split_bf16(x[0], hv.x, lv.x);
    split_bf16(x[1], hv.y, lv.y);
    split_bf16(x[2], hv.z, lv.z);
    split_bf16(x[3], hv.w, lv.w);
    ushort* dst = &A2[(size_t)row * (2 * K) + col];
    *reinterpret_cast<ushort4*>(dst) = hv;
    *reinterpret_cast<ushort4*>(dst + K) = lv;
}

// ---------------- prep: weights -> transpose + hi split -------------------
// Bt row n = [hi(w[:,n]) hi(w[:,n])], row stride K3 = 2K.
__global__ __launch_bounds__(256) void prepw_k(
    const float* __restrict__ w, ushort* __restrict__ Bt, int K, int N, int K3)
{
    __shared__ float tile[32][33];
    int k0 = blockIdx.x * 32, n0 = blockIdx.y * 32;
    int tx = threadIdx.x & 31, ty = threadIdx.x >> 5;  // 32 x 8
#pragma unroll
    for (int r = 0; r < 4; ++r) {
        int k = k0 + ty + r * 8;
        int n = n0 + tx;
        tile[ty + r * 8][tx] = (n < N) ? w[(size_t)k * N + n] : 0.f;
    }
    __syncthreads();
#pragma unroll
    for (int r = 0; r < 4; ++r) {
        int n = n0 + ty + r * 8;
        int k = k0 + tx;
        float x = tile[tx][ty + r * 8];
        __hip_bfloat16 h = __float2bfloat16(x);
        ushort hi = *reinterpret_cast<ushort*>(&h);
        size_t base = (size_t)n * K3;
        Bt[base + k] = hi;
        Bt[base + K + k] = hi;
    }
}

// ---------------- BN stats final reduce (64 row-block partials) -----------
__global__ __launch_bounds__(256) void colstats_final(
    const float* __restrict__ ps, const float* __restrict__ pq,
    float* __restrict__ mean, float* __restrict__ rstd)
{
    int c = blockIdx.x * 256 + threadIdx.x;
    float s = 0.f, q = 0.f;
    for (int rg = 0; rg < 64; ++rg) { s += ps[rg * 512 + c]; q += pq[rg * 512 + c]; }
    float m = s * (1.f / 8192.f);
    float v = q * (1.f / 8192.f) - m * m;
    mean[c] = m;
    rstd[c] = rsqrtf(v + 1e-5f);
}

// ---------------- Stockham radix-4 FFT, float2 LDS, 256 threads -----------
__device__ __forceinline__ float2 cmul(float2 a, float c, float s) {
    return make_float2(a.x * c - a.y * s, a.x * s + a.y * c);
}

template<bool INV, int L>
__device__ __forceinline__ void stk_stage(
    const float2* __restrict__ s, float2* __restrict__ d, int t)
{
    int k = t & (L - 1);
    float2 x0 = s[PC(t)];
    float2 x1 = s[PC(t + 256)];
    float2 x2 = s[PC(t + 512)];
    float2 x3 = s[PC(t + 768)];
    if (L > 1) {
        float th = (INV ? 2.0f : -2.0f) * (float)M_PI * (float)k / (float)(4 * L);
        float s1, c1; __sincosf(th, &s1, &c1);
        float c2 = c1 * c1 - s1 * s1, s2 = 2.f * c1 * s1;
        float c3 = c2 * c1 - s2 * s1, s3 = s2 * c1 + c2 * s1;
        x1 = cmul(x1, c1, s1);
        x2 = cmul(x2, c2, s2);
        x3 = cmul(x3, c3, s3);
    }
    float2 a = make_float2(x0.x + x2.x, x0.y + x2.y);
    float2 b = make_float2(x0.x - x2.x, x0.y - x2.y);
    float2 c = make_float2(x1.x + x3.x, x1.y + x3.y);
    float2 e = make_float2(x1.x - x3.x, x1.y - x3.y);
    int db = ((t - k) << 2) + k;
    d[PC(db)]         = make_float2(a.x + c.x, a.y + c.y);
    d[PC(db + 2 * L)] = make_float2(a.x - c.x, a.y - c.y);
    if (!INV) {
        d[PC(db + L)]     = make_float2(b.x + e.y, b.y - e.x);
        d[PC(db + 3 * L)] = make_float2(b.x - e.y, b.y + e.x);
    } else {
        d[PC(db + L)]     = make_float2(b.x - e.y, b.y + e.x);
        d[PC(db + 3 * L)] = make_float2(b.x + e.y, b.y - e.x);
    }
}

// audio = irfft( rfft(noise_row) * H ), H[k] = (-1)^k*(0.5 fc[k]+0.25 fc[k-1]+0.25 fc[k+1])
// (analytic collapse of rfft(fftshift(irfft(fc)*FW))). 1/1024 folded into H.
// OLA window derived from the final-stage twiddle (no extra sincos).
__global__ __launch_bounds__(256) void fft_filter_kernel(
    const float* __restrict__ noise, const float* __restrict__ fcs, float* __restrict__ aw)
{
    __shared__ float2 X[1152], Y[1152];
    __shared__ float F[1025];
    const int tid = threadIdx.x;
    const int r = blockIdx.x;

    const float2* nrow = reinterpret_cast<const float2*>(noise + ((size_t)r << 11));
    for (int i = tid; i < 1025; i += 256) F[i] = fcs[(size_t)r * 1040 + i];
    {
        // forward stage L=1 fused with global load (pack z[n]=x[2n]+i x[2n+1])
        float2 x0 = nrow[tid], x1 = nrow[tid + 256], x2 = nrow[tid + 512], x3 = nrow[tid + 768];
        float2 a = make_float2(x0.x + x2.x, x0.y + x2.y);
        float2 b = make_float2(x0.x - x2.x, x0.y - x2.y);
        float2 c = make_float2(x1.x + x3.x, x1.y + x3.y);
        float2 e = make_float2(x1.x - x3.x, x1.y - x3.y);
        int db = tid << 2;
        Y[PC(db)]     = make_float2(a.x + c.x, a.y + c.y);
        Y[PC(db + 1)] = make_float2(b.x + e.y, b.y - e.x);
        Y[PC(db + 2)] = make_float2(a.x - c.x, a.y - c.y);
        Y[PC(db + 3)] = make_float2(b.x - e.y, b.y + e.x);
    }
    __syncthreads();
    stk_stage<false, 4>(Y, X, tid);   __syncthreads();
    stk_stage<false, 16>(X, Y, tid);  __syncthreads();
    stk_stage<false, 64>(Y, X, tid);  __syncthreads();
    stk_stage<false, 256>(X, Y, tid); __syncthreads();
    // forward result in Y (natural order)

    // unpack real FFT, apply H (scaled by 1/1024), repack; read Y, write X
    const float INV1024 = 1.0f / 1024.0f;
    auto proc = [&](int k, float c, float s) {
        int k2 = (1024 - k) & 1023;
        float2 za = Y[PC(k)], zb = Y[PC(k2)];
        float Fer = 0.5f * (za.x + zb.x), Fei = 0.5f * (za.y - zb.y);
        float For = 0.5f * (za.y + zb.y), Foi = 0.5f * (zb.x - za.x);
        float wFr = c * For - s * Foi;
        float wFi = c * Foi + s * For;
        float Xkr = Fer + wFr, Xki = Fei + wFi;
        float Xbr = Fer - wFr, Xbi = wFi - Fei;
        float Hk, Hb;
        {
            float cl = (k == 0) ? F[1] : F[k - 1];
            float crr = (k == 1024) ? F[1023] : F[k + 1];
            float h = 0.5f * F[k] + 0.25f * (cl + crr);
            Hk = ((k & 1) ? -h : h) * INV1024;
        }
        {
            int kb = 1024 - k;
            float cl = (kb == 0) ? F[1] : F[kb - 1];
            float crr = (kb == 1024) ? F[1023] : F[kb + 1];
            float h = 0.5f * F[kb] + 0.25f * (cl + crr);
            Hb = ((kb & 1) ? -h : h) * INV1024;
        }
        float Ykr = Hk * Xkr, Yki = Hk * Xki;
        float Ybr = Hb * Xbr, Ybi = Hb * Xbi;
        if (k == 0) {
            X[PC(0)] = make_float2(0.5f * (Ykr + Ybr), 0.5f * (Ykr - Ybr));
        } else {
            float Ger = 0.5f * (Ykr + Ybr), Gei = 0.5f * (Yki - Ybi);
            float Sgr = 0.5f * (Ykr - Ybr), Sgi = 0.5f * (Yki + Ybi);
            float wpr = c, wpi = -s;
            float Gor = wpr * Sgr - wpi * Sgi;
            float Goi = wpr * Sgi + wpi * Sgr;
            X[PC(k)]  = make_float2(Ger - Goi, Gei + Gor);
            X[PC(k2)] = make_float2(Ger + Goi, Gor - Gei);
        }
    };
    {
        float s0, c0;
        __sincosf((float)(-M_PI / 1024.0) * tid, &s0, &c0);
        proc(tid, c0, s0);
        const float RT = 0.70710678118654752f;  // e^{-i pi/4}
        float c1 = (c0 + s0) * RT, s1 = (s0 - c0) * RT;
        proc(tid + 256, c1, s1);
        if (tid == 0) proc(512, 0.f, -1.f);
    }
    __syncthreads();

    stk_stage<true, 1>(X, Y, tid);  __syncthreads();
    stk_stage<true, 4>(Y, X, tid);  __syncthreads();
    stk_stage<true, 16>(X, Y, tid); __syncthreads();
    stk_stage<true, 64>(Y, X, tid); __syncthreads();

    // inverse final stage (L=256) fused with OLA window + store;
    // window cos(2*pi*n/1024) at n=t+256q derived from the twiddle (c1,s1).
    {
        const int g = r & 511;
        float2* awrow = reinterpret_cast<float2*>(aw + ((size_t)r << 11));
        int t = tid;
        float2 x0 = X[PC(t)], x1 = X[PC(t + 256)], x2 = X[PC(t + 512)], x3 = X[PC(t + 768)];
        float th = (float)(2.0 * M_PI / 1024.0) * t;
        float s1, c1; __sincosf(th, &s1, &c1);
        float c2 = c1 * c1 - s1 * s1, s2 = 2.f * c1 * s1;
        float c3 = c2 * c1 - s2 * s1, s3 = s2 * c1 + c2 * s1;
        x1 = cmul(x1, c1, s1);
        x2 = cmul(x2, c2, s2);
        x3 = cmul(x3, c3, s3);
        float2 a = make_float2(x0.x + x2.x, x0.y + x2.y);
        float2 b = make_float2(x0.x - x2.x, x0.y - x2.y);
        float2 c = make_float2(x1.x + x3.x, x1.y + x3.y);
        float2 e = make_float2(x1.x - x3.x, x1.y - x3.y);
        float2 o[4];
        o[0] = make_float2(a.x + c.x, a.y + c.y);
        o[1] = make_float2(b.x - e.y, b.y + e.x);
        o[2] = make_float2(a.x - c.x, a.y - c.y);
        o[3] = make_float2(b.x + e.y, b.y - e.x);
        float cq[4] = {c1, -s1, -c1, s1};
        float sq[4] = {s1, c1, -s1, -c1};
        const float COSD = 0.99999529380958f;   // cos(pi/1024)
        const float SIND = 0.00306795676296f;   // sin(pi/1024)
#pragma unroll
        for (int q = 0; q < 4; ++q) {
            int n = t + 256 * q;
            float w0, w1;
            bool edge = (g == 0 && q < 2) || (g == 511 && q >= 2);
            if (edge) { w0 = 1.f; w1 = 1.f; }
            else {
                w0 = 0.5f - 0.5f * cq[q];
                w1 = 0.5f - 0.5f * (cq[q] * COSD - sq[q] * SIND);
            }
            awrow[n] = make_float2(o[q].x * w0, o[q].y * w1);
        }
    }
}

// ---------------- fused OLA gather + 65-tap conv + softsign ---------------
__global__ __launch_bounds__(256) void ola_ppconv_kernel(
    const float* __restrict__ aw, const float* __restrict__ ppw,
    const float* __restrict__ ppb, float* __restrict__ out)
{
    __shared__ float tile[320];
    __shared__ float Ksh[65];
    int t0 = blockIdx.x * 256;
    int b = blockIdx.y;
    for (int i = threadIdx.x; i < 320; i += 256) {
        int tt = t0 - 32 + i;
        float v = 0.f;
        if (tt >= 0 && tt < TARLEN) {
            int ghi = min(511, tt >> 9);
            int glo = max(0, (tt - 1536) >> 9);
            float s = 0.f;
            for (int g = glo; g <= ghi; ++g) {
                int n = tt - (g << 9);
                s += aw[((size_t)(b * 512 + g) << 11) + n];
            }
            v = s / (float)(ghi - glo + 1);
        }
        tile[i] = v;
    }
    if (threadIdx.x < 65) {
        float k = 0.f;
#pragma unroll
        for (int c = 0; c < 5; ++c) k += ppw[c * 65 + threadIdx.x];
        Ksh[threadIdx.x] = k;
    }
    __syncthreads();
    float y = ppb[0];
#pragma unroll
    for (int j = 0; j < 65; ++j) y = fmaf(Ksh[j], tile[threadIdx.x + j], y);
    int t = t0 + threadIdx.x;
    out[(size_t)b * TARLEN + t] = y / (1.f + fabsf(y));
}

// ---------------- launch --------------------------------------------------
extern "C" void kernel_launch(void* const* d_in, const int* in_sizes, int n_in,
                              void* d_out, int out_size, void* d_ws, size_t ws_size,
                              hipStream_t stream) {
    const float* z    = (const float*)d_in[0];
    const float* w0   = (const float*)d_in[1];
    const float* b0   = (const float*)d_in[2];
    const float* g0   = (const float*)d_in[3];
    const float* be0  = (const float*)d_in[4];
    const float* w1   = (const float*)d_in[5];
    const float* b1   = (const float*)d_in[6];
    const float* g1   = (const float*)d_in[7];
    const float* be1  = (const float*)d_in[8];
    const float* w2   = (const float*)d_in[9];
    const float* b2   = (const float*)d_in[10];
    const float* g2   = (const float*)d_in[11];
    const float* be2  = (const float*)d_in[12];
    const float* w3   = (const float*)d_in[13];
    const float* b3   = (const float*)d_in[14];
    const float* ppw  = (const float*)d_in[15];
    const float* ppb  = (const float*)d_in[16];
    const float* noise= (const float*)d_in[17];
    float* out = (float*)d_out;
    float* ws = (float*)d_ws;

    // workspace (floats)
    float* h0   = ws;                  // 8192*512
    float* ps   = ws + 4194304;        // 64*512
    float* pq   = ps + 32768;          // 64*512
    float* mean = pq + 32768;          // 512
    float* rstd = mean + 512;          // 512
    float* Btf  = rstd + 512;          // up to 1152*1024 bf16 = 589824 f
    float* fcs  = Btf + 884736;        // 8192*1040 f (h1 aliases start)
    float* awf  = fcs + 8519680;       // 8192*2048 f (A2 aliases start)
    ushort* Bt  = (ushort*)Btf;
    ushort* A2  = (ushort*)awf;
    float* h1 = fcs;   // dead before fcs written
    float* h2 = h0;    // h0 dead after its prep
    float* aw = awf;   // A2 dead before fft writes

    dim3 blk(256);
    dim3 gblk(512);
    // layer 0: h0 = z @ w0 + b0 (+ fused col stats); 2-term, K2=256
    prep_act_k<7, false><<<dim3(1024), blk, 0, stream>>>(z, nullptr, nullptr, nullptr, nullptr, A2);
    prepw_k<<<dim3(4, 16), blk, 0, stream>>>(w0, Bt, 128, 512, 256);
    gemm8<0><<<dim3(4, 64), gblk, 0, stream>>>(A2, Bt, b0, h0, 256, 512, 512, ps, pq);
    colstats_final<<<dim3(2), blk, 0, stream>>>(ps, pq, mean, rstd);
    // layer 1: 2-term, K2=1024
    prep_act_k<9, true><<<dim3(4096), blk, 0, stream>>>(h0, mean, rstd, g0, be0, A2);
    prepw_k<<<dim3(16, 16), blk, 0, stream>>>(w1, Bt, 512, 512, 1024);
    gemm8<0><<<dim3(4, 64), gblk, 0, stream>>>(A2, Bt, b1, h1, 1024, 512, 512, ps, pq);
    colstats_final<<<dim3(2), blk, 0, stream>>>(ps, pq, mean, rstd);
    // layer 2: 2-term
    prep_act_k<9, true><<<dim3(4096), blk, 0, stream>>>(h1, mean, rstd, g1, be1, A2);
    prepw_k<<<dim3(16, 16), blk, 0, stream>>>(w2, Bt, 512, 512, 1024);
    gemm8<0><<<dim3(4, 64), gblk, 0, stream>>>(A2, Bt, b2, h2, 1024, 512, 512, ps, pq);
    colstats_final<<<dim3(2), blk, 0, stream>>>(ps, pq, mean, rstd);
    // layer 3: 2-term (K2=1024), fcs = mod_sigmoid(...) [8192][1040], 1025 valid
    prep_act_k<9, true><<<dim3(4096), blk, 0, stream>>>(h2, mean, rstd, g2, be2, A2);
    prepw_k<<<dim3(16, 36), blk, 0, stream>>>(w3, Bt, 512, 1025, 1024);
    gemm8<1><<<dim3(9, 64), gblk, 0, stream>>>(A2, Bt, b3, fcs, 1024, 1025, 1040, nullptr, nullptr);
    // spectral filtering + window (fused)
    fft_filter_kernel<<<dim3(8192), blk, 0, stream>>>(noise, fcs, aw);
    // fused OLA + post conv + softsign
    ola_ppconv_kernel<<<dim3(1030, 16), blk, 0, stream>>>(aw, ppw, ppb, out);
    (void)in_sizes; (void)n_in; (void)out_size; (void)ws_size;
}

// Round 7
// 208.775 us; speedup vs baseline: 2.9150x; 1.0996x over previous
//
#include <hip/hip_runtime.h>
#include <hip/hip_bf16.h>
#include <math.h>

#define TARLEN 263680
#define POWEXP 2.302585092994046f  // ln(10)
#define PC(i) ((i) + ((i) >> 3))   // complex-unit LDS padding (1 per 8)

typedef __attribute__((ext_vector_type(8))) short bf16x8;
typedef __attribute__((ext_vector_type(4))) float f32x4;

__device__ __forceinline__ void gload16(const void* g, void* l) {
    __builtin_amdgcn_global_load_lds((const __attribute__((address_space(1))) void*)g,
                                     (__attribute__((address_space(3))) void*)l, 16, 0, 0);
}

__device__ __forceinline__ float norm_lrelu(float a, float m, float rs, float g, float b) {
    float x = (a - m) * rs * g + b;
    return x >= 0.f ? x : 0.2f * x;
}

// ============ unified GEMM: 128x128 tile, 512 thr, 8 waves of 64x32 =========
// 1-term bf16: C = Ahi @ Bhi (B already bf16-only since r1; absmax floor
// evidence says A-side bf16 stays under threshold). A [M][K] bf16 hi,
// Bt [N][K] bf16 hi. LDS k-chunk XOR swizzle both sides (conflict-free, r5).
// 3-buffer deep pipeline, counted vmcnt(2) + raw s_barrier (r6-verified).
// EPI==0: fused BN column-stats partials. EPI==1: mod_sigmoid epilogue.
template<int EPI>
__global__ __launch_bounds__(512) void gemm8(
    const ushort* __restrict__ A, const ushort* __restrict__ Bt,
    const float* __restrict__ bias, float* __restrict__ C,
    int K, int Nvalid, int ldc,
    float* __restrict__ ps, float* __restrict__ pq)
{
    __shared__ ushort As[3][4096];  // [128][32] each
    __shared__ ushort Bs[3][4096];
    __shared__ float sred[8][2][16];
    __shared__ float qred[8][2][16];
    const int tid = threadIdx.x;
    const int lane = tid & 63;
    const int wid = tid >> 6;
    // bijective XCD swizzle (nwg % 8 == 0 for all our grids)
    const int nwg = gridDim.x * gridDim.y;
    const int bid = blockIdx.y * gridDim.x + blockIdx.x;
    const int q8 = nwg >> 3;
    const int swzb = (bid & 7) * q8 + (bid >> 3);
    const int bx = swzb % gridDim.x;
    const int by = swzb / gridDim.x;
    const int m0 = by * 128;
    const int n0 = bx * 128;
    const int NT = K >> 5;

    f32x4 acc[4][2];
#pragma unroll
    for (int m = 0; m < 4; ++m)
#pragma unroll
        for (int n = 0; n < 2; ++n)
            acc[m][n] = (f32x4){0.f, 0.f, 0.f, 0.f};

    const int srow = tid >> 2;                              // 0..127
    const int scol = (((tid & 3) ^ ((tid >> 3) & 3)) << 3); // swizzled src chunk

    auto stage = [&](int t, int buf) {
        const int k0 = t << 5;
        gload16(A + (size_t)(m0 + srow) * K + k0 + scol, &As[buf][tid * 8]);
        gload16(Bt + (size_t)(n0 + srow) * K + k0 + scol, &Bs[buf][tid * 8]);
    };

    const int lr = lane & 15;
    const int sw8 = (((lane >> 4) ^ ((lane >> 1) & 3)) << 3);  // swizzled read chunk
    const int wm0 = (wid >> 2) * 64;
    const int wn0 = (wid & 3) * 32;

    stage(0, 0);
    stage(1, 1);
    for (int t = 0; t < NT; ++t) {
        const int cur = t % 3;
        if (t + 2 < NT) {
            asm volatile("s_waitcnt vmcnt(2)" ::: "memory");  // own stage(t) landed
            __builtin_amdgcn_s_barrier();                     // all waves' stage(t) landed
            stage(t + 2, (t + 2) % 3);
        } else {
            asm volatile("s_waitcnt vmcnt(0)" ::: "memory");
            __builtin_amdgcn_s_barrier();
        }
        const ushort* as = As[cur];
        const ushort* bs = Bs[cur];
        bf16x8 af[4], bfv[2];
#pragma unroll
        for (int m = 0; m < 4; ++m)
            af[m] = *reinterpret_cast<const bf16x8*>(&as[(wm0 + m * 16 + lr) * 32 + sw8]);
#pragma unroll
        for (int n = 0; n < 2; ++n)
            bfv[n] = *reinterpret_cast<const bf16x8*>(&bs[(wn0 + n * 16 + lr) * 32 + sw8]);
#pragma unroll
        for (int m = 0; m < 4; ++m)
#pragma unroll
            for (int n = 0; n < 2; ++n)
                acc[m][n] = __builtin_amdgcn_mfma_f32_16x16x32_bf16(af[m], bfv[n], acc[m][n], 0, 0, 0);
    }
    __syncthreads();

    // epilogue: C/D layout col=lane&15, row=(lane>>4)*4+reg
    const int cr = (lane >> 4) << 2;
    const int cc = lane & 15;
    float sacc[2] = {0.f, 0.f}, qacc[2] = {0.f, 0.f};
#pragma unroll
    for (int m = 0; m < 4; ++m) {
#pragma unroll
        for (int n = 0; n < 2; ++n) {
            int gcol = n0 + wn0 + n * 16 + cc;
            if (EPI == 0 || gcol < Nvalid) {
                float bv = bias[gcol];
                int grow = m0 + wm0 + m * 16 + cr;
#pragma unroll
                for (int j = 0; j < 4; ++j) {
                    float v = acc[m][n][j] + bv;
                    if (EPI == 1) {
                        float sg = 1.f / (1.f + __expf(-v));
                        v = 2.f * __expf(POWEXP * __logf(sg)) + 1e-7f;
                    } else {
                        sacc[n] += v;
                        qacc[n] += v * v;
                    }
                    C[(size_t)(grow + j) * ldc + gcol] = v;
                }
            }
        }
    }
    if (EPI == 0) {
#pragma unroll
        for (int n = 0; n < 2; ++n) {
            float s = sacc[n], q = qacc[n];
            s += __shfl_xor(s, 16); q += __shfl_xor(q, 16);
            s += __shfl_xor(s, 32); q += __shfl_xor(q, 32);
            if (lane < 16) { sred[wid][n][lane] = s; qred[wid][n][lane] = q; }
        }
        __syncthreads();
        if (tid < 128) {
            int wn_ = tid >> 5, n_ = (tid >> 4) & 1, cc_ = tid & 15;
            float s = sred[wn_][n_][cc_] + sred[4 + wn_][n_][cc_];
            float q = qred[wn_][n_][cc_] + qred[4 + wn_][n_][cc_];
            int col = n0 + wn_ * 32 + n_ * 16 + cc_;
            ps[(size_t)by * 512 + col] = s;
            pq[(size_t)by * 512 + col] = q;
        }
    }
}

// ---------------- prep: activations -> BN+LeakyReLU -> bf16 hi ------------
template<int KSH, bool NORM>
__global__ __launch_bounds__(256) void prep_act_k(
    const float* __restrict__ H, const float* __restrict__ mean,
    const float* __restrict__ rstd, const float* __restrict__ gamma,
    const float* __restrict__ beta, ushort* __restrict__ A)
{
    const int K = 1 << KSH;
    int idx = (blockIdx.x * 256 + threadIdx.x) << 2;
    int col = idx & (K - 1);
    float4 h = *reinterpret_cast<const float4*>(&H[idx]);
    float x[4] = {h.x, h.y, h.z, h.w};
    if (NORM) {
        float4 mm = *reinterpret_cast<const float4*>(&mean[col]);
        float4 rs = *reinterpret_cast<const float4*>(&rstd[col]);
        float4 gg = *reinterpret_cast<const float4*>(&gamma[col]);
        float4 bb = *reinterpret_cast<const float4*>(&beta[col]);
        x[0] = norm_lrelu(x[0], mm.x, rs.x, gg.x, bb.x);
        x[1] = norm_lrelu(x[1], mm.y, rs.y, gg.y, bb.y);
        x[2] = norm_lrelu(x[2], mm.z, rs.z, gg.z, bb.z);
        x[3] = norm_lrelu(x[3], mm.w, rs.w, gg.w, bb.w);
    }
    ushort4 hv;
    __hip_bfloat16 b0 = __float2bfloat16(x[0]); hv.x = *reinterpret_cast<ushort*>(&b0);
    __hip_bfloat16 b1 = __float2bfloat16(x[1]); hv.y = *reinterpret_cast<ushort*>(&b1);
    __hip_bfloat16 b2 = __float2bfloat16(x[2]); hv.z = *reinterpret_cast<ushort*>(&b2);
    __hip_bfloat16 b3 = __float2bfloat16(x[3]); hv.w = *reinterpret_cast<ushort*>(&b3);
    *reinterpret_cast<ushort4*>(&A[idx]) = hv;
}

// ---------------- prep: weights -> transpose + bf16 hi --------------------
__global__ __launch_bounds__(256) void prepw_k(
    const float* __restrict__ w, ushort* __restrict__ Bt, int K, int N)
{
    __shared__ float tile[32][33];
    int k0 = blockIdx.x * 32, n0 = blockIdx.y * 32;
    int tx = threadIdx.x & 31, ty = threadIdx.x >> 5;  // 32 x 8
#pragma unroll
    for (int r = 0; r < 4; ++r) {
        int k = k0 + ty + r * 8;
        int n = n0 + tx;
        tile[ty + r * 8][tx] = (n < N) ? w[(size_t)k * N + n] : 0.f;
    }
    __syncthreads();
#pragma unroll
    for (int r = 0; r < 4; ++r) {
        int n = n0 + ty + r * 8;
        int k = k0 + tx;
        float x = tile[tx][ty + r * 8];
        __hip_bfloat16 h = __float2bfloat16(x);
        Bt[(size_t)n * K + k] = *reinterpret_cast<ushort*>(&h);
    }
}

// ---------------- BN stats final reduce (64 row-block partials) -----------
__global__ __launch_bounds__(256) void colstats_final(
    const float* __restrict__ ps, const float* __restrict__ pq,
    float* __restrict__ mean, float* __restrict__ rstd)
{
    int c = blockIdx.x * 256 + threadIdx.x;
    float s = 0.f, q = 0.f;
    for (int rg = 0; rg < 64; ++rg) { s += ps[rg * 512 + c]; q += pq[rg * 512 + c]; }
    float m = s * (1.f / 8192.f);
    float v = q * (1.f / 8192.f) - m * m;
    mean[c] = m;
    rstd[c] = rsqrtf(v + 1e-5f);
}

// ---------------- Stockham radix-4 FFT, float2 LDS, twiddle table ---------
__device__ __forceinline__ float2 cmul(float2 a, float c, float s) {
    return make_float2(a.x * c - a.y * s, a.x * s + a.y * c);
}

// Wt[j] = (cos, sin)(2*pi*j/1024). Stage twiddle e^{-+2pi i k/(4L)} = Wt[k*256/L]
// (conj for forward). Max index 3*j <= 765 < 1024 -> no wrap.
template<bool INV, int L>
__device__ __forceinline__ void stk_stage(
    const float2* __restrict__ s, float2* __restrict__ d,
    const float2* __restrict__ Wt, int t)
{
    int k = t & (L - 1);
    float2 x0 = s[PC(t)];
    float2 x1 = s[PC(t + 256)];
    float2 x2 = s[PC(t + 512)];
    float2 x3 = s[PC(t + 768)];
    if (L > 1) {
        const int ST = 256 / L;
        int j = k * ST;
        float2 w1 = Wt[j], w2 = Wt[2 * j], w3 = Wt[3 * j];
        if (!INV) {
            x1 = cmul(x1, w1.x, -w1.y);
            x2 = cmul(x2, w2.x, -w2.y);
            x3 = cmul(x3, w3.x, -w3.y);
        } else {
            x1 = cmul(x1, w1.x, w1.y);
            x2 = cmul(x2, w2.x, w2.y);
            x3 = cmul(x3, w3.x, w3.y);
        }
    }
    float2 a = make_float2(x0.x + x2.x, x0.y + x2.y);
    float2 b = make_float2(x0.x - x2.x, x0.y - x2.y);
    float2 c = make_float2(x1.x + x3.x, x1.y + x3.y);
    float2 e = make_float2(x1.x - x3.x, x1.y - x3.y);
    int db = ((t - k) << 2) + k;
    d[PC(db)]         = make_float2(a.x + c.x, a.y + c.y);
    d[PC(db + 2 * L)] = make_float2(a.x - c.x, a.y - c.y);
    if (!INV) {
        d[PC(db + L)]     = make_float2(b.x + e.y, b.y - e.x);
        d[PC(db + 3 * L)] = make_float2(b.x - e.y, b.y + e.x);
    } else {
        d[PC(db + L)]     = make_float2(b.x - e.y, b.y + e.x);
        d[PC(db + 3 * L)] = make_float2(b.x + e.y, b.y - e.x);
    }
}

// audio = irfft( rfft(noise_row) * H ), H[k] = (-1)^k*(0.5 fc[k]+0.25 fc[k-1]+0.25 fc[k+1])
// (analytic collapse of rfft(fftshift(irfft(fc)*FW))). 1/1024 folded into H.
// First fwd / last inv stages fused with global IO; OLA window from table.
__global__ __launch_bounds__(256) void fft_filter_kernel(
    const float* __restrict__ noise, const float* __restrict__ fcs, float* __restrict__ aw)
{
    __shared__ float2 X[1152], Y[1152], Wt[1024];
    __shared__ float F[1025];
    const int tid = threadIdx.x;
    const int r = blockIdx.x;

    const float2* nrow = reinterpret_cast<const float2*>(noise + ((size_t)r << 11));
    for (int i = tid; i < 1025; i += 256) F[i] = fcs[(size_t)r * 1040 + i];
    for (int j = tid; j < 1024; j += 256) {
        float s, c;
        __sincosf((float)(2.0 * M_PI / 1024.0) * j, &s, &c);
        Wt[j] = make_float2(c, s);
    }
    {
        // forward stage L=1 fused with global load (pack z[n]=x[2n]+i x[2n+1])
        float2 x0 = nrow[tid], x1 = nrow[tid + 256], x2 = nrow[tid + 512], x3 = nrow[tid + 768];
        float2 a = make_float2(x0.x + x2.x, x0.y + x2.y);
        float2 b = make_float2(x0.x - x2.x, x0.y - x2.y);
        float2 c = make_float2(x1.x + x3.x, x1.y + x3.y);
        float2 e = make_float2(x1.x - x3.x, x1.y - x3.y);
        int db = tid << 2;
        Y[PC(db)]     = make_float2(a.x + c.x, a.y + c.y);
        Y[PC(db + 1)] = make_float2(b.x + e.y, b.y - e.x);
        Y[PC(db + 2)] = make_float2(a.x - c.x, a.y - c.y);
        Y[PC(db + 3)] = make_float2(b.x - e.y, b.y + e.x);
    }
    __syncthreads();
    stk_stage<false, 4>(Y, X, Wt, tid);   __syncthreads();
    stk_stage<false, 16>(X, Y, Wt, tid);  __syncthreads();
    stk_stage<false, 64>(Y, X, Wt, tid);  __syncthreads();
    stk_stage<false, 256>(X, Y, Wt, tid); __syncthreads();
    // forward result in Y (natural order)

    // unpack real FFT, apply H (scaled by 1/1024), repack; read Y, write X
    const float INV1024 = 1.0f / 1024.0f;
    auto proc = [&](int k, float c, float s) {
        int k2 = (1024 - k) & 1023;
        float2 za = Y[PC(k)], zb = Y[PC(k2)];
        float Fer = 0.5f * (za.x + zb.x), Fei = 0.5f * (za.y - zb.y);
        float For = 0.5f * (za.y + zb.y), Foi = 0.5f * (zb.x - za.x);
        float wFr = c * For - s * Foi;
        float wFi = c * Foi + s * For;
        float Xkr = Fer + wFr, Xki = Fei + wFi;
        float Xbr = Fer - wFr, Xbi = wFi - Fei;
        float Hk, Hb;
        {
            float cl = (k == 0) ? F[1] : F[k - 1];
            float crr = (k == 1024) ? F[1023] : F[k + 1];
            float h = 0.5f * F[k] + 0.25f * (cl + crr);
            Hk = ((k & 1) ? -h : h) * INV1024;
        }
        {
            int kb = 1024 - k;
            float cl = (kb == 0) ? F[1] : F[kb - 1];
            float crr = (kb == 1024) ? F[1023] : F[kb + 1];
            float h = 0.5f * F[kb] + 0.25f * (cl + crr);
            Hb = ((kb & 1) ? -h : h) * INV1024;
        }
        float Ykr = Hk * Xkr, Yki = Hk * Xki;
        float Ybr = Hb * Xbr, Ybi = Hb * Xbi;
        if (k == 0) {
            X[PC(0)] = make_float2(0.5f * (Ykr + Ybr), 0.5f * (Ykr - Ybr));
        } else {
            float Ger = 0.5f * (Ykr + Ybr), Gei = 0.5f * (Yki - Ybi);
            float Sgr = 0.5f * (Ykr - Ybr), Sgi = 0.5f * (Yki + Ybi);
            float wpr = c, wpi = -s;
            float Gor = wpr * Sgr - wpi * Sgi;
            float Goi = wpr * Sgi + wpi * Sgr;
            X[PC(k)]  = make_float2(Ger - Goi, Gei + Gor);
            X[PC(k2)] = make_float2(Ger + Goi, Gor - Gei);
        }
    };
    {
        float s0, c0;
        __sincosf((float)(-M_PI / 1024.0) * tid, &s0, &c0);
        proc(tid, c0, s0);
        const float RT = 0.70710678118654752f;  // e^{-i pi/4}
        float c1 = (c0 + s0) * RT, s1 = (s0 - c0) * RT;
        proc(tid + 256, c1, s1);
        if (tid == 0) proc(512, 0.f, -1.f);
    }
    __syncthreads();

    stk_stage<true, 1>(X, Y, Wt, tid);  __syncthreads();
    stk_stage<true, 4>(Y, X, Wt, tid);  __syncthreads();
    stk_stage<true, 16>(X, Y, Wt, tid); __syncthreads();
    stk_stage<true, 64>(Y, X, Wt, tid); __syncthreads();

    // inverse final stage (L=256) fused with OLA window + store;
    // twiddles and window cos(2*pi*n/1024) from the table.
    {
        const int g = r & 511;
        float2* awrow = reinterpret_cast<float2*>(aw + ((size_t)r << 11));
        int t = tid;
        float2 x0 = X[PC(t)], x1 = X[PC(t + 256)], x2 = X[PC(t + 512)], x3 = X[PC(t + 768)];
        float2 w1 = Wt[t], w2 = Wt[2 * t], w3 = Wt[3 * t];
        float c1 = w1.x, s1 = w1.y;
        x1 = cmul(x1, w2 /*unused*/ .x * 0.f + c1, s1);  // keep order simple below
        // (redo cleanly)
        x1 = cmul(make_float2(x1.x, x1.y), 1.f, 0.f);    // no-op guard
        // proper twiddles:
        x1 = cmul(make_float2(X[PC(t + 256)].x, X[PC(t + 256)].y), c1, s1);
        x2 = cmul(x2, w2.x, w2.y);
        x3 = cmul(x3, w3.x, w3.y);
        float2 a = make_float2(x0.x + x2.x, x0.y + x2.y);
        float2 b = make_float2(x0.x - x2.x, x0.y - x2.y);
        float2 c = make_float2(x1.x + x3.x, x1.y + x3.y);
        float2 e = make_float2(x1.x - x3.x, x1.y - x3.y);
        float2 o[4];
        o[0] = make_float2(a.x + c.x, a.y + c.y);
        o[1] = make_float2(b.x - e.y, b.y + e.x);
        o[2] = make_float2(a.x - c.x, a.y - c.y);
        o[3] = make_float2(b.x + e.y, b.y - e.x);
        float cq[4] = {c1, -s1, -c1, s1};
        float sq[4] = {s1, c1, -s1, -c1};
        const float COSD = 0.99999529380958f;   // cos(pi/1024)
        const float SIND = 0.00306795676296f;   // sin(pi/1024)
#pragma unroll
        for (int q = 0; q < 4; ++q) {
            int n = t + 256 * q;
            float w0, w1v;
            bool edge = (g == 0 && q < 2) || (g == 511 && q >= 2);
            if (edge) { w0 = 1.f; w1v = 1.f; }
            else {
                w0 = 0.5f - 0.5f * cq[q];
                w1v = 0.5f - 0.5f * (cq[q] * COSD - sq[q] * SIND);
            }
            awrow[n] = make_float2(o[q].x * w0, o[q].y * w1v);
        }
    }
}

// ---------------- fused OLA gather + 65-tap conv + softsign ---------------
__global__ __launch_bounds__(256) void ola_ppconv_kernel(
    const float* __restrict__ aw, const float* __restrict__ ppw,
    const float* __restrict__ ppb, float* __restrict__ out)
{
    __shared__ float tile[320];
    __shared__ float Ksh[65];
    int t0 = blockIdx.x * 256;
    int b = blockIdx.y;
    for (int i = threadIdx.x; i < 320; i += 256) {
        int tt = t0 - 32 + i;
        float v = 0.f;
        if (tt >= 0 && tt < TARLEN) {
            int ghi = min(511, tt >> 9);
            int glo = max(0, (tt - 1536) >> 9);
            float s = 0.f;
            for (int g = glo; g <= ghi; ++g) {
                int n = tt - (g << 9);
                s += aw[((size_t)(b * 512 + g) << 11) + n];
            }
            v = s / (float)(ghi - glo + 1);
        }
        tile[i] = v;
    }
    if (threadIdx.x < 65) {
        float k = 0.f;
#pragma unroll
        for (int c = 0; c < 5; ++c) k += ppw[c * 65 + threadIdx.x];
        Ksh[threadIdx.x] = k;
    }
    __syncthreads();
    float y = ppb[0];
#pragma unroll
    for (int j = 0; j < 65; ++j) y = fmaf(Ksh[j], tile[threadIdx.x + j], y);
    int t = t0 + threadIdx.x;
    out[(size_t)b * TARLEN + t] = y / (1.f + fabsf(y));
}

// ---------------- launch --------------------------------------------------
extern "C" void kernel_launch(void* const* d_in, const int* in_sizes, int n_in,
                              void* d_out, int out_size, void* d_ws, size_t ws_size,
                              hipStream_t stream) {
    const float* z    = (const float*)d_in[0];
    const float* w0   = (const float*)d_in[1];
    const float* b0   = (const float*)d_in[2];
    const float* g0   = (const float*)d_in[3];
    const float* be0  = (const float*)d_in[4];
    const float* w1   = (const float*)d_in[5];
    const float* b1   = (const float*)d_in[6];
    const float* g1   = (const float*)d_in[7];
    const float* be1  = (const float*)d_in[8];
    const float* w2   = (const float*)d_in[9];
    const float* b2   = (const float*)d_in[10];
    const float* g2   = (const float*)d_in[11];
    const float* be2  = (const float*)d_in[12];
    const float* w3   = (const float*)d_in[13];
    const float* b3   = (const float*)d_in[14];
    const float* ppw  = (const float*)d_in[15];
    const float* ppb  = (const float*)d_in[16];
    const float* noise= (const float*)d_in[17];
    float* out = (float*)d_out;
    float* ws = (float*)d_ws;

    // workspace (floats)
    float* h0   = ws;                  // 8192*512
    float* ps   = ws + 4194304;        // 64*512
    float* pq   = ps + 32768;          // 64*512
    float* mean = pq + 32768;          // 512
    float* rstd = mean + 512;          // 512
    float* Btf  = rstd + 512;          // up to 1152*512 ushort
    float* fcs  = Btf + 884736;        // 8192*1040 f (h1 aliases start)
    float* awf  = fcs + 8519680;       // 8192*2048 f (A aliases start)
    ushort* Bt  = (ushort*)Btf;
    ushort* A   = (ushort*)awf;
    float* h1 = fcs;   // dead before fcs written
    float* h2 = h0;    // h0 dead after its prep
    float* aw = awf;   // A dead before fft writes

    dim3 blk(256);
    dim3 gblk(512);
    // layer 0: h0 = z @ w0 + b0 (+ fused col stats); K=128
    prep_act_k<7, false><<<dim3(1024), blk, 0, stream>>>(z, nullptr, nullptr, nullptr, nullptr, A);
    prepw_k<<<dim3(4, 16), blk, 0, stream>>>(w0, Bt, 128, 512);
    gemm8<0><<<dim3(4, 64), gblk, 0, stream>>>(A, Bt, b0, h0, 128, 512, 512, ps, pq);
    colstats_final<<<dim3(2), blk, 0, stream>>>(ps, pq, mean, rstd);
    // layer 1: K=512
    prep_act_k<9, true><<<dim3(4096), blk, 0, stream>>>(h0, mean, rstd, g0, be0, A);
    prepw_k<<<dim3(16, 16), blk, 0, stream>>>(w1, Bt, 512, 512);
    gemm8<0><<<dim3(4, 64), gblk, 0, stream>>>(A, Bt, b1, h1, 512, 512, 512, ps, pq);
    colstats_final<<<dim3(2), blk, 0, stream>>>(ps, pq, mean, rstd);
    // layer 2
    prep_act_k<9, true><<<dim3(4096), blk, 0, stream>>>(h1, mean, rstd, g1, be1, A);
    prepw_k<<<dim3(16, 16), blk, 0, stream>>>(w2, Bt, 512, 512);
    gemm8<0><<<dim3(4, 64), gblk, 0, stream>>>(A, Bt, b2, h2, 512, 512, 512, ps, pq);
    colstats_final<<<dim3(2), blk, 0, stream>>>(ps, pq, mean, rstd);
    // layer 3: K=512, fcs = mod_sigmoid(...) [8192][1040], 1025 valid
    prep_act_k<9, true><<<dim3(4096), blk, 0, stream>>>(h2, mean, rstd, g2, be2, A);
    prepw_k<<<dim3(16, 36), blk, 0, stream>>>(w3, Bt, 512, 1025);
    gemm8<1><<<dim3(9, 64), gblk, 0, stream>>>(A, Bt, b3, fcs, 512, 1025, 1040, nullptr, nullptr);
    // spectral filtering + window (fused)
    fft_filter_kernel<<<dim3(8192), blk, 0, stream>>>(noise, fcs, aw);
    // fused OLA + post conv + softsign
    ola_ppconv_kernel<<<dim3(1030, 16), blk, 0, stream>>>(aw, ppw, ppb, out);
    (void)in_sizes; (void)n_in; (void)out_size; (void)ws_size;
}

// Round 8
// 191.295 us; speedup vs baseline: 3.1814x; 1.0914x over previous
//
#include <hip/hip_runtime.h>
#include <hip/hip_bf16.h>
#include <math.h>

#define TARLEN 263680
#define POWEXP 2.302585092994046f  // ln(10)
#define PC(i) ((i) + ((i) >> 3))   // complex-unit LDS padding (1 per 8)

typedef __attribute__((ext_vector_type(8))) short bf16x8;
typedef __attribute__((ext_vector_type(8))) ushort u16x8;
typedef __attribute__((ext_vector_type(4))) float f32x4;

__device__ __forceinline__ void gload16(const void* g, void* l) {
    __builtin_amdgcn_global_load_lds((const __attribute__((address_space(1))) void*)g,
                                     (__attribute__((address_space(3))) void*)l, 16, 0, 0);
}

__device__ __forceinline__ float bf16f(ushort u) {
    union { uint u; float f; } v; v.u = (uint)u << 16; return v.f;
}
__device__ __forceinline__ ushort fbf16(float x) {
    __hip_bfloat16 h = __float2bfloat16(x);
    return *reinterpret_cast<ushort*>(&h);
}

__device__ __forceinline__ float norm_lrelu(float a, float m, float rs, float g, float b) {
    float x = (a - m) * rs * g + b;
    return x >= 0.f ? x : 0.2f * x;
}

// ============ unified GEMM: 128x128 tile, 512 thr, 8 waves of 64x32 =========
// 1-term bf16: C = A @ Bt^T. A [M][K] bf16, Bt [N][K] bf16. LDS k-chunk XOR
// swizzle both sides (conflict-free, r5). 3-buffer deep pipeline, counted
// vmcnt(2) + raw s_barrier (r6-verified). C written as bf16.
// EPI==0: fused BN column-stats partials. EPI==1: mod_sigmoid epilogue.
template<int EPI>
__global__ __launch_bounds__(512) void gemm8(
    const ushort* __restrict__ A, const ushort* __restrict__ Bt,
    const float* __restrict__ bias, ushort* __restrict__ C,
    int K, int Nvalid, int ldc,
    float* __restrict__ ps, float* __restrict__ pq)
{
    __shared__ ushort As[3][4096];  // [128][32] each
    __shared__ ushort Bs[3][4096];
    __shared__ float sred[8][2][16];
    __shared__ float qred[8][2][16];
    const int tid = threadIdx.x;
    const int lane = tid & 63;
    const int wid = tid >> 6;
    // bijective XCD swizzle (nwg % 8 == 0 for all our grids)
    const int nwg = gridDim.x * gridDim.y;
    const int bid = blockIdx.y * gridDim.x + blockIdx.x;
    const int q8 = nwg >> 3;
    const int swzb = (bid & 7) * q8 + (bid >> 3);
    const int bx = swzb % gridDim.x;
    const int by = swzb / gridDim.x;
    const int m0 = by * 128;
    const int n0 = bx * 128;
    const int NT = K >> 5;

    f32x4 acc[4][2];
#pragma unroll
    for (int m = 0; m < 4; ++m)
#pragma unroll
        for (int n = 0; n < 2; ++n)
            acc[m][n] = (f32x4){0.f, 0.f, 0.f, 0.f};

    const int srow = tid >> 2;                              // 0..127
    const int scol = (((tid & 3) ^ ((tid >> 3) & 3)) << 3); // swizzled src chunk

    auto stage = [&](int t, int buf) {
        const int k0 = t << 5;
        gload16(A + (size_t)(m0 + srow) * K + k0 + scol, &As[buf][tid * 8]);
        gload16(Bt + (size_t)(n0 + srow) * K + k0 + scol, &Bs[buf][tid * 8]);
    };

    const int lr = lane & 15;
    const int sw8 = (((lane >> 4) ^ ((lane >> 1) & 3)) << 3);  // swizzled read chunk
    const int wm0 = (wid >> 2) * 64;
    const int wn0 = (wid & 3) * 32;

    stage(0, 0);
    stage(1, 1);
    for (int t = 0; t < NT; ++t) {
        const int cur = t % 3;
        if (t + 2 < NT) {
            asm volatile("s_waitcnt vmcnt(2)" ::: "memory");  // own stage(t) landed
            __builtin_amdgcn_s_barrier();                     // all waves' stage(t) landed
            stage(t + 2, (t + 2) % 3);
        } else {
            asm volatile("s_waitcnt vmcnt(0)" ::: "memory");
            __builtin_amdgcn_s_barrier();
        }
        const ushort* as = As[cur];
        const ushort* bs = Bs[cur];
        bf16x8 af[4], bfv[2];
#pragma unroll
        for (int m = 0; m < 4; ++m)
            af[m] = *reinterpret_cast<const bf16x8*>(&as[(wm0 + m * 16 + lr) * 32 + sw8]);
#pragma unroll
        for (int n = 0; n < 2; ++n)
            bfv[n] = *reinterpret_cast<const bf16x8*>(&bs[(wn0 + n * 16 + lr) * 32 + sw8]);
#pragma unroll
        for (int m = 0; m < 4; ++m)
#pragma unroll
            for (int n = 0; n < 2; ++n)
                acc[m][n] = __builtin_amdgcn_mfma_f32_16x16x32_bf16(af[m], bfv[n], acc[m][n], 0, 0, 0);
    }
    __syncthreads();

    // epilogue: C/D layout col=lane&15, row=(lane>>4)*4+reg
    const int cr = (lane >> 4) << 2;
    const int cc = lane & 15;
    float sacc[2] = {0.f, 0.f}, qacc[2] = {0.f, 0.f};
#pragma unroll
    for (int m = 0; m < 4; ++m) {
#pragma unroll
        for (int n = 0; n < 2; ++n) {
            int gcol = n0 + wn0 + n * 16 + cc;
            if (EPI == 0 || gcol < Nvalid) {
                float bv = bias[gcol];
                int grow = m0 + wm0 + m * 16 + cr;
#pragma unroll
                for (int j = 0; j < 4; ++j) {
                    float v = acc[m][n][j] + bv;
                    if (EPI == 1) {
                        float sg = 1.f / (1.f + __expf(-v));
                        v = 2.f * __expf(POWEXP * __logf(sg)) + 1e-7f;
                    } else {
                        sacc[n] += v;
                        qacc[n] += v * v;
                    }
                    C[(size_t)(grow + j) * ldc + gcol] = fbf16(v);
                }
            }
        }
    }
    if (EPI == 0) {
#pragma unroll
        for (int n = 0; n < 2; ++n) {
            float s = sacc[n], q = qacc[n];
            s += __shfl_xor(s, 16); q += __shfl_xor(q, 16);
            s += __shfl_xor(s, 32); q += __shfl_xor(q, 32);
            if (lane < 16) { sred[wid][n][lane] = s; qred[wid][n][lane] = q; }
        }
        __syncthreads();
        if (tid < 128) {
            int wn_ = tid >> 5, n_ = (tid >> 4) & 1, cc_ = tid & 15;
            float s = sred[wn_][n_][cc_] + sred[4 + wn_][n_][cc_];
            float q = qred[wn_][n_][cc_] + qred[4 + wn_][n_][cc_];
            int col = n0 + wn_ * 32 + n_ * 16 + cc_;
            ps[(size_t)by * 512 + col] = s;
            pq[(size_t)by * 512 + col] = q;
        }
    }
}

// ---------------- prep: h (bf16 or f32) -> BN+LeakyReLU -> bf16 A ---------
// 8 elements per thread.
template<int KSH, bool NORM, bool INBF16>
__global__ __launch_bounds__(256) void prep_act_k(
    const void* __restrict__ Hv, const float* __restrict__ mean,
    const float* __restrict__ rstd, const float* __restrict__ gamma,
    const float* __restrict__ beta, ushort* __restrict__ A)
{
    const int K = 1 << KSH;
    int idx = (blockIdx.x * 256 + threadIdx.x) << 3;
    int col = idx & (K - 1);
    float x[8];
    if (INBF16) {
        u16x8 hv = *reinterpret_cast<const u16x8*>((const ushort*)Hv + idx);
#pragma unroll
        for (int j = 0; j < 8; ++j) x[j] = bf16f(hv[j]);
    } else {
        const float* H = (const float*)Hv;
        float4 a = *reinterpret_cast<const float4*>(&H[idx]);
        float4 b = *reinterpret_cast<const float4*>(&H[idx + 4]);
        x[0] = a.x; x[1] = a.y; x[2] = a.z; x[3] = a.w;
        x[4] = b.x; x[5] = b.y; x[6] = b.z; x[7] = b.w;
    }
    if (NORM) {
#pragma unroll
        for (int h = 0; h < 2; ++h) {
            float4 mm = *reinterpret_cast<const float4*>(&mean[col + h * 4]);
            float4 rs = *reinterpret_cast<const float4*>(&rstd[col + h * 4]);
            float4 gg = *reinterpret_cast<const float4*>(&gamma[col + h * 4]);
            float4 bb = *reinterpret_cast<const float4*>(&beta[col + h * 4]);
            x[h * 4 + 0] = norm_lrelu(x[h * 4 + 0], mm.x, rs.x, gg.x, bb.x);
            x[h * 4 + 1] = norm_lrelu(x[h * 4 + 1], mm.y, rs.y, gg.y, bb.y);
            x[h * 4 + 2] = norm_lrelu(x[h * 4 + 2], mm.z, rs.z, gg.z, bb.z);
            x[h * 4 + 3] = norm_lrelu(x[h * 4 + 3], mm.w, rs.w, gg.w, bb.w);
        }
    }
    u16x8 o;
#pragma unroll
    for (int j = 0; j < 8; ++j) o[j] = fbf16(x[j]);
    *reinterpret_cast<u16x8*>(&A[idx]) = o;
}

// ---------------- prep: weights -> transpose + bf16 -----------------------
__global__ __launch_bounds__(256) void prepw_k(
    const float* __restrict__ w, ushort* __restrict__ Bt, int K, int N)
{
    __shared__ float tile[32][33];
    int k0 = blockIdx.x * 32, n0 = blockIdx.y * 32;
    int tx = threadIdx.x & 31, ty = threadIdx.x >> 5;  // 32 x 8
#pragma unroll
    for (int r = 0; r < 4; ++r) {
        int k = k0 + ty + r * 8;
        int n = n0 + tx;
        tile[ty + r * 8][tx] = (n < N) ? w[(size_t)k * N + n] : 0.f;
    }
    __syncthreads();
#pragma unroll
    for (int r = 0; r < 4; ++r) {
        int n = n0 + ty + r * 8;
        int k = k0 + tx;
        Bt[(size_t)n * K + k] = fbf16(tile[tx][ty + r * 8]);
    }
}

// ---------------- BN stats final reduce (64 row-block partials) -----------
__global__ __launch_bounds__(256) void colstats_final(
    const float* __restrict__ ps, const float* __restrict__ pq,
    float* __restrict__ mean, float* __restrict__ rstd)
{
    int c = blockIdx.x * 256 + threadIdx.x;
    float s = 0.f, q = 0.f;
    for (int rg = 0; rg < 64; ++rg) { s += ps[rg * 512 + c]; q += pq[rg * 512 + c]; }
    float m = s * (1.f / 8192.f);
    float v = q * (1.f / 8192.f) - m * m;
    mean[c] = m;
    rstd[c] = rsqrtf(v + 1e-5f);
}

// ---------------- Stockham radix-4 FFT, float2 LDS, 256 threads (r6) ------
__device__ __forceinline__ float2 cmul(float2 a, float c, float s) {
    return make_float2(a.x * c - a.y * s, a.x * s + a.y * c);
}

template<bool INV, int L>
__device__ __forceinline__ void stk_stage(
    const float2* __restrict__ s, float2* __restrict__ d, int t)
{
    int k = t & (L - 1);
    float2 x0 = s[PC(t)];
    float2 x1 = s[PC(t + 256)];
    float2 x2 = s[PC(t + 512)];
    float2 x3 = s[PC(t + 768)];
    if (L > 1) {
        float th = (INV ? 2.0f : -2.0f) * (float)M_PI * (float)k / (float)(4 * L);
        float s1, c1; __sincosf(th, &s1, &c1);
        float c2 = c1 * c1 - s1 * s1, s2 = 2.f * c1 * s1;
        float c3 = c2 * c1 - s2 * s1, s3 = s2 * c1 + c2 * s1;
        x1 = cmul(x1, c1, s1);
        x2 = cmul(x2, c2, s2);
        x3 = cmul(x3, c3, s3);
    }
    float2 a = make_float2(x0.x + x2.x, x0.y + x2.y);
    float2 b = make_float2(x0.x - x2.x, x0.y - x2.y);
    float2 c = make_float2(x1.x + x3.x, x1.y + x3.y);
    float2 e = make_float2(x1.x - x3.x, x1.y - x3.y);
    int db = ((t - k) << 2) + k;
    d[PC(db)]         = make_float2(a.x + c.x, a.y + c.y);
    d[PC(db + 2 * L)] = make_float2(a.x - c.x, a.y - c.y);
    if (!INV) {
        d[PC(db + L)]     = make_float2(b.x + e.y, b.y - e.x);
        d[PC(db + 3 * L)] = make_float2(b.x - e.y, b.y + e.x);
    } else {
        d[PC(db + L)]     = make_float2(b.x - e.y, b.y + e.x);
        d[PC(db + 3 * L)] = make_float2(b.x + e.y, b.y - e.x);
    }
}

// audio = irfft( rfft(noise_row) * H ), H[k] = (-1)^k*(0.5 fc[k]+0.25 fc[k-1]+0.25 fc[k+1])
// (analytic collapse of rfft(fftshift(irfft(fc)*FW))). 1/1024 folded into H.
// fcs read as bf16; aw written as bf16. OLA window from final-stage twiddle.
__global__ __launch_bounds__(256) void fft_filter_kernel(
    const float* __restrict__ noise, const ushort* __restrict__ fcsb,
    ushort* __restrict__ awb)
{
    __shared__ float2 X[1152], Y[1152];
    __shared__ float F[1025];
    const int tid = threadIdx.x;
    const int r = blockIdx.x;

    const float2* nrow = reinterpret_cast<const float2*>(noise + ((size_t)r << 11));
    for (int i = tid; i < 1025; i += 256) F[i] = bf16f(fcsb[(size_t)r * 1040 + i]);
    {
        // forward stage L=1 fused with global load (pack z[n]=x[2n]+i x[2n+1])
        float2 x0 = nrow[tid], x1 = nrow[tid + 256], x2 = nrow[tid + 512], x3 = nrow[tid + 768];
        float2 a = make_float2(x0.x + x2.x, x0.y + x2.y);
        float2 b = make_float2(x0.x - x2.x, x0.y - x2.y);
        float2 c = make_float2(x1.x + x3.x, x1.y + x3.y);
        float2 e = make_float2(x1.x - x3.x, x1.y - x3.y);
        int db = tid << 2;
        Y[PC(db)]     = make_float2(a.x + c.x, a.y + c.y);
        Y[PC(db + 1)] = make_float2(b.x + e.y, b.y - e.x);
        Y[PC(db + 2)] = make_float2(a.x - c.x, a.y - c.y);
        Y[PC(db + 3)] = make_float2(b.x - e.y, b.y + e.x);
    }
    __syncthreads();
    stk_stage<false, 4>(Y, X, tid);   __syncthreads();
    stk_stage<false, 16>(X, Y, tid);  __syncthreads();
    stk_stage<false, 64>(Y, X, tid);  __syncthreads();
    stk_stage<false, 256>(X, Y, tid); __syncthreads();
    // forward result in Y (natural order)

    // unpack real FFT, apply H (scaled by 1/1024), repack; read Y, write X
    const float INV1024 = 1.0f / 1024.0f;
    auto proc = [&](int k, float c, float s) {
        int k2 = (1024 - k) & 1023;
        float2 za = Y[PC(k)], zb = Y[PC(k2)];
        float Fer = 0.5f * (za.x + zb.x), Fei = 0.5f * (za.y - zb.y);
        float For = 0.5f * (za.y + zb.y), Foi = 0.5f * (zb.x - za.x);
        float wFr = c * For - s * Foi;
        float wFi = c * Foi + s * For;
        float Xkr = Fer + wFr, Xki = Fei + wFi;
        float Xbr = Fer - wFr, Xbi = wFi - Fei;
        float Hk, Hb;
        {
            float cl = (k == 0) ? F[1] : F[k - 1];
            float crr = (k == 1024) ? F[1023] : F[k + 1];
            float h = 0.5f * F[k] + 0.25f * (cl + crr);
            Hk = ((k & 1) ? -h : h) * INV1024;
        }
        {
            int kb = 1024 - k;
            float cl = (kb == 0) ? F[1] : F[kb - 1];
            float crr = (kb == 1024) ? F[1023] : F[kb + 1];
            float h = 0.5f * F[kb] + 0.25f * (cl + crr);
            Hb = ((kb & 1) ? -h : h) * INV1024;
        }
        float Ykr = Hk * Xkr, Yki = Hk * Xki;
        float Ybr = Hb * Xbr, Ybi = Hb * Xbi;
        if (k == 0) {
            X[PC(0)] = make_float2(0.5f * (Ykr + Ybr), 0.5f * (Ykr - Ybr));
        } else {
            float Ger = 0.5f * (Ykr + Ybr), Gei = 0.5f * (Yki - Ybi);
            float Sgr = 0.5f * (Ykr - Ybr), Sgi = 0.5f * (Yki + Ybi);
            float wpr = c, wpi = -s;
            float Gor = wpr * Sgr - wpi * Sgi;
            float Goi = wpr * Sgi + wpi * Sgr;
            X[PC(k)]  = make_float2(Ger - Goi, Gei + Gor);
            X[PC(k2)] = make_float2(Ger + Goi, Gor - Gei);
        }
    };
    {
        float s0, c0;
        __sincosf((float)(-M_PI / 1024.0) * tid, &s0, &c0);
        proc(tid, c0, s0);
        const float RT = 0.70710678118654752f;  // e^{-i pi/4}
        float c1 = (c0 + s0) * RT, s1 = (s0 - c0) * RT;
        proc(tid + 256, c1, s1);
        if (tid == 0) proc(512, 0.f, -1.f);
    }
    __syncthreads();

    stk_stage<true, 1>(X, Y, tid);  __syncthreads();
    stk_stage<true, 4>(Y, X, tid);  __syncthreads();
    stk_stage<true, 16>(X, Y, tid); __syncthreads();
    stk_stage<true, 64>(Y, X, tid); __syncthreads();

    // inverse final stage (L=256) fused with OLA window + bf16 store;
    // window cos(2*pi*n/1024) at n=t+256q derived from the twiddle (c1,s1).
    {
        const int g = r & 511;
        ushort2* awrow = reinterpret_cast<ushort2*>(awb + ((size_t)r << 11));
        int t = tid;
        float2 x0 = X[PC(t)], x1 = X[PC(t + 256)], x2 = X[PC(t + 512)], x3 = X[PC(t + 768)];
        float th = (float)(2.0 * M_PI / 1024.0) * t;
        float s1, c1; __sincosf(th, &s1, &c1);
        float c2 = c1 * c1 - s1 * s1, s2 = 2.f * c1 * s1;
        float c3 = c2 * c1 - s2 * s1, s3 = s2 * c1 + c2 * s1;
        x1 = cmul(x1, c1, s1);
        x2 = cmul(x2, c2, s2);
        x3 = cmul(x3, c3, s3);
        float2 a = make_float2(x0.x + x2.x, x0.y + x2.y);
        float2 b = make_float2(x0.x - x2.x, x0.y - x2.y);
        float2 c = make_float2(x1.x + x3.x, x1.y + x3.y);
        float2 e = make_float2(x1.x - x3.x, x1.y - x3.y);
        float2 o[4];
        o[0] = make_float2(a.x + c.x, a.y + c.y);
        o[1] = make_float2(b.x - e.y, b.y + e.x);
        o[2] = make_float2(a.x - c.x, a.y - c.y);
        o[3] = make_float2(b.x + e.y, b.y - e.x);
        float cq[4] = {c1, -s1, -c1, s1};
        float sq[4] = {s1, c1, -s1, -c1};
        const float COSD = 0.99999529380958f;   // cos(pi/1024)
        const float SIND = 0.00306795676296f;   // sin(pi/1024)
#pragma unroll
        for (int q = 0; q < 4; ++q) {
            int n = t + 256 * q;
            float w0, w1;
            bool edge = (g == 0 && q < 2) || (g == 511 && q >= 2);
            if (edge) { w0 = 1.f; w1 = 1.f; }
            else {
                w0 = 0.5f - 0.5f * cq[q];
                w1 = 0.5f - 0.5f * (cq[q] * COSD - sq[q] * SIND);
            }
            ushort2 ov; ov.x = fbf16(o[q].x * w0); ov.y = fbf16(o[q].y * w1);
            awrow[n] = ov;
        }
    }
}

// ---------------- fused OLA gather + 65-tap conv + softsign ---------------
__global__ __launch_bounds__(256) void ola_ppconv_kernel(
    const ushort* __restrict__ awb, const float* __restrict__ ppw,
    const float* __restrict__ ppb, float* __restrict__ out)
{
    __shared__ float tile[320];
    __shared__ float Ksh[65];
    int t0 = blockIdx.x * 256;
    int b = blockIdx.y;
    for (int i = threadIdx.x; i < 320; i += 256) {
        int tt = t0 - 32 + i;
        float v = 0.f;
        if (tt >= 0 && tt < TARLEN) {
            int ghi = min(511, tt >> 9);
            int glo = max(0, (tt - 1536) >> 9);
            float s = 0.f;
            for (int g = glo; g <= ghi; ++g) {
                int n = tt - (g << 9);
                s += bf16f(awb[((size_t)(b * 512 + g) << 11) + n]);
            }
            v = s / (float)(ghi - glo + 1);
        }
        tile[i] = v;
    }
    if (threadIdx.x < 65) {
        float k = 0.f;
#pragma unroll
        for (int c = 0; c < 5; ++c) k += ppw[c * 65 + threadIdx.x];
        Ksh[threadIdx.x] = k;
    }
    __syncthreads();
    float y = ppb[0];
#pragma unroll
    for (int j = 0; j < 65; ++j) y = fmaf(Ksh[j], tile[threadIdx.x + j], y);
    int t = t0 + threadIdx.x;
    out[(size_t)b * TARLEN + t] = y / (1.f + fabsf(y));
}

// ---------------- launch --------------------------------------------------
extern "C" void kernel_launch(void* const* d_in, const int* in_sizes, int n_in,
                              void* d_out, int out_size, void* d_ws, size_t ws_size,
                              hipStream_t stream) {
    const float* z    = (const float*)d_in[0];
    const float* w0   = (const float*)d_in[1];
    const float* b0   = (const float*)d_in[2];
    const float* g0   = (const float*)d_in[3];
    const float* be0  = (const float*)d_in[4];
    const float* w1   = (const float*)d_in[5];
    const float* b1   = (const float*)d_in[6];
    const float* g1   = (const float*)d_in[7];
    const float* be1  = (const float*)d_in[8];
    const float* w2   = (const float*)d_in[9];
    const float* b2   = (const float*)d_in[10];
    const float* g2   = (const float*)d_in[11];
    const float* be2  = (const float*)d_in[12];
    const float* w3   = (const float*)d_in[13];
    const float* b3   = (const float*)d_in[14];
    const float* ppw  = (const float*)d_in[15];
    const float* ppb  = (const float*)d_in[16];
    const float* noise= (const float*)d_in[17];
    float* out = (float*)d_out;
    float* ws = (float*)d_ws;

    // workspace (float offsets)
    ushort* h0b = (ushort*)ws;                    // 8192*512 bf16 = 2,097,152 f
    ushort* h1b = (ushort*)(ws + 2097152);        // 8192*512 bf16
    float* ps   = ws + 4194304;                   // 64*512
    float* pq   = ps + 32768;                     // 64*512
    float* mean = pq + 32768;                     // 512
    float* rstd = mean + 512;                     // 512
    ushort* Bt  = (ushort*)(rstd + 512);          // 1152*512 bf16 = 294,912 f
    ushort* fcsb= (ushort*)(rstd + 512 + 294912); // 8192*1040 bf16 = 4,259,840 f
    ushort* awb = (ushort*)(rstd + 512 + 294912 + 4259840);  // 8192*2048 bf16
    ushort* A   = (ushort*)(rstd + 512 + 294912 + 4259840 + 8388608);  // 8192*512 bf16
    ushort* h2b = h0b;  // h0 dead after its prep

    dim3 blk(256);
    dim3 gblk(512);
    // layer 0: h0 = z @ w0 + b0 (+ fused col stats); K=128
    prep_act_k<7, false, false><<<dim3(512), blk, 0, stream>>>(z, nullptr, nullptr, nullptr, nullptr, A);
    prepw_k<<<dim3(4, 16), blk, 0, stream>>>(w0, Bt, 128, 512);
    gemm8<0><<<dim3(4, 64), gblk, 0, stream>>>(A, Bt, b0, h0b, 128, 512, 512, ps, pq);
    colstats_final<<<dim3(2), blk, 0, stream>>>(ps, pq, mean, rstd);
    // layer 1: K=512
    prep_act_k<9, true, true><<<dim3(2048), blk, 0, stream>>>(h0b, mean, rstd, g0, be0, A);
    prepw_k<<<dim3(16, 16), blk, 0, stream>>>(w1, Bt, 512, 512);
    gemm8<0><<<dim3(4, 64), gblk, 0, stream>>>(A, Bt, b1, h1b, 512, 512, 512, ps, pq);
    colstats_final<<<dim3(2), blk, 0, stream>>>(ps, pq, mean, rstd);
    // layer 2
    prep_act_k<9, true, true><<<dim3(2048), blk, 0, stream>>>(h1b, mean, rstd, g1, be1, A);
    prepw_k<<<dim3(16, 16), blk, 0, stream>>>(w2, Bt, 512, 512);
    gemm8<0><<<dim3(4, 64), gblk, 0, stream>>>(A, Bt, b2, h2b, 512, 512, 512, ps, pq);
    colstats_final<<<dim3(2), blk, 0, stream>>>(ps, pq, mean, rstd);
    // layer 3: K=512, fcs = mod_sigmoid(...) bf16 [8192][1040], 1025 valid
    prep_act_k<9, true, true><<<dim3(2048), blk, 0, stream>>>(h2b, mean, rstd, g2, be2, A);
    prepw_k<<<dim3(16, 36), blk, 0, stream>>>(w3, Bt, 512, 1025);
    gemm8<1><<<dim3(9, 64), gblk, 0, stream>>>(A, Bt, b3, fcsb, 512, 1025, 1040, nullptr, nullptr);
    // spectral filtering + window (fused), bf16 in/out
    fft_filter_kernel<<<dim3(8192), blk, 0, stream>>>(noise, fcsb, awb);
    // fused OLA + post conv + softsign
    ola_ppconv_kernel<<<dim3(1030, 16), blk, 0, stream>>>(awb, ppw, ppb, out);
    (void)in_sizes; (void)n_in; (void)out_size; (void)ws_size;
}

// Round 9
// 187.443 us; speedup vs baseline: 3.2468x; 1.0206x over previous
//
#include <hip/hip_runtime.h>
#include <hip/hip_bf16.h>
#include <math.h>

#define TARLEN 263680
#define POWEXP 2.302585092994046f  // ln(10)
#define PC(i) ((i) + ((i) >> 3))   // complex-unit LDS padding (1 per 8)

typedef __attribute__((ext_vector_type(8))) short bf16x8;
typedef __attribute__((ext_vector_type(8))) ushort u16x8;
typedef __attribute__((ext_vector_type(4))) float f32x4;

__device__ __forceinline__ void gload16(const void* g, void* l) {
    __builtin_amdgcn_global_load_lds((const __attribute__((address_space(1))) void*)g,
                                     (__attribute__((address_space(3))) void*)l, 16, 0, 0);
}

__device__ __forceinline__ float bf16f(ushort u) {
    union { uint u; float f; } v; v.u = (uint)u << 16; return v.f;
}
__device__ __forceinline__ ushort fbf16(float x) {
    __hip_bfloat16 h = __float2bfloat16(x);
    return *reinterpret_cast<ushort*>(&h);
}

__device__ __forceinline__ float norm_lrelu(float a, float m, float rs, float g, float b) {
    float x = (a - m) * rs * g + b;
    return x >= 0.f ? x : 0.2f * x;
}

// ============ unified GEMM: 128x128 tile, 512 thr, 8 waves of 64x32 =========
// C = A @ Bt^T, all bf16. LDS k-chunk XOR swizzle both sides (conflict-free,
// r5). 3-buffer deep pipeline, counted vmcnt(2) + raw s_barrier (r6-verified).
// EPI==0: fused BN column-stats partials. EPI==1: mod_sigmoid epilogue.
template<int EPI>
__global__ __launch_bounds__(512) void gemm8(
    const ushort* __restrict__ A, const ushort* __restrict__ Bt,
    const float* __restrict__ bias, ushort* __restrict__ C,
    int K, int Nvalid, int ldc,
    float* __restrict__ ps, float* __restrict__ pq)
{
    __shared__ ushort As[3][4096];  // [128][32] each
    __shared__ ushort Bs[3][4096];
    __shared__ float sred[8][2][16];
    __shared__ float qred[8][2][16];
    const int tid = threadIdx.x;
    const int lane = tid & 63;
    const int wid = tid >> 6;
    // bijective XCD swizzle (nwg % 8 == 0 for all our grids)
    const int nwg = gridDim.x * gridDim.y;
    const int bid = blockIdx.y * gridDim.x + blockIdx.x;
    const int q8 = nwg >> 3;
    const int swzb = (bid & 7) * q8 + (bid >> 3);
    const int bx = swzb % gridDim.x;
    const int by = swzb / gridDim.x;
    const int m0 = by * 128;
    const int n0 = bx * 128;
    const int NT = K >> 5;

    f32x4 acc[4][2];
#pragma unroll
    for (int m = 0; m < 4; ++m)
#pragma unroll
        for (int n = 0; n < 2; ++n)
            acc[m][n] = (f32x4){0.f, 0.f, 0.f, 0.f};

    const int srow = tid >> 2;                              // 0..127
    const int scol = (((tid & 3) ^ ((tid >> 3) & 3)) << 3); // swizzled src chunk

    auto stage = [&](int t, int buf) {
        const int k0 = t << 5;
        gload16(A + (size_t)(m0 + srow) * K + k0 + scol, &As[buf][tid * 8]);
        gload16(Bt + (size_t)(n0 + srow) * K + k0 + scol, &Bs[buf][tid * 8]);
    };

    const int lr = lane & 15;
    const int sw8 = (((lane >> 4) ^ ((lane >> 1) & 3)) << 3);  // swizzled read chunk
    const int wm0 = (wid >> 2) * 64;
    const int wn0 = (wid & 3) * 32;

    stage(0, 0);
    stage(1, 1);
    for (int t = 0; t < NT; ++t) {
        const int cur = t % 3;
        if (t + 2 < NT) {
            asm volatile("s_waitcnt vmcnt(2)" ::: "memory");  // own stage(t) landed
            __builtin_amdgcn_s_barrier();                     // all waves' stage(t) landed
            stage(t + 2, (t + 2) % 3);
        } else {
            asm volatile("s_waitcnt vmcnt(0)" ::: "memory");
            __builtin_amdgcn_s_barrier();
        }
        const ushort* as = As[cur];
        const ushort* bs = Bs[cur];
        bf16x8 af[4], bfv[2];
#pragma unroll
        for (int m = 0; m < 4; ++m)
            af[m] = *reinterpret_cast<const bf16x8*>(&as[(wm0 + m * 16 + lr) * 32 + sw8]);
#pragma unroll
        for (int n = 0; n < 2; ++n)
            bfv[n] = *reinterpret_cast<const bf16x8*>(&bs[(wn0 + n * 16 + lr) * 32 + sw8]);
#pragma unroll
        for (int m = 0; m < 4; ++m)
#pragma unroll
            for (int n = 0; n < 2; ++n)
                acc[m][n] = __builtin_amdgcn_mfma_f32_16x16x32_bf16(af[m], bfv[n], acc[m][n], 0, 0, 0);
    }
    __syncthreads();

    // epilogue: C/D layout col=lane&15, row=(lane>>4)*4+reg
    const int cr = (lane >> 4) << 2;
    const int cc = lane & 15;
    float sacc[2] = {0.f, 0.f}, qacc[2] = {0.f, 0.f};
#pragma unroll
    for (int m = 0; m < 4; ++m) {
#pragma unroll
        for (int n = 0; n < 2; ++n) {
            int gcol = n0 + wn0 + n * 16 + cc;
            if (EPI == 0 || gcol < Nvalid) {
                float bv = bias[gcol];
                int grow = m0 + wm0 + m * 16 + cr;
#pragma unroll
                for (int j = 0; j < 4; ++j) {
                    float v = acc[m][n][j] + bv;
                    if (EPI == 1) {
                        float sg = 1.f / (1.f + __expf(-v));
                        v = 2.f * __expf(POWEXP * __logf(sg)) + 1e-7f;
                    } else {
                        sacc[n] += v;
                        qacc[n] += v * v;
                    }
                    C[(size_t)(grow + j) * ldc + gcol] = fbf16(v);
                }
            }
        }
    }
    if (EPI == 0) {
#pragma unroll
        for (int n = 0; n < 2; ++n) {
            float s = sacc[n], q = qacc[n];
            s += __shfl_xor(s, 16); q += __shfl_xor(q, 16);
            s += __shfl_xor(s, 32); q += __shfl_xor(q, 32);
            if (lane < 16) { sred[wid][n][lane] = s; qred[wid][n][lane] = q; }
        }
        __syncthreads();
        if (tid < 128) {
            int wn_ = tid >> 5, n_ = (tid >> 4) & 1, cc_ = tid & 15;
            float s = sred[wn_][n_][cc_] + sred[4 + wn_][n_][cc_];
            float q = qred[wn_][n_][cc_] + qred[4 + wn_][n_][cc_];
            int col = n0 + wn_ * 32 + n_ * 16 + cc_;
            ps[(size_t)by * 512 + col] = s;
            pq[(size_t)by * 512 + col] = q;
        }
    }
}

// ---------------- prep: h (bf16 or f32) -> BN+LeakyReLU -> bf16 A ---------
template<int KSH, bool NORM, bool INBF16>
__global__ __launch_bounds__(256) void prep_act_k(
    const void* __restrict__ Hv, const float* __restrict__ mean,
    const float* __restrict__ rstd, const float* __restrict__ gamma,
    const float* __restrict__ beta, ushort* __restrict__ A)
{
    const int K = 1 << KSH;
    int idx = (blockIdx.x * 256 + threadIdx.x) << 3;
    int col = idx & (K - 1);
    float x[8];
    if (INBF16) {
        u16x8 hv = *reinterpret_cast<const u16x8*>((const ushort*)Hv + idx);
#pragma unroll
        for (int j = 0; j < 8; ++j) x[j] = bf16f(hv[j]);
    } else {
        const float* H = (const float*)Hv;
        float4 a = *reinterpret_cast<const float4*>(&H[idx]);
        float4 b = *reinterpret_cast<const float4*>(&H[idx + 4]);
        x[0] = a.x; x[1] = a.y; x[2] = a.z; x[3] = a.w;
        x[4] = b.x; x[5] = b.y; x[6] = b.z; x[7] = b.w;
    }
    if (NORM) {
#pragma unroll
        for (int h = 0; h < 2; ++h) {
            float4 mm = *reinterpret_cast<const float4*>(&mean[col + h * 4]);
            float4 rs = *reinterpret_cast<const float4*>(&rstd[col + h * 4]);
            float4 gg = *reinterpret_cast<const float4*>(&gamma[col + h * 4]);
            float4 bb = *reinterpret_cast<const float4*>(&beta[col + h * 4]);
            x[h * 4 + 0] = norm_lrelu(x[h * 4 + 0], mm.x, rs.x, gg.x, bb.x);
            x[h * 4 + 1] = norm_lrelu(x[h * 4 + 1], mm.y, rs.y, gg.y, bb.y);
            x[h * 4 + 2] = norm_lrelu(x[h * 4 + 2], mm.z, rs.z, gg.z, bb.z);
            x[h * 4 + 3] = norm_lrelu(x[h * 4 + 3], mm.w, rs.w, gg.w, bb.w);
        }
    }
    u16x8 o;
#pragma unroll
    for (int j = 0; j < 8; ++j) o[j] = fbf16(x[j]);
    *reinterpret_cast<u16x8*>(&A[idx]) = o;
}

// ---------------- batched weight transpose + bf16 (all 4 layers) ----------
__global__ __launch_bounds__(256) void prepw_all(
    const float* __restrict__ w0, const float* __restrict__ w1,
    const float* __restrict__ w2, const float* __restrict__ w3,
    ushort* __restrict__ B0, ushort* __restrict__ B1,
    ushort* __restrict__ B2, ushort* __restrict__ B3)
{
    const float* w; ushort* Bt; int K, N, GX, GY;
    switch (blockIdx.z) {
        case 0: w = w0; Bt = B0; K = 128; N = 512;  GX = 4;  GY = 16; break;
        case 1: w = w1; Bt = B1; K = 512; N = 512;  GX = 16; GY = 16; break;
        case 2: w = w2; Bt = B2; K = 512; N = 512;  GX = 16; GY = 16; break;
        default:w = w3; Bt = B3; K = 512; N = 1025; GX = 16; GY = 36; break;
    }
    if ((int)blockIdx.x >= GX || (int)blockIdx.y >= GY) return;
    __shared__ float tile[32][33];
    int k0 = blockIdx.x * 32, n0 = blockIdx.y * 32;
    int tx = threadIdx.x & 31, ty = threadIdx.x >> 5;  // 32 x 8
#pragma unroll
    for (int r = 0; r < 4; ++r) {
        int k = k0 + ty + r * 8;
        int n = n0 + tx;
        tile[ty + r * 8][tx] = (n < N) ? w[(size_t)k * N + n] : 0.f;
    }
    __syncthreads();
#pragma unroll
    for (int r = 0; r < 4; ++r) {
        int n = n0 + ty + r * 8;
        int k = k0 + tx;
        Bt[(size_t)n * K + k] = fbf16(tile[tx][ty + r * 8]);
    }
}

// ---------------- BN stats final reduce (64 row-block partials) -----------
__global__ __launch_bounds__(256) void colstats_final(
    const float* __restrict__ ps, const float* __restrict__ pq,
    float* __restrict__ mean, float* __restrict__ rstd)
{
    int c = blockIdx.x * 256 + threadIdx.x;
    float s = 0.f, q = 0.f;
    for (int rg = 0; rg < 64; ++rg) { s += ps[rg * 512 + c]; q += pq[rg * 512 + c]; }
    float m = s * (1.f / 8192.f);
    float v = q * (1.f / 8192.f) - m * m;
    mean[c] = m;
    rstd[c] = rsqrtf(v + 1e-5f);
}

// ---------------- Stockham radix-4 FFT, float2 LDS, hoisted twiddles ------
__device__ __forceinline__ float2 cmul(float2 a, float c, float s) {
    return make_float2(a.x * c - a.y * s, a.x * s + a.y * c);
}

// Stage twiddles for L: k=t&(L-1), base angle +2*pi*k/(4L). Forward = conj.
template<bool INV, int L>
__device__ __forceinline__ void stk_stage(
    const float2* __restrict__ s, float2* __restrict__ d, int t,
    float c1, float s1, float c2, float s2, float c3, float s3)
{
    int k = t & (L - 1);
    float2 x0 = s[PC(t)];
    float2 x1 = s[PC(t + 256)];
    float2 x2 = s[PC(t + 512)];
    float2 x3 = s[PC(t + 768)];
    if (L > 1) {
        if (!INV) {
            x1 = cmul(x1, c1, -s1);
            x2 = cmul(x2, c2, -s2);
            x3 = cmul(x3, c3, -s3);
        } else {
            x1 = cmul(x1, c1, s1);
            x2 = cmul(x2, c2, s2);
            x3 = cmul(x3, c3, s3);
        }
    }
    float2 a = make_float2(x0.x + x2.x, x0.y + x2.y);
    float2 b = make_float2(x0.x - x2.x, x0.y - x2.y);
    float2 c = make_float2(x1.x + x3.x, x1.y + x3.y);
    float2 e = make_float2(x1.x - x3.x, x1.y - x3.y);
    int db = ((t - k) << 2) + k;
    d[PC(db)]         = make_float2(a.x + c.x, a.y + c.y);
    d[PC(db + 2 * L)] = make_float2(a.x - c.x, a.y - c.y);
    if (!INV) {
        d[PC(db + L)]     = make_float2(b.x + e.y, b.y - e.x);
        d[PC(db + 3 * L)] = make_float2(b.x - e.y, b.y + e.x);
    } else {
        d[PC(db + L)]     = make_float2(b.x - e.y, b.y + e.x);
        d[PC(db + 3 * L)] = make_float2(b.x + e.y, b.y - e.x);
    }
}

// audio = irfft( rfft(noise_row) * H ), H[k] = (-1)^k*(0.5 fc[k]+0.25 fc[k-1]+0.25 fc[k+1])
// (analytic collapse of rfft(fftshift(irfft(fc)*FW))). 1/1024 folded into H.
// Twiddle sets for L={4,16,64,256} computed ONCE per thread, shared by both
// FFT directions (fwd=conj) and the fused final stage + OLA window.
__global__ __launch_bounds__(256) void fft_filter_kernel(
    const float* __restrict__ noise, const ushort* __restrict__ fcsb,
    ushort* __restrict__ awb)
{
    __shared__ float2 X[1152], Y[1152];
    __shared__ float F[1025];
    const int tid = threadIdx.x;
    const int r = blockIdx.x;

    const float2* nrow = reinterpret_cast<const float2*>(noise + ((size_t)r << 11));
    for (int i = tid; i < 1025; i += 256) F[i] = bf16f(fcsb[(size_t)r * 1040 + i]);

    // hoisted twiddle sets: tc1[si]=cos(2*pi*k/(4L)), L=4<<2si, k=t&(L-1)
    float tc1[4], ts1[4], tc2[4], ts2[4], tc3[4], ts3[4];
#pragma unroll
    for (int si = 0; si < 4; ++si) {
        const int L = 4 << (2 * si);
        int k = tid & (L - 1);
        float th = (float)(2.0 * M_PI) * (float)k / (float)(4 * L);
        float s1, c1; __sincosf(th, &s1, &c1);
        tc1[si] = c1; ts1[si] = s1;
        tc2[si] = c1 * c1 - s1 * s1; ts2[si] = 2.f * c1 * s1;
        tc3[si] = tc2[si] * c1 - ts2[si] * s1; ts3[si] = ts2[si] * c1 + tc2[si] * s1;
    }

    {
        // forward stage L=1 fused with global load (pack z[n]=x[2n]+i x[2n+1])
        float2 x0 = nrow[tid], x1 = nrow[tid + 256], x2 = nrow[tid + 512], x3 = nrow[tid + 768];
        float2 a = make_float2(x0.x + x2.x, x0.y + x2.y);
        float2 b = make_float2(x0.x - x2.x, x0.y - x2.y);
        float2 c = make_float2(x1.x + x3.x, x1.y + x3.y);
        float2 e = make_float2(x1.x - x3.x, x1.y - x3.y);
        int db = tid << 2;
        Y[PC(db)]     = make_float2(a.x + c.x, a.y + c.y);
        Y[PC(db + 1)] = make_float2(b.x + e.y, b.y - e.x);
        Y[PC(db + 2)] = make_float2(a.x - c.x, a.y - c.y);
        Y[PC(db + 3)] = make_float2(b.x - e.y, b.y + e.x);
    }
    __syncthreads();
    stk_stage<false, 4>(Y, X, tid, tc1[0], ts1[0], tc2[0], ts2[0], tc3[0], ts3[0]);   __syncthreads();
    stk_stage<false, 16>(X, Y, tid, tc1[1], ts1[1], tc2[1], ts2[1], tc3[1], ts3[1]);  __syncthreads();
    stk_stage<false, 64>(Y, X, tid, tc1[2], ts1[2], tc2[2], ts2[2], tc3[2], ts3[2]);  __syncthreads();
    stk_stage<false, 256>(X, Y, tid, tc1[3], ts1[3], tc2[3], ts2[3], tc3[3], ts3[3]); __syncthreads();
    // forward result in Y (natural order)

    // unpack real FFT, apply H (scaled by 1/1024), repack; read Y, write X
    const float INV1024 = 1.0f / 1024.0f;
    auto proc = [&](int k, float c, float s) {
        int k2 = (1024 - k) & 1023;
        float2 za = Y[PC(k)], zb = Y[PC(k2)];
        float Fer = 0.5f * (za.x + zb.x), Fei = 0.5f * (za.y - zb.y);
        float For = 0.5f * (za.y + zb.y), Foi = 0.5f * (zb.x - za.x);
        float wFr = c * For - s * Foi;
        float wFi = c * Foi + s * For;
        float Xkr = Fer + wFr, Xki = Fei + wFi;
        float Xbr = Fer - wFr, Xbi = wFi - Fei;
        float Hk, Hb;
        {
            float cl = (k == 0) ? F[1] : F[k - 1];
            float crr = (k == 1024) ? F[1023] : F[k + 1];
            float h = 0.5f * F[k] + 0.25f * (cl + crr);
            Hk = ((k & 1) ? -h : h) * INV1024;
        }
        {
            int kb = 1024 - k;
            float cl = (kb == 0) ? F[1] : F[kb - 1];
            float crr = (kb == 1024) ? F[1023] : F[kb + 1];
            float h = 0.5f * F[kb] + 0.25f * (cl + crr);
            Hb = ((kb & 1) ? -h : h) * INV1024;
        }
        float Ykr = Hk * Xkr, Yki = Hk * Xki;
        float Ybr = Hb * Xbr, Ybi = Hb * Xbi;
        if (k == 0) {
            X[PC(0)] = make_float2(0.5f * (Ykr + Ybr), 0.5f * (Ykr - Ybr));
        } else {
            float Ger = 0.5f * (Ykr + Ybr), Gei = 0.5f * (Yki - Ybi);
            float Sgr = 0.5f * (Ykr - Ybr), Sgi = 0.5f * (Yki + Ybi);
            float wpr = c, wpi = -s;
            float Gor = wpr * Sgr - wpi * Sgi;
            float Goi = wpr * Sgi + wpi * Sgr;
            X[PC(k)]  = make_float2(Ger - Goi, Gei + Gor);
            X[PC(k2)] = make_float2(Ger + Goi, Gor - Gei);
        }
    };
    {
        float s0, c0;
        __sincosf((float)(-M_PI / 1024.0) * tid, &s0, &c0);
        proc(tid, c0, s0);
        const float RT = 0.70710678118654752f;  // e^{-i pi/4}
        float c1 = (c0 + s0) * RT, s1 = (s0 - c0) * RT;
        proc(tid + 256, c1, s1);
        if (tid == 0) proc(512, 0.f, -1.f);
    }
    __syncthreads();

    stk_stage<true, 1>(X, Y, tid, 1.f, 0.f, 1.f, 0.f, 1.f, 0.f);  __syncthreads();
    stk_stage<true, 4>(Y, X, tid, tc1[0], ts1[0], tc2[0], ts2[0], tc3[0], ts3[0]);  __syncthreads();
    stk_stage<true, 16>(X, Y, tid, tc1[1], ts1[1], tc2[1], ts2[1], tc3[1], ts3[1]); __syncthreads();
    stk_stage<true, 64>(Y, X, tid, tc1[2], ts1[2], tc2[2], ts2[2], tc3[2], ts3[2]); __syncthreads();

    // inverse final stage (L=256) fused with OLA window + bf16 store;
    // twiddle = set3; window cos(2*pi*n/1024) at n=t+256q = rotations of set3.
    {
        const int g = r & 511;
        ushort2* awrow = reinterpret_cast<ushort2*>(awb + ((size_t)r << 11));
        int t = tid;
        float2 x0 = X[PC(t)], x1 = X[PC(t + 256)], x2 = X[PC(t + 512)], x3 = X[PC(t + 768)];
        float c1 = tc1[3], s1 = ts1[3];
        x1 = cmul(x1, c1, s1);
        x2 = cmul(x2, tc2[3], ts2[3]);
        x3 = cmul(x3, tc3[3], ts3[3]);
        float2 a = make_float2(x0.x + x2.x, x0.y + x2.y);
        float2 b = make_float2(x0.x - x2.x, x0.y - x2.y);
        float2 c = make_float2(x1.x + x3.x, x1.y + x3.y);
        float2 e = make_float2(x1.x - x3.x, x1.y - x3.y);
        float2 o[4];
        o[0] = make_float2(a.x + c.x, a.y + c.y);
        o[1] = make_float2(b.x - e.y, b.y + e.x);
        o[2] = make_float2(a.x - c.x, a.y - c.y);
        o[3] = make_float2(b.x + e.y, b.y - e.x);
        float cq[4] = {c1, -s1, -c1, s1};
        float sq[4] = {s1, c1, -s1, -c1};
        const float COSD = 0.99999529380958f;   // cos(pi/1024)
        const float SIND = 0.00306795676296f;   // sin(pi/1024)
#pragma unroll
        for (int q = 0; q < 4; ++q) {
            int n = t + 256 * q;
            float w0, w1;
            bool edge = (g == 0 && q < 2) || (g == 511 && q >= 2);
            if (edge) { w0 = 1.f; w1 = 1.f; }
            else {
                w0 = 0.5f - 0.5f * cq[q];
                w1 = 0.5f - 0.5f * (cq[q] * COSD - sq[q] * SIND);
            }
            ushort2 ov; ov.x = fbf16(o[q].x * w0); ov.y = fbf16(o[q].y * w1);
            awrow[n] = ov;
        }
    }
}

// ---------------- fused OLA gather + 65-tap conv + softsign ---------------
__global__ __launch_bounds__(256) void ola_ppconv_kernel(
    const ushort* __restrict__ awb, const float* __restrict__ ppw,
    const float* __restrict__ ppb, float* __restrict__ out)
{
    __shared__ float tile[320];
    __shared__ float Ksh[65];
    int t0 = blockIdx.x * 256;
    int b = blockIdx.y;
    for (int i = threadIdx.x; i < 320; i += 256) {
        int tt = t0 - 32 + i;
        float v = 0.f;
        if (tt >= 0 && tt < TARLEN) {
            int ghi = min(511, tt >> 9);
            int glo = max(0, (tt - 1536) >> 9);
            float s = 0.f;
            for (int g = glo; g <= ghi; ++g) {
                int n = tt - (g << 9);
                s += bf16f(awb[((size_t)(b * 512 + g) << 11) + n]);
            }
            v = s / (float)(ghi - glo + 1);
        }
        tile[i] = v;
    }
    if (threadIdx.x < 65) {
        float k = 0.f;
#pragma unroll
        for (int c = 0; c < 5; ++c) k += ppw[c * 65 + threadIdx.x];
        Ksh[threadIdx.x] = k;
    }
    __syncthreads();
    float y = ppb[0];
#pragma unroll
    for (int j = 0; j < 65; ++j) y = fmaf(Ksh[j], tile[threadIdx.x + j], y);
    int t = t0 + threadIdx.x;
    out[(size_t)b * TARLEN + t] = y / (1.f + fabsf(y));
}

// ---------------- launch --------------------------------------------------
extern "C" void kernel_launch(void* const* d_in, const int* in_sizes, int n_in,
                              void* d_out, int out_size, void* d_ws, size_t ws_size,
                              hipStream_t stream) {
    const float* z    = (const float*)d_in[0];
    const float* w0   = (const float*)d_in[1];
    const float* b0   = (const float*)d_in[2];
    const float* g0   = (const float*)d_in[3];
    const float* be0  = (const float*)d_in[4];
    const float* w1   = (const float*)d_in[5];
    const float* b1   = (const float*)d_in[6];
    const float* g1   = (const float*)d_in[7];
    const float* be1  = (const float*)d_in[8];
    const float* w2   = (const float*)d_in[9];
    const float* b2   = (const float*)d_in[10];
    const float* g2   = (const float*)d_in[11];
    const float* be2  = (const float*)d_in[12];
    const float* w3   = (const float*)d_in[13];
    const float* b3   = (const float*)d_in[14];
    const float* ppw  = (const float*)d_in[15];
    const float* ppb  = (const float*)d_in[16];
    const float* noise= (const float*)d_in[17];
    float* out = (float*)d_out;
    float* ws = (float*)d_ws;

    // workspace (float offsets)
    ushort* h0b = (ushort*)ws;                    // 8192*512 bf16 = 2,097,152 f
    ushort* h1b = (ushort*)(ws + 2097152);        // 8192*512 bf16
    float* ps   = ws + 4194304;                   // 64*512
    float* pq   = ps + 32768;                     // 64*512
    float* mean = pq + 32768;                     // 512
    float* rstd = mean + 512;                     // 512
    float* base = rstd + 512;
    ushort* Bt0 = (ushort*)base;                  // 512*128  bf16 = 32768 f
    ushort* Bt1 = (ushort*)(base + 32768);        // 512*512  bf16 = 131072 f
    ushort* Bt2 = (ushort*)(base + 163840);       // 512*512  bf16 = 131072 f
    ushort* Bt3 = (ushort*)(base + 294912);       // 1152*512 bf16 = 294912 f
    ushort* fcsb= (ushort*)(base + 589824);       // 8192*1040 bf16 = 4,259,840 f
    ushort* awb = (ushort*)(base + 589824 + 4259840);            // 8192*2048 bf16
    ushort* A   = (ushort*)(base + 589824 + 4259840 + 8388608);  // 8192*512 bf16
    ushort* h2b = h0b;  // h0 dead after its prep

    dim3 blk(256);
    dim3 gblk(512);
    // all weight transposes in one launch (inputs only)
    prepw_all<<<dim3(16, 36, 4), blk, 0, stream>>>(w0, w1, w2, w3, Bt0, Bt1, Bt2, Bt3);
    // layer 0: h0 = z @ w0 + b0 (+ fused col stats); K=128
    prep_act_k<7, false, false><<<dim3(512), blk, 0, stream>>>(z, nullptr, nullptr, nullptr, nullptr, A);
    gemm8<0><<<dim3(4, 64), gblk, 0, stream>>>(A, Bt0, b0, h0b, 128, 512, 512, ps, pq);
    colstats_final<<<dim3(2), blk, 0, stream>>>(ps, pq, mean, rstd);
    // layer 1: K=512
    prep_act_k<9, true, true><<<dim3(2048), blk, 0, stream>>>(h0b, mean, rstd, g0, be0, A);
    gemm8<0><<<dim3(4, 64), gblk, 0, stream>>>(A, Bt1, b1, h1b, 512, 512, 512, ps, pq);
    colstats_final<<<dim3(2), blk, 0, stream>>>(ps, pq, mean, rstd);
    // layer 2
    prep_act_k<9, true, true><<<dim3(2048), blk, 0, stream>>>(h1b, mean, rstd, g1, be1, A);
    gemm8<0><<<dim3(4, 64), gblk, 0, stream>>>(A, Bt2, b2, h2b, 512, 512, 512, ps, pq);
    colstats_final<<<dim3(2), blk, 0, stream>>>(ps, pq, mean, rstd);
    // layer 3: K=512, fcs = mod_sigmoid(...) bf16 [8192][1040], 1025 valid
    prep_act_k<9, true, true><<<dim3(2048), blk, 0, stream>>>(h2b, mean, rstd, g2, be2, A);
    gemm8<1><<<dim3(9, 64), gblk, 0, stream>>>(A, Bt3, b3, fcsb, 512, 1025, 1040, nullptr, nullptr);
    // spectral filtering + window (fused), bf16 in/out
    fft_filter_kernel<<<dim3(8192), blk, 0, stream>>>(noise, fcsb, awb);
    // fused OLA + post conv + softsign
    ola_ppconv_kernel<<<dim3(1030, 16), blk, 0, stream>>>(awb, ppw, ppb, out);
    (void)in_sizes; (void)n_in; (void)out_size; (void)ws_size;
}

// Round 10
// 175.970 us; speedup vs baseline: 3.4585x; 1.0652x over previous
//
#include <hip/hip_runtime.h>
#include <hip/hip_bf16.h>
#include <math.h>

#define TARLEN 263680
#define POWEXP 2.302585092994046f  // ln(10)
#define PC(i) ((i) + ((i) >> 3))   // complex-unit LDS padding (1 per 8)

typedef __attribute__((ext_vector_type(8))) short bf16x8;
typedef __attribute__((ext_vector_type(8))) ushort u16x8;
typedef __attribute__((ext_vector_type(4))) float f32x4;

__device__ __forceinline__ void gload16(const void* g, void* l) {
    __builtin_amdgcn_global_load_lds((const __attribute__((address_space(1))) void*)g,
                                     (__attribute__((address_space(3))) void*)l, 16, 0, 0);
}

__device__ __forceinline__ float bf16f(ushort u) {
    union { uint u; float f; } v; v.u = (uint)u << 16; return v.f;
}
__device__ __forceinline__ ushort fbf16(float x) {
    __hip_bfloat16 h = __float2bfloat16(x);
    return *reinterpret_cast<ushort*>(&h);
}

// ============ unified GEMM: 128x128 tile, 512 thr, 8 waves of 64x32 =========
// C = A @ Bt^T, all bf16. LDS k-chunk XOR swizzle both sides (conflict-free,
// r5). 3-buffer deep pipeline, counted vmcnt(2) + raw s_barrier (r6-verified).
// EPI==0: fused BN column-stats partials. EPI==1: mod_sigmoid epilogue.
template<int EPI>
__global__ __launch_bounds__(512) void gemm8(
    const ushort* __restrict__ A, const ushort* __restrict__ Bt,
    const float* __restrict__ bias, ushort* __restrict__ C,
    int K, int Nvalid, int ldc,
    float* __restrict__ ps, float* __restrict__ pq)
{
    __shared__ ushort As[3][4096];  // [128][32] each
    __shared__ ushort Bs[3][4096];
    __shared__ float sred[8][2][16];
    __shared__ float qred[8][2][16];
    const int tid = threadIdx.x;
    const int lane = tid & 63;
    const int wid = tid >> 6;
    // bijective XCD swizzle (nwg % 8 == 0 for all our grids)
    const int nwg = gridDim.x * gridDim.y;
    const int bid = blockIdx.y * gridDim.x + blockIdx.x;
    const int q8 = nwg >> 3;
    const int swzb = (bid & 7) * q8 + (bid >> 3);
    const int bx = swzb % gridDim.x;
    const int by = swzb / gridDim.x;
    const int m0 = by * 128;
    const int n0 = bx * 128;
    const int NT = K >> 5;

    f32x4 acc[4][2];
#pragma unroll
    for (int m = 0; m < 4; ++m)
#pragma unroll
        for (int n = 0; n < 2; ++n)
            acc[m][n] = (f32x4){0.f, 0.f, 0.f, 0.f};

    const int srow = tid >> 2;                              // 0..127
    const int scol = (((tid & 3) ^ ((tid >> 3) & 3)) << 3); // swizzled src chunk

    auto stage = [&](int t, int buf) {
        const int k0 = t << 5;
        gload16(A + (size_t)(m0 + srow) * K + k0 + scol, &As[buf][tid * 8]);
        gload16(Bt + (size_t)(n0 + srow) * K + k0 + scol, &Bs[buf][tid * 8]);
    };

    const int lr = lane & 15;
    const int sw8 = (((lane >> 4) ^ ((lane >> 1) & 3)) << 3);  // swizzled read chunk
    const int wm0 = (wid >> 2) * 64;
    const int wn0 = (wid & 3) * 32;

    stage(0, 0);
    stage(1, 1);
    for (int t = 0; t < NT; ++t) {
        const int cur = t % 3;
        if (t + 2 < NT) {
            asm volatile("s_waitcnt vmcnt(2)" ::: "memory");  // own stage(t) landed
            __builtin_amdgcn_s_barrier();                     // all waves' stage(t) landed
            stage(t + 2, (t + 2) % 3);
        } else {
            asm volatile("s_waitcnt vmcnt(0)" ::: "memory");
            __builtin_amdgcn_s_barrier();
        }
        const ushort* as = As[cur];
        const ushort* bs = Bs[cur];
        bf16x8 af[4], bfv[2];
#pragma unroll
        for (int m = 0; m < 4; ++m)
            af[m] = *reinterpret_cast<const bf16x8*>(&as[(wm0 + m * 16 + lr) * 32 + sw8]);
#pragma unroll
        for (int n = 0; n < 2; ++n)
            bfv[n] = *reinterpret_cast<const bf16x8*>(&bs[(wn0 + n * 16 + lr) * 32 + sw8]);
#pragma unroll
        for (int m = 0; m < 4; ++m)
#pragma unroll
            for (int n = 0; n < 2; ++n)
                acc[m][n] = __builtin_amdgcn_mfma_f32_16x16x32_bf16(af[m], bfv[n], acc[m][n], 0, 0, 0);
    }
    __syncthreads();

    // epilogue: C/D layout col=lane&15, row=(lane>>4)*4+reg
    const int cr = (lane >> 4) << 2;
    const int cc = lane & 15;
    float sacc[2] = {0.f, 0.f}, qacc[2] = {0.f, 0.f};
#pragma unroll
    for (int m = 0; m < 4; ++m) {
#pragma unroll
        for (int n = 0; n < 2; ++n) {
            int gcol = n0 + wn0 + n * 16 + cc;
            if (EPI == 0 || gcol < Nvalid) {
                float bv = bias[gcol];
                int grow = m0 + wm0 + m * 16 + cr;
#pragma unroll
                for (int j = 0; j < 4; ++j) {
                    float v = acc[m][n][j] + bv;
                    if (EPI == 1) {
                        float sg = 1.f / (1.f + __expf(-v));
                        v = 2.f * __expf(POWEXP * __logf(sg)) + 1e-7f;
                    } else {
                        sacc[n] += v;
                        qacc[n] += v * v;
                    }
                    C[(size_t)(grow + j) * ldc + gcol] = fbf16(v);
                }
            }
        }
    }
    if (EPI == 0) {
#pragma unroll
        for (int n = 0; n < 2; ++n) {
            float s = sacc[n], q = qacc[n];
            s += __shfl_xor(s, 16); q += __shfl_xor(q, 16);
            s += __shfl_xor(s, 32); q += __shfl_xor(q, 32);
            if (lane < 16) { sred[wid][n][lane] = s; qred[wid][n][lane] = q; }
        }
        __syncthreads();
        if (tid < 128) {
            int wn_ = tid >> 5, n_ = (tid >> 4) & 1, cc_ = tid & 15;
            float s = sred[wn_][n_][cc_] + sred[4 + wn_][n_][cc_];
            float q = qred[wn_][n_][cc_] + qred[4 + wn_][n_][cc_];
            int col = n0 + wn_ * 32 + n_ * 16 + cc_;
            ps[(size_t)by * 512 + col] = s;
            pq[(size_t)by * 512 + col] = q;
        }
    }
}

// ---------------- prep layer 0: z (f32) -> bf16 A -------------------------
__global__ __launch_bounds__(256) void prep0_k(
    const float* __restrict__ H, ushort* __restrict__ A)
{
    int idx = (blockIdx.x * 256 + threadIdx.x) << 3;
    float4 a = *reinterpret_cast<const float4*>(&H[idx]);
    float4 b = *reinterpret_cast<const float4*>(&H[idx + 4]);
    float x[8] = {a.x, a.y, a.z, a.w, b.x, b.y, b.z, b.w};
    u16x8 o;
#pragma unroll
    for (int j = 0; j < 8; ++j) o[j] = fbf16(x[j]);
    *reinterpret_cast<u16x8*>(&A[idx]) = o;
}

// ---------------- fused: BN-stats final reduce + BN + LeakyReLU + bf16 ----
// Each block: (1) reduce 64 row-block partials -> per-column affine
// x*a+b (a=rs*g, b=be-m*a), deterministic fixed-order sum; (2) transform
// its 32 rows. Per-thread columns are fixed -> affine cached in registers.
__global__ __launch_bounds__(256) void prep_stats_act_k(
    const ushort* __restrict__ Hb, const float* __restrict__ ps,
    const float* __restrict__ pq, const float* __restrict__ gamma,
    const float* __restrict__ beta, ushort* __restrict__ A)
{
    __shared__ float sa[512], sb[512];
    const int tid = threadIdx.x;
    for (int c = tid; c < 512; c += 256) {
        float s = 0.f, q = 0.f;
        for (int rg = 0; rg < 64; ++rg) { s += ps[rg * 512 + c]; q += pq[rg * 512 + c]; }
        float m = s * (1.f / 8192.f);
        float v = q * (1.f / 8192.f) - m * m;
        float rs = rsqrtf(v + 1e-5f);
        float a = rs * gamma[c];
        sa[c] = a;
        sb[c] = beta[c] - m * a;
    }
    __syncthreads();
    const int col0 = (tid * 8) & 511;
    float ra[8], rb[8];
#pragma unroll
    for (int j = 0; j < 8; ++j) { ra[j] = sa[col0 + j]; rb[j] = sb[col0 + j]; }
    size_t base = (size_t)blockIdx.x * 16384;  // 32 rows * 512 cols
#pragma unroll
    for (int it = 0; it < 8; ++it) {
        int off = (it * 256 + tid) << 3;       // col = (tid*8)&511 for all it
        u16x8 hv = *reinterpret_cast<const u16x8*>(&Hb[base + off]);
        u16x8 o;
#pragma unroll
        for (int j = 0; j < 8; ++j) {
            float y = fmaf(bf16f(hv[j]), ra[j], rb[j]);
            o[j] = fbf16(y >= 0.f ? y : 0.2f * y);
        }
        *reinterpret_cast<u16x8*>(&A[base + off]) = o;
    }
}

// ---------------- batched weight transpose + bf16 (all 4 layers) ----------
__global__ __launch_bounds__(256) void prepw_all(
    const float* __restrict__ w0, const float* __restrict__ w1,
    const float* __restrict__ w2, const float* __restrict__ w3,
    ushort* __restrict__ B0, ushort* __restrict__ B1,
    ushort* __restrict__ B2, ushort* __restrict__ B3)
{
    const float* w; ushort* Bt; int K, N, GX, GY;
    switch (blockIdx.z) {
        case 0: w = w0; Bt = B0; K = 128; N = 512;  GX = 4;  GY = 16; break;
        case 1: w = w1; Bt = B1; K = 512; N = 512;  GX = 16; GY = 16; break;
        case 2: w = w2; Bt = B2; K = 512; N = 512;  GX = 16; GY = 16; break;
        default:w = w3; Bt = B3; K = 512; N = 1025; GX = 16; GY = 36; break;
    }
    if ((int)blockIdx.x >= GX || (int)blockIdx.y >= GY) return;
    __shared__ float tile[32][33];
    int k0 = blockIdx.x * 32, n0 = blockIdx.y * 32;
    int tx = threadIdx.x & 31, ty = threadIdx.x >> 5;  // 32 x 8
#pragma unroll
    for (int r = 0; r < 4; ++r) {
        int k = k0 + ty + r * 8;
        int n = n0 + tx;
        tile[ty + r * 8][tx] = (n < N) ? w[(size_t)k * N + n] : 0.f;
    }
    __syncthreads();
#pragma unroll
    for (int r = 0; r < 4; ++r) {
        int n = n0 + ty + r * 8;
        int k = k0 + tx;
        Bt[(size_t)n * K + k] = fbf16(tile[tx][ty + r * 8]);
    }
}

// ---------------- Stockham radix-4 FFT, float2 LDS, 256 threads (r8) ------
__device__ __forceinline__ float2 cmul(float2 a, float c, float s) {
    return make_float2(a.x * c - a.y * s, a.x * s + a.y * c);
}

template<bool INV, int L>
__device__ __forceinline__ void stk_stage(
    const float2* __restrict__ s, float2* __restrict__ d, int t)
{
    int k = t & (L - 1);
    float2 x0 = s[PC(t)];
    float2 x1 = s[PC(t + 256)];
    float2 x2 = s[PC(t + 512)];
    float2 x3 = s[PC(t + 768)];
    if (L > 1) {
        float th = (INV ? 2.0f : -2.0f) * (float)M_PI * (float)k / (float)(4 * L);
        float s1, c1; __sincosf(th, &s1, &c1);
        float c2 = c1 * c1 - s1 * s1, s2 = 2.f * c1 * s1;
        float c3 = c2 * c1 - s2 * s1, s3 = s2 * c1 + c2 * s1;
        x1 = cmul(x1, c1, s1);
        x2 = cmul(x2, c2, s2);
        x3 = cmul(x3, c3, s3);
    }
    float2 a = make_float2(x0.x + x2.x, x0.y + x2.y);
    float2 b = make_float2(x0.x - x2.x, x0.y - x2.y);
    float2 c = make_float2(x1.x + x3.x, x1.y + x3.y);
    float2 e = make_float2(x1.x - x3.x, x1.y - x3.y);
    int db = ((t - k) << 2) + k;
    d[PC(db)]         = make_float2(a.x + c.x, a.y + c.y);
    d[PC(db + 2 * L)] = make_float2(a.x - c.x, a.y - c.y);
    if (!INV) {
        d[PC(db + L)]     = make_float2(b.x + e.y, b.y - e.x);
        d[PC(db + 3 * L)] = make_float2(b.x - e.y, b.y + e.x);
    } else {
        d[PC(db + L)]     = make_float2(b.x - e.y, b.y + e.x);
        d[PC(db + 3 * L)] = make_float2(b.x + e.y, b.y - e.x);
    }
}

// audio = irfft( rfft(noise_row) * H ), H[k] = (-1)^k*(0.5 fc[k]+0.25 fc[k-1]+0.25 fc[k+1])
// (analytic collapse of rfft(fftshift(irfft(fc)*FW))). 1/1024 folded into H.
// fcs read as bf16; aw written as bf16. OLA window from final-stage twiddle.
__global__ __launch_bounds__(256) void fft_filter_kernel(
    const float* __restrict__ noise, const ushort* __restrict__ fcsb,
    ushort* __restrict__ awb)
{
    __shared__ float2 X[1152], Y[1152];
    __shared__ float F[1025];
    const int tid = threadIdx.x;
    const int r = blockIdx.x;

    const float2* nrow = reinterpret_cast<const float2*>(noise + ((size_t)r << 11));
    for (int i = tid; i < 1025; i += 256) F[i] = bf16f(fcsb[(size_t)r * 1040 + i]);
    {
        // forward stage L=1 fused with global load (pack z[n]=x[2n]+i x[2n+1])
        float2 x0 = nrow[tid], x1 = nrow[tid + 256], x2 = nrow[tid + 512], x3 = nrow[tid + 768];
        float2 a = make_float2(x0.x + x2.x, x0.y + x2.y);
        float2 b = make_float2(x0.x - x2.x, x0.y - x2.y);
        float2 c = make_float2(x1.x + x3.x, x1.y + x3.y);
        float2 e = make_float2(x1.x - x3.x, x1.y - x3.y);
        int db = tid << 2;
        Y[PC(db)]     = make_float2(a.x + c.x, a.y + c.y);
        Y[PC(db + 1)] = make_float2(b.x + e.y, b.y - e.x);
        Y[PC(db + 2)] = make_float2(a.x - c.x, a.y - c.y);
        Y[PC(db + 3)] = make_float2(b.x - e.y, b.y + e.x);
    }
    __syncthreads();
    stk_stage<false, 4>(Y, X, tid);   __syncthreads();
    stk_stage<false, 16>(X, Y, tid);  __syncthreads();
    stk_stage<false, 64>(Y, X, tid);  __syncthreads();
    stk_stage<false, 256>(X, Y, tid); __syncthreads();
    // forward result in Y (natural order)

    // unpack real FFT, apply H (scaled by 1/1024), repack; read Y, write X
    const float INV1024 = 1.0f / 1024.0f;
    auto proc = [&](int k, float c, float s) {
        int k2 = (1024 - k) & 1023;
        float2 za = Y[PC(k)], zb = Y[PC(k2)];
        float Fer = 0.5f * (za.x + zb.x), Fei = 0.5f * (za.y - zb.y);
        float For = 0.5f * (za.y + zb.y), Foi = 0.5f * (zb.x - za.x);
        float wFr = c * For - s * Foi;
        float wFi = c * Foi + s * For;
        float Xkr = Fer + wFr, Xki = Fei + wFi;
        float Xbr = Fer - wFr, Xbi = wFi - Fei;
        float Hk, Hb;
        {
            float cl = (k == 0) ? F[1] : F[k - 1];
            float crr = (k == 1024) ? F[1023] : F[k + 1];
            float h = 0.5f * F[k] + 0.25f * (cl + crr);
            Hk = ((k & 1) ? -h : h) * INV1024;
        }
        {
            int kb = 1024 - k;
            float cl = (kb == 0) ? F[1] : F[kb - 1];
            float crr = (kb == 1024) ? F[1023] : F[kb + 1];
            float h = 0.5f * F[kb] + 0.25f * (cl + crr);
            Hb = ((kb & 1) ? -h : h) * INV1024;
        }
        float Ykr = Hk * Xkr, Yki = Hk * Xki;
        float Ybr = Hb * Xbr, Ybi = Hb * Xbi;
        if (k == 0) {
            X[PC(0)] = make_float2(0.5f * (Ykr + Ybr), 0.5f * (Ykr - Ybr));
        } else {
            float Ger = 0.5f * (Ykr + Ybr), Gei = 0.5f * (Yki - Ybi);
            float Sgr = 0.5f * (Ykr - Ybr), Sgi = 0.5f * (Yki + Ybi);
            float wpr = c, wpi = -s;
            float Gor = wpr * Sgr - wpi * Sgi;
            float Goi = wpr * Sgi + wpi * Sgr;
            X[PC(k)]  = make_float2(Ger - Goi, Gei + Gor);
            X[PC(k2)] = make_float2(Ger + Goi, Gor - Gei);
        }
    };
    {
        float s0, c0;
        __sincosf((float)(-M_PI / 1024.0) * tid, &s0, &c0);
        proc(tid, c0, s0);
        const float RT = 0.70710678118654752f;  // e^{-i pi/4}
        float c1 = (c0 + s0) * RT, s1 = (s0 - c0) * RT;
        proc(tid + 256, c1, s1);
        if (tid == 0) proc(512, 0.f, -1.f);
    }
    __syncthreads();

    stk_stage<true, 1>(X, Y, tid);  __syncthreads();
    stk_stage<true, 4>(Y, X, tid);  __syncthreads();
    stk_stage<true, 16>(X, Y, tid); __syncthreads();
    stk_stage<true, 64>(Y, X, tid); __syncthreads();

    // inverse final stage (L=256) fused with OLA window + bf16 store;
    // window cos(2*pi*n/1024) at n=t+256q derived from the twiddle (c1,s1).
    {
        const int g = r & 511;
        ushort2* awrow = reinterpret_cast<ushort2*>(awb + ((size_t)r << 11));
        int t = tid;
        float2 x0 = X[PC(t)], x1 = X[PC(t + 256)], x2 = X[PC(t + 512)], x3 = X[PC(t + 768)];
        float th = (float)(2.0 * M_PI / 1024.0) * t;
        float s1, c1; __sincosf(th, &s1, &c1);
        float c2 = c1 * c1 - s1 * s1, s2 = 2.f * c1 * s1;
        float c3 = c2 * c1 - s2 * s1, s3 = s2 * c1 + c2 * s1;
        x1 = cmul(x1, c1, s1);
        x2 = cmul(x2, c2, s2);
        x3 = cmul(x3, c3, s3);
        float2 a = make_float2(x0.x + x2.x, x0.y + x2.y);
        float2 b = make_float2(x0.x - x2.x, x0.y - x2.y);
        float2 c = make_float2(x1.x + x3.x, x1.y + x3.y);
        float2 e = make_float2(x1.x - x3.x, x1.y - x3.y);
        float2 o[4];
        o[0] = make_float2(a.x + c.x, a.y + c.y);
        o[1] = make_float2(b.x - e.y, b.y + e.x);
        o[2] = make_float2(a.x - c.x, a.y - c.y);
        o[3] = make_float2(b.x + e.y, b.y - e.x);
        float cq[4] = {c1, -s1, -c1, s1};
        float sq[4] = {s1, c1, -s1, -c1};
        const float COSD = 0.99999529380958f;   // cos(pi/1024)
        const float SIND = 0.00306795676296f;   // sin(pi/1024)
#pragma unroll
        for (int q = 0; q < 4; ++q) {
            int n = t + 256 * q;
            float w0, w1;
            bool edge = (g == 0 && q < 2) || (g == 511 && q >= 2);
            if (edge) { w0 = 1.f; w1 = 1.f; }
            else {
                w0 = 0.5f - 0.5f * cq[q];
                w1 = 0.5f - 0.5f * (cq[q] * COSD - sq[q] * SIND);
            }
            ushort2 ov; ov.x = fbf16(o[q].x * w0); ov.y = fbf16(o[q].y * w1);
            awrow[n] = ov;
        }
    }
}

// ---------------- fused OLA gather + 65-tap conv + softsign ---------------
__global__ __launch_bounds__(256) void ola_ppconv_kernel(
    const ushort* __restrict__ awb, const float* __restrict__ ppw,
    const float* __restrict__ ppb, float* __restrict__ out)
{
    __shared__ float tile[320];
    __shared__ float Ksh[65];
    int t0 = blockIdx.x * 256;
    int b = blockIdx.y;
    for (int i = threadIdx.x; i < 320; i += 256) {
        int tt = t0 - 32 + i;
        float v = 0.f;
        if (tt >= 0 && tt < TARLEN) {
            int ghi = min(511, tt >> 9);
            int glo = max(0, (tt - 1536) >> 9);
            float s = 0.f;
            for (int g = glo; g <= ghi; ++g) {
                int n = tt - (g << 9);
                s += bf16f(awb[((size_t)(b * 512 + g) << 11) + n]);
            }
            v = s / (float)(ghi - glo + 1);
        }
        tile[i] = v;
    }
    if (threadIdx.x < 65) {
        float k = 0.f;
#pragma unroll
        for (int c = 0; c < 5; ++c) k += ppw[c * 65 + threadIdx.x];
        Ksh[threadIdx.x] = k;
    }
    __syncthreads();
    float y = ppb[0];
#pragma unroll
    for (int j = 0; j < 65; ++j) y = fmaf(Ksh[j], tile[threadIdx.x + j], y);
    int t = t0 + threadIdx.x;
    out[(size_t)b * TARLEN + t] = y / (1.f + fabsf(y));
}

// ---------------- launch --------------------------------------------------
extern "C" void kernel_launch(void* const* d_in, const int* in_sizes, int n_in,
                              void* d_out, int out_size, void* d_ws, size_t ws_size,
                              hipStream_t stream) {
    const float* z    = (const float*)d_in[0];
    const float* w0   = (const float*)d_in[1];
    const float* b0   = (const float*)d_in[2];
    const float* g0   = (const float*)d_in[3];
    const float* be0  = (const float*)d_in[4];
    const float* w1   = (const float*)d_in[5];
    const float* b1   = (const float*)d_in[6];
    const float* g1   = (const float*)d_in[7];
    const float* be1  = (const float*)d_in[8];
    const float* w2   = (const float*)d_in[9];
    const float* b2   = (const float*)d_in[10];
    const float* g2   = (const float*)d_in[11];
    const float* be2  = (const float*)d_in[12];
    const float* w3   = (const float*)d_in[13];
    const float* b3   = (const float*)d_in[14];
    const float* ppw  = (const float*)d_in[15];
    const float* ppb  = (const float*)d_in[16];
    const float* noise= (const float*)d_in[17];
    float* out = (float*)d_out;
    float* ws = (float*)d_ws;

    // workspace (float offsets)
    ushort* h0b = (ushort*)ws;                    // 8192*512 bf16 = 2,097,152 f
    ushort* h1b = (ushort*)(ws + 2097152);        // 8192*512 bf16
    float* ps   = ws + 4194304;                   // 64*512
    float* pq   = ps + 32768;                     // 64*512
    float* base = pq + 32768 + 1024;              // (old mean/rstd slot, unused)
    ushort* Bt0 = (ushort*)base;                  // 512*128  bf16 = 32768 f
    ushort* Bt1 = (ushort*)(base + 32768);        // 512*512  bf16 = 131072 f
    ushort* Bt2 = (ushort*)(base + 163840);       // 512*512  bf16 = 131072 f
    ushort* Bt3 = (ushort*)(base + 294912);       // 1152*512 bf16 = 294912 f
    ushort* fcsb= (ushort*)(base + 589824);       // 8192*1040 bf16 = 4,259,840 f
    ushort* awb = (ushort*)(base + 589824 + 4259840);            // 8192*2048 bf16
    ushort* A   = (ushort*)(base + 589824 + 4259840 + 8388608);  // 8192*512 bf16
    ushort* h2b = h0b;  // h0 dead after its prep

    dim3 blk(256);
    dim3 gblk(512);
    // all weight transposes in one launch (inputs only)
    prepw_all<<<dim3(16, 36, 4), blk, 0, stream>>>(w0, w1, w2, w3, Bt0, Bt1, Bt2, Bt3);
    // layer 0: h0 = z @ w0 + b0 (+ fused col stats); K=128
    prep0_k<<<dim3(512), blk, 0, stream>>>(z, A);
    gemm8<0><<<dim3(4, 64), gblk, 0, stream>>>(A, Bt0, b0, h0b, 128, 512, 512, ps, pq);
    // layer 1: fused stats+BN+lrelu prep, then gemm; K=512
    prep_stats_act_k<<<dim3(256), blk, 0, stream>>>(h0b, ps, pq, g0, be0, A);
    gemm8<0><<<dim3(4, 64), gblk, 0, stream>>>(A, Bt1, b1, h1b, 512, 512, 512, ps, pq);
    // layer 2
    prep_stats_act_k<<<dim3(256), blk, 0, stream>>>(h1b, ps, pq, g1, be1, A);
    gemm8<0><<<dim3(4, 64), gblk, 0, stream>>>(A, Bt2, b2, h2b, 512, 512, 512, ps, pq);
    // layer 3: K=512, fcs = mod_sigmoid(...) bf16 [8192][1040], 1025 valid
    prep_stats_act_k<<<dim3(256), blk, 0, stream>>>(h2b, ps, pq, g2, be2, A);
    gemm8<1><<<dim3(9, 64), gblk, 0, stream>>>(A, Bt3, b3, fcsb, 512, 1025, 1040, nullptr, nullptr);
    // spectral filtering + window (fused), bf16 in/out
    fft_filter_kernel<<<dim3(8192), blk, 0, stream>>>(noise, fcsb, awb);
    // fused OLA + post conv + softsign
    ola_ppconv_kernel<<<dim3(1030, 16), blk, 0, stream>>>(awb, ppw, ppb, out);
    (void)in_sizes; (void)n_in; (void)out_size; (void)ws_size;
}

// Round 11
// 174.260 us; speedup vs baseline: 3.4924x; 1.0098x over previous
//
#include <hip/hip_runtime.h>
#include <hip/hip_bf16.h>
#include <math.h>

#define TARLEN 263680
#define POWEXP 2.302585092994046f  // ln(10)
#define PC(i) ((i) + ((i) >> 3))   // complex-unit LDS padding (1 per 8)

typedef __attribute__((ext_vector_type(8))) short bf16x8;
typedef __attribute__((ext_vector_type(8))) ushort u16x8;
typedef __attribute__((ext_vector_type(4))) float f32x4;

__device__ __forceinline__ void gload16(const void* g, void* l) {
    __builtin_amdgcn_global_load_lds((const __attribute__((address_space(1))) void*)g,
                                     (__attribute__((address_space(3))) void*)l, 16, 0, 0);
}

__device__ __forceinline__ float bf16f(ushort u) {
    union { uint u; float f; } v; v.u = (uint)u << 16; return v.f;
}
__device__ __forceinline__ ushort fbf16(float x) {
    __hip_bfloat16 h = __float2bfloat16(x);
    return *reinterpret_cast<ushort*>(&h);
}

// sin/cos with input in REVOLUTIONS (v_sin_f32 native domain). Args here are
// exact binary fractions (k/4L, t/1024, t/2048) -> no rounding, no range
// reduction needed (all inputs in [0,1)).
__device__ __forceinline__ float vsin_rev(float rev) {
    float r; asm("v_sin_f32 %0, %1" : "=v"(r) : "v"(rev)); return r;
}
__device__ __forceinline__ float vcos_rev(float rev) {
    float r; asm("v_cos_f32 %0, %1" : "=v"(r) : "v"(rev)); return r;
}

// ============ unified GEMM: 128x128 tile, 512 thr, 8 waves of 64x32 =========
// C = A @ Bt^T, all bf16. LDS k-chunk XOR swizzle both sides (conflict-free,
// r5). 3-buffer deep pipeline, counted vmcnt(2) + raw s_barrier (r6-verified).
// EPI==0: fused BN column-stats partials. EPI==1: mod_sigmoid epilogue.
template<int EPI>
__global__ __launch_bounds__(512) void gemm8(
    const ushort* __restrict__ A, const ushort* __restrict__ Bt,
    const float* __restrict__ bias, ushort* __restrict__ C,
    int K, int Nvalid, int ldc,
    float* __restrict__ ps, float* __restrict__ pq)
{
    __shared__ ushort As[3][4096];  // [128][32] each
    __shared__ ushort Bs[3][4096];
    __shared__ float sred[8][2][16];
    __shared__ float qred[8][2][16];
    const int tid = threadIdx.x;
    const int lane = tid & 63;
    const int wid = tid >> 6;
    // bijective XCD swizzle (nwg % 8 == 0 for all our grids)
    const int nwg = gridDim.x * gridDim.y;
    const int bid = blockIdx.y * gridDim.x + blockIdx.x;
    const int q8 = nwg >> 3;
    const int swzb = (bid & 7) * q8 + (bid >> 3);
    const int bx = swzb % gridDim.x;
    const int by = swzb / gridDim.x;
    const int m0 = by * 128;
    const int n0 = bx * 128;
    const int NT = K >> 5;

    f32x4 acc[4][2];
#pragma unroll
    for (int m = 0; m < 4; ++m)
#pragma unroll
        for (int n = 0; n < 2; ++n)
            acc[m][n] = (f32x4){0.f, 0.f, 0.f, 0.f};

    const int srow = tid >> 2;                              // 0..127
    const int scol = (((tid & 3) ^ ((tid >> 3) & 3)) << 3); // swizzled src chunk

    auto stage = [&](int t, int buf) {
        const int k0 = t << 5;
        gload16(A + (size_t)(m0 + srow) * K + k0 + scol, &As[buf][tid * 8]);
        gload16(Bt + (size_t)(n0 + srow) * K + k0 + scol, &Bs[buf][tid * 8]);
    };

    const int lr = lane & 15;
    const int sw8 = (((lane >> 4) ^ ((lane >> 1) & 3)) << 3);  // swizzled read chunk
    const int wm0 = (wid >> 2) * 64;
    const int wn0 = (wid & 3) * 32;

    stage(0, 0);
    stage(1, 1);
    for (int t = 0; t < NT; ++t) {
        const int cur = t % 3;
        if (t + 2 < NT) {
            asm volatile("s_waitcnt vmcnt(2)" ::: "memory");  // own stage(t) landed
            __builtin_amdgcn_s_barrier();                     // all waves' stage(t) landed
            stage(t + 2, (t + 2) % 3);
        } else {
            asm volatile("s_waitcnt vmcnt(0)" ::: "memory");
            __builtin_amdgcn_s_barrier();
        }
        const ushort* as = As[cur];
        const ushort* bs = Bs[cur];
        bf16x8 af[4], bfv[2];
#pragma unroll
        for (int m = 0; m < 4; ++m)
            af[m] = *reinterpret_cast<const bf16x8*>(&as[(wm0 + m * 16 + lr) * 32 + sw8]);
#pragma unroll
        for (int n = 0; n < 2; ++n)
            bfv[n] = *reinterpret_cast<const bf16x8*>(&bs[(wn0 + n * 16 + lr) * 32 + sw8]);
#pragma unroll
        for (int m = 0; m < 4; ++m)
#pragma unroll
            for (int n = 0; n < 2; ++n)
                acc[m][n] = __builtin_amdgcn_mfma_f32_16x16x32_bf16(af[m], bfv[n], acc[m][n], 0, 0, 0);
    }
    __syncthreads();

    // epilogue: C/D layout col=lane&15, row=(lane>>4)*4+reg
    const int cr = (lane >> 4) << 2;
    const int cc = lane & 15;
    float sacc[2] = {0.f, 0.f}, qacc[2] = {0.f, 0.f};
#pragma unroll
    for (int m = 0; m < 4; ++m) {
#pragma unroll
        for (int n = 0; n < 2; ++n) {
            int gcol = n0 + wn0 + n * 16 + cc;
            if (EPI == 0 || gcol < Nvalid) {
                float bv = bias[gcol];
                int grow = m0 + wm0 + m * 16 + cr;
#pragma unroll
                for (int j = 0; j < 4; ++j) {
                    float v = acc[m][n][j] + bv;
                    if (EPI == 1) {
                        float sg = 1.f / (1.f + __expf(-v));
                        v = 2.f * __expf(POWEXP * __logf(sg)) + 1e-7f;
                    } else {
                        sacc[n] += v;
                        qacc[n] += v * v;
                    }
                    C[(size_t)(grow + j) * ldc + gcol] = fbf16(v);
                }
            }
        }
    }
    if (EPI == 0) {
#pragma unroll
        for (int n = 0; n < 2; ++n) {
            float s = sacc[n], q = qacc[n];
            s += __shfl_xor(s, 16); q += __shfl_xor(q, 16);
            s += __shfl_xor(s, 32); q += __shfl_xor(q, 32);
            if (lane < 16) { sred[wid][n][lane] = s; qred[wid][n][lane] = q; }
        }
        __syncthreads();
        if (tid < 128) {
            int wn_ = tid >> 5, n_ = (tid >> 4) & 1, cc_ = tid & 15;
            float s = sred[wn_][n_][cc_] + sred[4 + wn_][n_][cc_];
            float q = qred[wn_][n_][cc_] + qred[4 + wn_][n_][cc_];
            int col = n0 + wn_ * 32 + n_ * 16 + cc_;
            ps[(size_t)by * 512 + col] = s;
            pq[(size_t)by * 512 + col] = q;
        }
    }
}

// ---------------- fused: BN-stats final reduce + BN + LeakyReLU + bf16 ----
// Each block: (1) reduce 64 row-block partials -> per-column affine
// x*a+b (a=rs*g, b=be-m*a), deterministic fixed-order sum; (2) transform
// its 32 rows. Per-thread columns are fixed -> affine cached in registers.
__global__ __launch_bounds__(256) void prep_stats_act_k(
    const ushort* __restrict__ Hb, const float* __restrict__ ps,
    const float* __restrict__ pq, const float* __restrict__ gamma,
    const float* __restrict__ beta, ushort* __restrict__ A)
{
    __shared__ float sa[512], sb[512];
    const int tid = threadIdx.x;
    for (int c = tid; c < 512; c += 256) {
        float s = 0.f, q = 0.f;
        for (int rg = 0; rg < 64; ++rg) { s += ps[rg * 512 + c]; q += pq[rg * 512 + c]; }
        float m = s * (1.f / 8192.f);
        float v = q * (1.f / 8192.f) - m * m;
        float rs = rsqrtf(v + 1e-5f);
        float a = rs * gamma[c];
        sa[c] = a;
        sb[c] = beta[c] - m * a;
    }
    __syncthreads();
    const int col0 = (tid * 8) & 511;
    float ra[8], rb[8];
#pragma unroll
    for (int j = 0; j < 8; ++j) { ra[j] = sa[col0 + j]; rb[j] = sb[col0 + j]; }
    size_t base = (size_t)blockIdx.x * 16384;  // 32 rows * 512 cols
#pragma unroll
    for (int it = 0; it < 8; ++it) {
        int off = (it * 256 + tid) << 3;       // col = (tid*8)&511 for all it
        u16x8 hv = *reinterpret_cast<const u16x8*>(&Hb[base + off]);
        u16x8 o;
#pragma unroll
        for (int j = 0; j < 8; ++j) {
            float y = fmaf(bf16f(hv[j]), ra[j], rb[j]);
            o[j] = fbf16(y >= 0.f ? y : 0.2f * y);
        }
        *reinterpret_cast<u16x8*>(&A[base + off]) = o;
    }
}

// ---------------- batched input prep: 4 weight transposes + z cast --------
__global__ __launch_bounds__(256) void prep_inputs(
    const float* __restrict__ w0, const float* __restrict__ w1,
    const float* __restrict__ w2, const float* __restrict__ w3,
    const float* __restrict__ z,
    ushort* __restrict__ B0, ushort* __restrict__ B1,
    ushort* __restrict__ B2, ushort* __restrict__ B3,
    ushort* __restrict__ A)
{
    if (blockIdx.z == 4) {
        // z [8192][128] f32 -> bf16 (512 effective blocks of 256x8)
        int bid = blockIdx.y * gridDim.x + blockIdx.x;
        if (bid >= 512) return;
        int idx = (bid * 256 + threadIdx.x) << 3;
        float4 a = *reinterpret_cast<const float4*>(&z[idx]);
        float4 b = *reinterpret_cast<const float4*>(&z[idx + 4]);
        float x[8] = {a.x, a.y, a.z, a.w, b.x, b.y, b.z, b.w};
        u16x8 o;
#pragma unroll
        for (int j = 0; j < 8; ++j) o[j] = fbf16(x[j]);
        *reinterpret_cast<u16x8*>(&A[idx]) = o;
        return;
    }
    const float* w; ushort* Bt; int K, N, GX, GY;
    switch (blockIdx.z) {
        case 0: w = w0; Bt = B0; K = 128; N = 512;  GX = 4;  GY = 16; break;
        case 1: w = w1; Bt = B1; K = 512; N = 512;  GX = 16; GY = 16; break;
        case 2: w = w2; Bt = B2; K = 512; N = 512;  GX = 16; GY = 16; break;
        default:w = w3; Bt = B3; K = 512; N = 1025; GX = 16; GY = 36; break;
    }
    if ((int)blockIdx.x >= GX || (int)blockIdx.y >= GY) return;
    __shared__ float tile[32][33];
    int k0 = blockIdx.x * 32, n0 = blockIdx.y * 32;
    int tx = threadIdx.x & 31, ty = threadIdx.x >> 5;  // 32 x 8
#pragma unroll
    for (int r = 0; r < 4; ++r) {
        int k = k0 + ty + r * 8;
        int n = n0 + tx;
        tile[ty + r * 8][tx] = (n < N) ? w[(size_t)k * N + n] : 0.f;
    }
    __syncthreads();
#pragma unroll
    for (int r = 0; r < 4; ++r) {
        int n = n0 + ty + r * 8;
        int k = k0 + tx;
        Bt[(size_t)n * K + k] = fbf16(tile[tx][ty + r * 8]);
    }
}

// ---------------- Stockham radix-4 FFT, float2 LDS, 256 threads -----------
__device__ __forceinline__ float2 cmul(float2 a, float c, float s) {
    return make_float2(a.x * c - a.y * s, a.x * s + a.y * c);
}

template<bool INV, int L>
__device__ __forceinline__ void stk_stage(
    const float2* __restrict__ s, float2* __restrict__ d, int t)
{
    int k = t & (L - 1);
    float2 x0 = s[PC(t)];
    float2 x1 = s[PC(t + 256)];
    float2 x2 = s[PC(t + 512)];
    float2 x3 = s[PC(t + 768)];
    if (L > 1) {
        // twiddle angle k/(4L) revolutions — exact binary fraction
        float rev = (float)k * (1.0f / (float)(4 * L));
        float s1 = vsin_rev(rev), c1 = vcos_rev(rev);
        if (!INV) s1 = -s1;
        float c2 = c1 * c1 - s1 * s1, s2 = 2.f * c1 * s1;
        float c3 = c2 * c1 - s2 * s1, s3 = s2 * c1 + c2 * s1;
        x1 = cmul(x1, c1, s1);
        x2 = cmul(x2, c2, s2);
        x3 = cmul(x3, c3, s3);
    }
    float2 a = make_float2(x0.x + x2.x, x0.y + x2.y);
    float2 b = make_float2(x0.x - x2.x, x0.y - x2.y);
    float2 c = make_float2(x1.x + x3.x, x1.y + x3.y);
    float2 e = make_float2(x1.x - x3.x, x1.y - x3.y);
    int db = ((t - k) << 2) + k;
    d[PC(db)]         = make_float2(a.x + c.x, a.y + c.y);
    d[PC(db + 2 * L)] = make_float2(a.x - c.x, a.y - c.y);
    if (!INV) {
        d[PC(db + L)]     = make_float2(b.x + e.y, b.y - e.x);
        d[PC(db + 3 * L)] = make_float2(b.x - e.y, b.y + e.x);
    } else {
        d[PC(db + L)]     = make_float2(b.x - e.y, b.y + e.x);
        d[PC(db + 3 * L)] = make_float2(b.x + e.y, b.y - e.x);
    }
}

// audio = irfft( rfft(noise_row) * H ), H[k] = (-1)^k*(0.5 fc[k]+0.25 fc[k-1]+0.25 fc[k+1])
// (analytic collapse of rfft(fftshift(irfft(fc)*FW))). 1/1024 folded into H.
// fcs read as bf16; aw written as bf16. OLA window from final-stage twiddle.
__global__ __launch_bounds__(256) void fft_filter_kernel(
    const float* __restrict__ noise, const ushort* __restrict__ fcsb,
    ushort* __restrict__ awb)
{
    __shared__ float2 X[1152], Y[1152];
    __shared__ float F[1025];
    const int tid = threadIdx.x;
    const int r = blockIdx.x;

    const float2* nrow = reinterpret_cast<const float2*>(noise + ((size_t)r << 11));
    for (int i = tid; i < 1025; i += 256) F[i] = bf16f(fcsb[(size_t)r * 1040 + i]);
    {
        // forward stage L=1 fused with global load (pack z[n]=x[2n]+i x[2n+1])
        float2 x0 = nrow[tid], x1 = nrow[tid + 256], x2 = nrow[tid + 512], x3 = nrow[tid + 768];
        float2 a = make_float2(x0.x + x2.x, x0.y + x2.y);
        float2 b = make_float2(x0.x - x2.x, x0.y - x2.y);
        float2 c = make_float2(x1.x + x3.x, x1.y + x3.y);
        float2 e = make_float2(x1.x - x3.x, x1.y - x3.y);
        int db = tid << 2;
        Y[PC(db)]     = make_float2(a.x + c.x, a.y + c.y);
        Y[PC(db + 1)] = make_float2(b.x + e.y, b.y - e.x);
        Y[PC(db + 2)] = make_float2(a.x - c.x, a.y - c.y);
        Y[PC(db + 3)] = make_float2(b.x - e.y, b.y + e.x);
    }
    __syncthreads();
    stk_stage<false, 4>(Y, X, tid);   __syncthreads();
    stk_stage<false, 16>(X, Y, tid);  __syncthreads();
    stk_stage<false, 64>(Y, X, tid);  __syncthreads();
    stk_stage<false, 256>(X, Y, tid); __syncthreads();
    // forward result in Y (natural order)

    // unpack real FFT, apply H (scaled by 1/1024), repack; read Y, write X
    const float INV1024 = 1.0f / 1024.0f;
    auto proc = [&](int k, float c, float s) {
        int k2 = (1024 - k) & 1023;
        float2 za = Y[PC(k)], zb = Y[PC(k2)];
        float Fer = 0.5f * (za.x + zb.x), Fei = 0.5f * (za.y - zb.y);
        float For = 0.5f * (za.y + zb.y), Foi = 0.5f * (zb.x - za.x);
        float wFr = c * For - s * Foi;
        float wFi = c * Foi + s * For;
        float Xkr = Fer + wFr, Xki = Fei + wFi;
        float Xbr = Fer - wFr, Xbi = wFi - Fei;
        float Hk, Hb;
        {
            float cl = (k == 0) ? F[1] : F[k - 1];
            float crr = (k == 1024) ? F[1023] : F[k + 1];
            float h = 0.5f * F[k] + 0.25f * (cl + crr);
            Hk = ((k & 1) ? -h : h) * INV1024;
        }
        {
            int kb = 1024 - k;
            float cl = (kb == 0) ? F[1] : F[kb - 1];
            float crr = (kb == 1024) ? F[1023] : F[kb + 1];
            float h = 0.5f * F[kb] + 0.25f * (cl + crr);
            Hb = ((kb & 1) ? -h : h) * INV1024;
        }
        float Ykr = Hk * Xkr, Yki = Hk * Xki;
        float Ybr = Hb * Xbr, Ybi = Hb * Xbi;
        if (k == 0) {
            X[PC(0)] = make_float2(0.5f * (Ykr + Ybr), 0.5f * (Ykr - Ybr));
        } else {
            float Ger = 0.5f * (Ykr + Ybr), Gei = 0.5f * (Yki - Ybi);
            float Sgr = 0.5f * (Ykr - Ybr), Sgi = 0.5f * (Yki + Ybi);
            float wpr = c, wpi = -s;
            float Gor = wpr * Sgr - wpi * Sgi;
            float Goi = wpr * Sgi + wpi * Sgr;
            X[PC(k)]  = make_float2(Ger - Goi, Gei + Gor);
            X[PC(k2)] = make_float2(Ger + Goi, Gor - Gei);
        }
    };
    {
        // w = e^{-i pi k/1024}: rev = k/2048 (exact), sin negated
        float rev0 = (float)tid * (1.0f / 2048.0f);
        float c0 = vcos_rev(rev0), s0 = -vsin_rev(rev0);
        proc(tid, c0, s0);
        float rev1 = (float)(tid + 256) * (1.0f / 2048.0f);
        float c1 = vcos_rev(rev1), s1 = -vsin_rev(rev1);
        proc(tid + 256, c1, s1);
        if (tid == 0) proc(512, 0.f, -1.f);
    }
    __syncthreads();

    stk_stage<true, 1>(X, Y, tid);  __syncthreads();
    stk_stage<true, 4>(Y, X, tid);  __syncthreads();
    stk_stage<true, 16>(X, Y, tid); __syncthreads();
    stk_stage<true, 64>(Y, X, tid); __syncthreads();

    // inverse final stage (L=256) fused with OLA window + bf16 store;
    // window cos(2*pi*n/1024) at n=t+256q derived from the twiddle (c1,s1).
    {
        const int g = r & 511;
        ushort2* awrow = reinterpret_cast<ushort2*>(awb + ((size_t)r << 11));
        int t = tid;
        float2 x0 = X[PC(t)], x1 = X[PC(t + 256)], x2 = X[PC(t + 512)], x3 = X[PC(t + 768)];
        float rev = (float)t * (1.0f / 1024.0f);
        float s1 = vsin_rev(rev), c1 = vcos_rev(rev);
        float c2 = c1 * c1 - s1 * s1, s2 = 2.f * c1 * s1;
        float c3 = c2 * c1 - s2 * s1, s3 = s2 * c1 + c2 * s1;
        x1 = cmul(x1, c1, s1);
        x2 = cmul(x2, c2, s2);
        x3 = cmul(x3, c3, s3);
        float2 a = make_float2(x0.x + x2.x, x0.y + x2.y);
        float2 b = make_float2(x0.x - x2.x, x0.y - x2.y);
        float2 c = make_float2(x1.x + x3.x, x1.y + x3.y);
        float2 e = make_float2(x1.x - x3.x, x1.y - x3.y);
        float2 o[4];
        o[0] = make_float2(a.x + c.x, a.y + c.y);
        o[1] = make_float2(b.x - e.y, b.y + e.x);
        o[2] = make_float2(a.x - c.x, a.y - c.y);
        o[3] = make_float2(b.x + e.y, b.y - e.x);
        float cq[4] = {c1, -s1, -c1, s1};
        float sq[4] = {s1, c1, -s1, -c1};
        const float COSD = 0.99999529380958f;   // cos(pi/1024)
        const float SIND = 0.00306795676296f;   // sin(pi/1024)
#pragma unroll
        for (int q = 0; q < 4; ++q) {
            int n = t + 256 * q;
            float w0, w1;
            bool edge = (g == 0 && q < 2) || (g == 511 && q >= 2);
            if (edge) { w0 = 1.f; w1 = 1.f; }
            else {
                w0 = 0.5f - 0.5f * cq[q];
                w1 = 0.5f - 0.5f * (cq[q] * COSD - sq[q] * SIND);
            }
            ushort2 ov; ov.x = fbf16(o[q].x * w0); ov.y = fbf16(o[q].y * w1);
            awrow[n] = ov;
        }
    }
}

// ---------------- fused OLA gather + 65-tap conv + softsign ---------------
__global__ __launch_bounds__(256) void ola_ppconv_kernel(
    const ushort* __restrict__ awb, const float* __restrict__ ppw,
    const float* __restrict__ ppb, float* __restrict__ out)
{
    __shared__ float tile[320];
    __shared__ float Ksh[65];
    int t0 = blockIdx.x * 256;
    int b = blockIdx.y;
    for (int i = threadIdx.x; i < 320; i += 256) {
        int tt = t0 - 32 + i;
        float v = 0.f;
        if (tt >= 0 && tt < TARLEN) {
            int ghi = min(511, tt >> 9);
            int glo = max(0, (tt - 1536) >> 9);
            float s = 0.f;
            for (int g = glo; g <= ghi; ++g) {
                int n = tt - (g << 9);
                s += bf16f(awb[((size_t)(b * 512 + g) << 11) + n]);
            }
            v = s / (float)(ghi - glo + 1);
        }
        tile[i] = v;
    }
    if (threadIdx.x < 65) {
        float k = 0.f;
#pragma unroll
        for (int c = 0; c < 5; ++c) k += ppw[c * 65 + threadIdx.x];
        Ksh[threadIdx.x] = k;
    }
    __syncthreads();
    float y = ppb[0];
#pragma unroll
    for (int j = 0; j < 65; ++j) y = fmaf(Ksh[j], tile[threadIdx.x + j], y);
    int t = t0 + threadIdx.x;
    out[(size_t)b * TARLEN + t] = y / (1.f + fabsf(y));
}

// ---------------- launch --------------------------------------------------
extern "C" void kernel_launch(void* const* d_in, const int* in_sizes, int n_in,
                              void* d_out, int out_size, void* d_ws, size_t ws_size,
                              hipStream_t stream) {
    const float* z    = (const float*)d_in[0];
    const float* w0   = (const float*)d_in[1];
    const float* b0   = (const float*)d_in[2];
    const float* g0   = (const float*)d_in[3];
    const float* be0  = (const float*)d_in[4];
    const float* w1   = (const float*)d_in[5];
    const float* b1   = (const float*)d_in[6];
    const float* g1   = (const float*)d_in[7];
    const float* be1  = (const float*)d_in[8];
    const float* w2   = (const float*)d_in[9];
    const float* b2   = (const float*)d_in[10];
    const float* g2   = (const float*)d_in[11];
    const float* be2  = (const float*)d_in[12];
    const float* w3   = (const float*)d_in[13];
    const float* b3   = (const float*)d_in[14];
    const float* ppw  = (const float*)d_in[15];
    const float* ppb  = (const float*)d_in[16];
    const float* noise= (const float*)d_in[17];
    float* out = (float*)d_out;
    float* ws = (float*)d_ws;

    // workspace (float offsets)
    ushort* h0b = (ushort*)ws;                    // 8192*512 bf16 = 2,097,152 f
    ushort* h1b = (ushort*)(ws + 2097152);        // 8192*512 bf16
    float* ps   = ws + 4194304;                   // 64*512
    float* pq   = ps + 32768;                     // 64*512
    float* base = pq + 32768 + 1024;
    ushort* Bt0 = (ushort*)base;                  // 512*128  bf16 = 32768 f
    ushort* Bt1 = (ushort*)(base + 32768);        // 512*512  bf16 = 131072 f
    ushort* Bt2 = (ushort*)(base + 163840);       // 512*512  bf16 = 131072 f
    ushort* Bt3 = (ushort*)(base + 294912);       // 1152*512 bf16 = 294912 f
    ushort* fcsb= (ushort*)(base + 589824);       // 8192*1040 bf16 = 4,259,840 f
    ushort* awb = (ushort*)(base + 589824 + 4259840);            // 8192*2048 bf16
    ushort* A   = (ushort*)(base + 589824 + 4259840 + 8388608);  // 8192*512 bf16
    ushort* h2b = h0b;  // h0 dead after its prep

    dim3 blk(256);
    dim3 gblk(512);
    // all input prep (4 weight transposes + z cast) in one launch
    prep_inputs<<<dim3(16, 36, 5), blk, 0, stream>>>(
        w0, w1, w2, w3, z, Bt0, Bt1, Bt2, Bt3, A);
    // layer 0: h0 = z @ w0 + b0 (+ fused col stats); K=128
    gemm8<0><<<dim3(4, 64), gblk, 0, stream>>>(A, Bt0, b0, h0b, 128, 512, 512, ps, pq);
    // layer 1: fused stats+BN+lrelu prep, then gemm; K=512
    prep_stats_act_k<<<dim3(256), blk, 0, stream>>>(h0b, ps, pq, g0, be0, A);
    gemm8<0><<<dim3(4, 64), gblk, 0, stream>>>(A, Bt1, b1, h1b, 512, 512, 512, ps, pq);
    // layer 2
    prep_stats_act_k<<<dim3(256), blk, 0, stream>>>(h1b, ps, pq, g1, be1, A);
    gemm8<0><<<dim3(4, 64), gblk, 0, stream>>>(A, Bt2, b2, h2b, 512, 512, 512, ps, pq);
    // layer 3: K=512, fcs = mod_sigmoid(...) bf16 [8192][1040], 1025 valid
    prep_stats_act_k<<<dim3(256), blk, 0, stream>>>(h2b, ps, pq, g2, be2, A);
    gemm8<1><<<dim3(9, 64), gblk, 0, stream>>>(A, Bt3, b3, fcsb, 512, 1025, 1040, nullptr, nullptr);
    // spectral filtering + window (fused), bf16 in/out
    fft_filter_kernel<<<dim3(8192), blk, 0, stream>>>(noise, fcsb, awb);
    // fused OLA + post conv + softsign
    ola_ppconv_kernel<<<dim3(1030, 16), blk, 0, stream>>>(awb, ppw, ppb, out);
    (void)in_sizes; (void)n_in; (void)out_size; (void)ws_size;
}

// Round 12
// 173.433 us; speedup vs baseline: 3.5091x; 1.0048x over previous
//
#include <hip/hip_runtime.h>
#include <hip/hip_bf16.h>
#include <math.h>

#define TARLEN 263680
#define POWEXP 2.302585092994046f  // ln(10)
#define PC(i) ((i) + ((i) >> 3))   // complex-unit LDS padding (1 per 8)

typedef __attribute__((ext_vector_type(8))) short bf16x8;
typedef __attribute__((ext_vector_type(8))) ushort u16x8;
typedef __attribute__((ext_vector_type(4))) float f32x4;

__device__ __forceinline__ void gload16(const void* g, void* l) {
    __builtin_amdgcn_global_load_lds((const __attribute__((address_space(1))) void*)g,
                                     (__attribute__((address_space(3))) void*)l, 16, 0, 0);
}

__device__ __forceinline__ float bf16f(ushort u) {
    union { uint u; float f; } v; v.u = (uint)u << 16; return v.f;
}
__device__ __forceinline__ ushort fbf16(float x) {
    __hip_bfloat16 h = __float2bfloat16(x);
    return *reinterpret_cast<ushort*>(&h);
}

// sin/cos with input in REVOLUTIONS (v_sin_f32 native domain). Args here are
// exact binary fractions (k/4L, t/1024, t/2048) -> no rounding, no range
// reduction needed.
__device__ __forceinline__ float vsin_rev(float rev) {
    float r; asm("v_sin_f32 %0, %1" : "=v"(r) : "v"(rev)); return r;
}
__device__ __forceinline__ float vcos_rev(float rev) {
    float r; asm("v_cos_f32 %0, %1" : "=v"(r) : "v"(rev)); return r;
}

// ============ unified GEMM: 128x128 tile, 512 thr, 8 waves of 64x32 =========
// C = A @ Bt^T, all bf16. LDS k-chunk XOR swizzle both sides (conflict-free,
// r5). 3-buffer deep pipeline, counted vmcnt(2) + raw s_barrier (r6-verified).
// EPI==0: fused BN column-stats partials. EPI==1: mod_sigmoid epilogue.
template<int EPI>
__global__ __launch_bounds__(512) void gemm8(
    const ushort* __restrict__ A, const ushort* __restrict__ Bt,
    const float* __restrict__ bias, ushort* __restrict__ C,
    int K, int Nvalid, int ldc,
    float* __restrict__ ps, float* __restrict__ pq)
{
    __shared__ ushort As[3][4096];  // [128][32] each
    __shared__ ushort Bs[3][4096];
    __shared__ float sred[8][2][16];
    __shared__ float qred[8][2][16];
    const int tid = threadIdx.x;
    const int lane = tid & 63;
    const int wid = tid >> 6;
    // bijective XCD swizzle (nwg % 8 == 0 for all our grids)
    const int nwg = gridDim.x * gridDim.y;
    const int bid = blockIdx.y * gridDim.x + blockIdx.x;
    const int q8 = nwg >> 3;
    const int swzb = (bid & 7) * q8 + (bid >> 3);
    const int bx = swzb % gridDim.x;
    const int by = swzb / gridDim.x;
    const int m0 = by * 128;
    const int n0 = bx * 128;
    const int NT = K >> 5;

    f32x4 acc[4][2];
#pragma unroll
    for (int m = 0; m < 4; ++m)
#pragma unroll
        for (int n = 0; n < 2; ++n)
            acc[m][n] = (f32x4){0.f, 0.f, 0.f, 0.f};

    const int srow = tid >> 2;                              // 0..127
    const int scol = (((tid & 3) ^ ((tid >> 3) & 3)) << 3); // swizzled src chunk

    auto stage = [&](int t, int buf) {
        const int k0 = t << 5;
        gload16(A + (size_t)(m0 + srow) * K + k0 + scol, &As[buf][tid * 8]);
        gload16(Bt + (size_t)(n0 + srow) * K + k0 + scol, &Bs[buf][tid * 8]);
    };

    const int lr = lane & 15;
    const int sw8 = (((lane >> 4) ^ ((lane >> 1) & 3)) << 3);  // swizzled read chunk
    const int wm0 = (wid >> 2) * 64;
    const int wn0 = (wid & 3) * 32;

    stage(0, 0);
    stage(1, 1);
    for (int t = 0; t < NT; ++t) {
        const int cur = t % 3;
        if (t + 2 < NT) {
            asm volatile("s_waitcnt vmcnt(2)" ::: "memory");  // own stage(t) landed
            __builtin_amdgcn_s_barrier();                     // all waves' stage(t) landed
            stage(t + 2, (t + 2) % 3);
        } else {
            asm volatile("s_waitcnt vmcnt(0)" ::: "memory");
            __builtin_amdgcn_s_barrier();
        }
        const ushort* as = As[cur];
        const ushort* bs = Bs[cur];
        bf16x8 af[4], bfv[2];
#pragma unroll
        for (int m = 0; m < 4; ++m)
            af[m] = *reinterpret_cast<const bf16x8*>(&as[(wm0 + m * 16 + lr) * 32 + sw8]);
#pragma unroll
        for (int n = 0; n < 2; ++n)
            bfv[n] = *reinterpret_cast<const bf16x8*>(&bs[(wn0 + n * 16 + lr) * 32 + sw8]);
#pragma unroll
        for (int m = 0; m < 4; ++m)
#pragma unroll
            for (int n = 0; n < 2; ++n)
                acc[m][n] = __builtin_amdgcn_mfma_f32_16x16x32_bf16(af[m], bfv[n], acc[m][n], 0, 0, 0);
    }
    __syncthreads();

    // epilogue: C/D layout col=lane&15, row=(lane>>4)*4+reg
    const int cr = (lane >> 4) << 2;
    const int cc = lane & 15;
    float sacc[2] = {0.f, 0.f}, qacc[2] = {0.f, 0.f};
#pragma unroll
    for (int m = 0; m < 4; ++m) {
#pragma unroll
        for (int n = 0; n < 2; ++n) {
            int gcol = n0 + wn0 + n * 16 + cc;
            if (EPI == 0 || gcol < Nvalid) {
                float bv = bias[gcol];
                int grow = m0 + wm0 + m * 16 + cr;
#pragma unroll
                for (int j = 0; j < 4; ++j) {
                    float v = acc[m][n][j] + bv;
                    if (EPI == 1) {
                        float sg = 1.f / (1.f + __expf(-v));
                        v = 2.f * __expf(POWEXP * __logf(sg)) + 1e-7f;
                    } else {
                        sacc[n] += v;
                        qacc[n] += v * v;
                    }
                    C[(size_t)(grow + j) * ldc + gcol] = fbf16(v);
                }
            }
        }
    }
    if (EPI == 0) {
#pragma unroll
        for (int n = 0; n < 2; ++n) {
            float s = sacc[n], q = qacc[n];
            s += __shfl_xor(s, 16); q += __shfl_xor(q, 16);
            s += __shfl_xor(s, 32); q += __shfl_xor(q, 32);
            if (lane < 16) { sred[wid][n][lane] = s; qred[wid][n][lane] = q; }
        }
        __syncthreads();
        if (tid < 128) {
            int wn_ = tid >> 5, n_ = (tid >> 4) & 1, cc_ = tid & 15;
            float s = sred[wn_][n_][cc_] + sred[4 + wn_][n_][cc_];
            float q = qred[wn_][n_][cc_] + qred[4 + wn_][n_][cc_];
            int col = n0 + wn_ * 32 + n_ * 16 + cc_;
            ps[(size_t)by * 512 + col] = s;
            pq[(size_t)by * 512 + col] = q;
        }
    }
}

// ---------------- fused: BN-stats final reduce + BN + LeakyReLU + bf16 ----
__global__ __launch_bounds__(256) void prep_stats_act_k(
    const ushort* __restrict__ Hb, const float* __restrict__ ps,
    const float* __restrict__ pq, const float* __restrict__ gamma,
    const float* __restrict__ beta, ushort* __restrict__ A)
{
    __shared__ float sa[512], sb[512];
    const int tid = threadIdx.x;
    for (int c = tid; c < 512; c += 256) {
        float s = 0.f, q = 0.f;
#pragma unroll 8
        for (int rg = 0; rg < 64; ++rg) { s += ps[rg * 512 + c]; q += pq[rg * 512 + c]; }
        float m = s * (1.f / 8192.f);
        float v = q * (1.f / 8192.f) - m * m;
        float rs = rsqrtf(v + 1e-5f);
        float a = rs * gamma[c];
        sa[c] = a;
        sb[c] = beta[c] - m * a;
    }
    __syncthreads();
    const int col0 = (tid * 8) & 511;
    float ra[8], rb[8];
#pragma unroll
    for (int j = 0; j < 8; ++j) { ra[j] = sa[col0 + j]; rb[j] = sb[col0 + j]; }
    size_t base = (size_t)blockIdx.x * 16384;  // 32 rows * 512 cols
#pragma unroll
    for (int it = 0; it < 8; ++it) {
        int off = (it * 256 + tid) << 3;       // col = (tid*8)&511 for all it
        u16x8 hv = *reinterpret_cast<const u16x8*>(&Hb[base + off]);
        u16x8 o;
#pragma unroll
        for (int j = 0; j < 8; ++j) {
            float y = fmaf(bf16f(hv[j]), ra[j], rb[j]);
            o[j] = fbf16(y >= 0.f ? y : 0.2f * y);
        }
        *reinterpret_cast<u16x8*>(&A[base + off]) = o;
    }
}

// ---------------- batched input prep: 4 weight transposes + z cast --------
__global__ __launch_bounds__(256) void prep_inputs(
    const float* __restrict__ w0, const float* __restrict__ w1,
    const float* __restrict__ w2, const float* __restrict__ w3,
    const float* __restrict__ z,
    ushort* __restrict__ B0, ushort* __restrict__ B1,
    ushort* __restrict__ B2, ushort* __restrict__ B3,
    ushort* __restrict__ A)
{
    if (blockIdx.z == 4) {
        int bid = blockIdx.y * gridDim.x + blockIdx.x;
        if (bid >= 512) return;
        int idx = (bid * 256 + threadIdx.x) << 3;
        float4 a = *reinterpret_cast<const float4*>(&z[idx]);
        float4 b = *reinterpret_cast<const float4*>(&z[idx + 4]);
        float x[8] = {a.x, a.y, a.z, a.w, b.x, b.y, b.z, b.w};
        u16x8 o;
#pragma unroll
        for (int j = 0; j < 8; ++j) o[j] = fbf16(x[j]);
        *reinterpret_cast<u16x8*>(&A[idx]) = o;
        return;
    }
    const float* w; ushort* Bt; int K, N, GX, GY;
    switch (blockIdx.z) {
        case 0: w = w0; Bt = B0; K = 128; N = 512;  GX = 4;  GY = 16; break;
        case 1: w = w1; Bt = B1; K = 512; N = 512;  GX = 16; GY = 16; break;
        case 2: w = w2; Bt = B2; K = 512; N = 512;  GX = 16; GY = 16; break;
        default:w = w3; Bt = B3; K = 512; N = 1025; GX = 16; GY = 36; break;
    }
    if ((int)blockIdx.x >= GX || (int)blockIdx.y >= GY) return;
    __shared__ float tile[32][33];
    int k0 = blockIdx.x * 32, n0 = blockIdx.y * 32;
    int tx = threadIdx.x & 31, ty = threadIdx.x >> 5;  // 32 x 8
#pragma unroll
    for (int r = 0; r < 4; ++r) {
        int k = k0 + ty + r * 8;
        int n = n0 + tx;
        tile[ty + r * 8][tx] = (n < N) ? w[(size_t)k * N + n] : 0.f;
    }
    __syncthreads();
#pragma unroll
    for (int r = 0; r < 4; ++r) {
        int n = n0 + ty + r * 8;
        int k = k0 + tx;
        Bt[(size_t)n * K + k] = fbf16(tile[tx][ty + r * 8]);
    }
}

// ---------------- Stockham radix-4 FFT, float2 LDS, 256 threads -----------
__device__ __forceinline__ float2 cmul(float2 a, float c, float s) {
    return make_float2(a.x * c - a.y * s, a.x * s + a.y * c);
}

template<bool INV, int L>
__device__ __forceinline__ void stk_stage(
    const float2* __restrict__ s, float2* __restrict__ d, int t)
{
    int k = t & (L - 1);
    float2 x0 = s[PC(t)];
    float2 x1 = s[PC(t + 256)];
    float2 x2 = s[PC(t + 512)];
    float2 x3 = s[PC(t + 768)];
    if (L > 1) {
        // twiddle angle k/(4L) revolutions — exact binary fraction
        float rev = (float)k * (1.0f / (float)(4 * L));
        float s1 = vsin_rev(rev), c1 = vcos_rev(rev);
        if (!INV) s1 = -s1;
        float c2 = c1 * c1 - s1 * s1, s2 = 2.f * c1 * s1;
        float c3 = c2 * c1 - s2 * s1, s3 = s2 * c1 + c2 * s1;
        x1 = cmul(x1, c1, s1);
        x2 = cmul(x2, c2, s2);
        x3 = cmul(x3, c3, s3);
    }
    float2 a = make_float2(x0.x + x2.x, x0.y + x2.y);
    float2 b = make_float2(x0.x - x2.x, x0.y - x2.y);
    float2 c = make_float2(x1.x + x3.x, x1.y + x3.y);
    float2 e = make_float2(x1.x - x3.x, x1.y - x3.y);
    int db = ((t - k) << 2) + k;
    d[PC(db)]         = make_float2(a.x + c.x, a.y + c.y);
    d[PC(db + 2 * L)] = make_float2(a.x - c.x, a.y - c.y);
    if (!INV) {
        d[PC(db + L)]     = make_float2(b.x + e.y, b.y - e.x);
        d[PC(db + 3 * L)] = make_float2(b.x - e.y, b.y + e.x);
    } else {
        d[PC(db + L)]     = make_float2(b.x - e.y, b.y + e.x);
        d[PC(db + 3 * L)] = make_float2(b.x + e.y, b.y - e.x);
    }
}

// audio = irfft( rfft(noise_row) * H ), H[k] = (-1)^k*(0.5 fc[k]+0.25 fc[k-1]+0.25 fc[k+1])
// (analytic collapse of rfft(fftshift(irfft(fc)*FW))). 1/1024 folded into H.
// fcs kept in LDS as bf16 (occupancy: 23->20.5KB LDS -> 7 blocks/CU).
__global__ __launch_bounds__(256) void fft_filter_kernel(
    const float* __restrict__ noise, const ushort* __restrict__ fcsb,
    ushort* __restrict__ awb)
{
    __shared__ float2 X[1152], Y[1152];
    __shared__ ushort Fb[1026];
    const int tid = threadIdx.x;
    const int r = blockIdx.x;

    const float2* nrow = reinterpret_cast<const float2*>(noise + ((size_t)r << 11));
    for (int i = tid; i < 1025; i += 256) Fb[i] = fcsb[(size_t)r * 1040 + i];
    {
        // forward stage L=1 fused with global load (pack z[n]=x[2n]+i x[2n+1])
        float2 x0 = nrow[tid], x1 = nrow[tid + 256], x2 = nrow[tid + 512], x3 = nrow[tid + 768];
        float2 a = make_float2(x0.x + x2.x, x0.y + x2.y);
        float2 b = make_float2(x0.x - x2.x, x0.y - x2.y);
        float2 c = make_float2(x1.x + x3.x, x1.y + x3.y);
        float2 e = make_float2(x1.x - x3.x, x1.y - x3.y);
        int db = tid << 2;
        Y[PC(db)]     = make_float2(a.x + c.x, a.y + c.y);
        Y[PC(db + 1)] = make_float2(b.x + e.y, b.y - e.x);
        Y[PC(db + 2)] = make_float2(a.x - c.x, a.y - c.y);
        Y[PC(db + 3)] = make_float2(b.x - e.y, b.y + e.x);
    }
    __syncthreads();
    stk_stage<false, 4>(Y, X, tid);   __syncthreads();
    stk_stage<false, 16>(X, Y, tid);  __syncthreads();
    stk_stage<false, 64>(Y, X, tid);  __syncthreads();
    stk_stage<false, 256>(X, Y, tid); __syncthreads();
    // forward result in Y (natural order)

    // unpack real FFT, apply H (scaled by 1/1024), repack; read Y, write X
    const float INV1024 = 1.0f / 1024.0f;
    auto proc = [&](int k, float c, float s) {
        int k2 = (1024 - k) & 1023;
        float2 za = Y[PC(k)], zb = Y[PC(k2)];
        float Fer = 0.5f * (za.x + zb.x), Fei = 0.5f * (za.y - zb.y);
        float For = 0.5f * (za.y + zb.y), Foi = 0.5f * (zb.x - za.x);
        float wFr = c * For - s * Foi;
        float wFi = c * Foi + s * For;
        float Xkr = Fer + wFr, Xki = Fei + wFi;
        float Xbr = Fer - wFr, Xbi = wFi - Fei;
        float Hk, Hb;
        {
            float cl = (k == 0) ? bf16f(Fb[1]) : bf16f(Fb[k - 1]);
            float crr = (k == 1024) ? bf16f(Fb[1023]) : bf16f(Fb[k + 1]);
            float h = 0.5f * bf16f(Fb[k]) + 0.25f * (cl + crr);
            Hk = ((k & 1) ? -h : h) * INV1024;
        }
        {
            int kb = 1024 - k;
            float cl = (kb == 0) ? bf16f(Fb[1]) : bf16f(Fb[kb - 1]);
            float crr = (kb == 1024) ? bf16f(Fb[1023]) : bf16f(Fb[kb + 1]);
            float h = 0.5f * bf16f(Fb[kb]) + 0.25f * (cl + crr);
            Hb = ((kb & 1) ? -h : h) * INV1024;
        }
        float Ykr = Hk * Xkr, Yki = Hk * Xki;
        float Ybr = Hb * Xbr, Ybi = Hb * Xbi;
        if (k == 0) {
            X[PC(0)] = make_float2(0.5f * (Ykr + Ybr), 0.5f * (Ykr - Ybr));
        } else {
            float Ger = 0.5f * (Ykr + Ybr), Gei = 0.5f * (Yki - Ybi);
            float Sgr = 0.5f * (Ykr - Ybr), Sgi = 0.5f * (Yki + Ybi);
            float wpr = c, wpi = -s;
            float Gor = wpr * Sgr - wpi * Sgi;
            float Goi = wpr * Sgi + wpi * Sgr;
            X[PC(k)]  = make_float2(Ger - Goi, Gei + Gor);
            X[PC(k2)] = make_float2(Ger + Goi, Gor - Gei);
        }
    };
    {
        // w = e^{-i pi k/1024}: rev = k/2048 (exact), sin negated
        float rev0 = (float)tid * (1.0f / 2048.0f);
        float c0 = vcos_rev(rev0), s0 = -vsin_rev(rev0);
        proc(tid, c0, s0);
        float rev1 = (float)(tid + 256) * (1.0f / 2048.0f);
        float c1 = vcos_rev(rev1), s1 = -vsin_rev(rev1);
        proc(tid + 256, c1, s1);
        if (tid == 0) proc(512, 0.f, -1.f);
    }
    __syncthreads();

    stk_stage<true, 1>(X, Y, tid);  __syncthreads();
    stk_stage<true, 4>(Y, X, tid);  __syncthreads();
    stk_stage<true, 16>(X, Y, tid); __syncthreads();
    stk_stage<true, 64>(Y, X, tid); __syncthreads();

    // inverse final stage (L=256) fused with OLA window + bf16 store;
    // window cos(2*pi*n/1024) at n=t+256q derived from the twiddle (c1,s1).
    {
        const int g = r & 511;
        ushort2* awrow = reinterpret_cast<ushort2*>(awb + ((size_t)r << 11));
        int t = tid;
        float2 x0 = X[PC(t)], x1 = X[PC(t + 256)], x2 = X[PC(t + 512)], x3 = X[PC(t + 768)];
        float rev = (float)t * (1.0f / 1024.0f);
        float s1 = vsin_rev(rev), c1 = vcos_rev(rev);
        float c2 = c1 * c1 - s1 * s1, s2 = 2.f * c1 * s1;
        float c3 = c2 * c1 - s2 * s1, s3 = s2 * c1 + c2 * s1;
        x1 = cmul(x1, c1, s1);
        x2 = cmul(x2, c2, s2);
        x3 = cmul(x3, c3, s3);
        float2 a = make_float2(x0.x + x2.x, x0.y + x2.y);
        float2 b = make_float2(x0.x - x2.x, x0.y - x2.y);
        float2 c = make_float2(x1.x + x3.x, x1.y + x3.y);
        float2 e = make_float2(x1.x - x3.x, x1.y - x3.y);
        float2 o[4];
        o[0] = make_float2(a.x + c.x, a.y + c.y);
        o[1] = make_float2(b.x - e.y, b.y + e.x);
        o[2] = make_float2(a.x - c.x, a.y - c.y);
        o[3] = make_float2(b.x + e.y, b.y - e.x);
        float cq[4] = {c1, -s1, -c1, s1};
        float sq[4] = {s1, c1, -s1, -c1};
        const float COSD = 0.99999529380958f;   // cos(pi/1024)
        const float SIND = 0.00306795676296f;   // sin(pi/1024)
#pragma unroll
        for (int q = 0; q < 4; ++q) {
            int n = t + 256 * q;
            float w0, w1;
            bool edge = (g == 0 && q < 2) || (g == 511 && q >= 2);
            if (edge) { w0 = 1.f; w1 = 1.f; }
            else {
                w0 = 0.5f - 0.5f * cq[q];
                w1 = 0.5f - 0.5f * (cq[q] * COSD - sq[q] * SIND);
            }
            ushort2 ov; ov.x = fbf16(o[q].x * w0); ov.y = fbf16(o[q].y * w1);
            awrow[n] = ov;
        }
    }
}

// ---------------- fused OLA gather + 65-tap conv + softsign ---------------
// Interior samples (tt in [1536, 262144)) always hit exactly 4 grains with
// divisor 4 and constant address stride (+1536 elems) -> branch-free path.
__global__ __launch_bounds__(256) void ola_ppconv_kernel(
    const ushort* __restrict__ awb, const float* __restrict__ ppw,
    const float* __restrict__ ppb, float* __restrict__ out)
{
    __shared__ float tile[320];
    __shared__ float Ksh[65];
    int t0 = blockIdx.x * 256;
    int b = blockIdx.y;
    const ushort* awbase = awb + ((size_t)(b * 512) << 11);
    for (int i = threadIdx.x; i < 320; i += 256) {
        int tt = t0 - 32 + i;
        float v = 0.f;
        if (tt >= 1536 && tt < 262144) {
            int glo = (tt - 1536) >> 9;
            const ushort* p = awbase + ((size_t)glo << 11) + (tt - (glo << 9));
            float s = bf16f(p[0]) + bf16f(p[1536]) + bf16f(p[3072]) + bf16f(p[4608]);
            v = s * 0.25f;
        } else if (tt >= 0 && tt < TARLEN) {
            int ghi = min(511, tt >> 9);
            int glo = max(0, (tt - 1536) >> 9);
            float s = 0.f;
            for (int g = glo; g <= ghi; ++g) {
                int n = tt - (g << 9);
                s += bf16f(awbase[((size_t)g << 11) + n]);
            }
            v = s / (float)(ghi - glo + 1);
        }
        tile[i] = v;
    }
    if (threadIdx.x < 65) {
        float k = 0.f;
#pragma unroll
        for (int c = 0; c < 5; ++c) k += ppw[c * 65 + threadIdx.x];
        Ksh[threadIdx.x] = k;
    }
    __syncthreads();
    float y = ppb[0];
#pragma unroll
    for (int j = 0; j < 65; ++j) y = fmaf(Ksh[j], tile[threadIdx.x + j], y);
    int t = t0 + threadIdx.x;
    out[(size_t)b * TARLEN + t] = y / (1.f + fabsf(y));
}

// ---------------- launch --------------------------------------------------
extern "C" void kernel_launch(void* const* d_in, const int* in_sizes, int n_in,
                              void* d_out, int out_size, void* d_ws, size_t ws_size,
                              hipStream_t stream) {
    const float* z    = (const float*)d_in[0];
    const float* w0   = (const float*)d_in[1];
    const float* b0   = (const float*)d_in[2];
    const float* g0   = (const float*)d_in[3];
    const float* be0  = (const float*)d_in[4];
    const float* w1   = (const float*)d_in[5];
    const float* b1   = (const float*)d_in[6];
    const float* g1   = (const float*)d_in[7];
    const float* be1  = (const float*)d_in[8];
    const float* w2   = (const float*)d_in[9];
    const float* b2   = (const float*)d_in[10];
    const float* g2   = (const float*)d_in[11];
    const float* be2  = (const float*)d_in[12];
    const float* w3   = (const float*)d_in[13];
    const float* b3   = (const float*)d_in[14];
    const float* ppw  = (const float*)d_in[15];
    const float* ppb  = (const float*)d_in[16];
    const float* noise= (const float*)d_in[17];
    float* out = (float*)d_out;
    float* ws = (float*)d_ws;

    // workspace (float offsets)
    ushort* h0b = (ushort*)ws;                    // 8192*512 bf16 = 2,097,152 f
    ushort* h1b = (ushort*)(ws + 2097152);        // 8192*512 bf16
    float* ps   = ws + 4194304;                   // 64*512
    float* pq   = ps + 32768;                     // 64*512
    float* base = pq + 32768 + 1024;
    ushort* Bt0 = (ushort*)base;                  // 512*128  bf16 = 32768 f
    ushort* Bt1 = (ushort*)(base + 32768);        // 512*512  bf16 = 131072 f
    ushort* Bt2 = (ushort*)(base + 163840);       // 512*512  bf16 = 131072 f
    ushort* Bt3 = (ushort*)(base + 294912);       // 1152*512 bf16 = 294912 f
    ushort* fcsb= (ushort*)(base + 589824);       // 8192*1040 bf16 = 4,259,840 f
    ushort* awb = (ushort*)(base + 589824 + 4259840);            // 8192*2048 bf16
    ushort* A   = (ushort*)(base + 589824 + 4259840 + 8388608);  // 8192*512 bf16
    ushort* h2b = h0b;  // h0 dead after its prep

    dim3 blk(256);
    dim3 gblk(512);
    // all input prep (4 weight transposes + z cast) in one launch
    prep_inputs<<<dim3(16, 36, 5), blk, 0, stream>>>(
        w0, w1, w2, w3, z, Bt0, Bt1, Bt2, Bt3, A);
    // layer 0: h0 = z @ w0 + b0 (+ fused col stats); K=128
    gemm8<0><<<dim3(4, 64), gblk, 0, stream>>>(A, Bt0, b0, h0b, 128, 512, 512, ps, pq);
    // layer 1: fused stats+BN+lrelu prep, then gemm; K=512
    prep_stats_act_k<<<dim3(256), blk, 0, stream>>>(h0b, ps, pq, g0, be0, A);
    gemm8<0><<<dim3(4, 64), gblk, 0, stream>>>(A, Bt1, b1, h1b, 512, 512, 512, ps, pq);
    // layer 2
    prep_stats_act_k<<<dim3(256), blk, 0, stream>>>(h1b, ps, pq, g1, be1, A);
    gemm8<0><<<dim3(4, 64), gblk, 0, stream>>>(A, Bt2, b2, h2b, 512, 512, 512, ps, pq);
    // layer 3: K=512, fcs = mod_sigmoid(...) bf16 [8192][1040], 1025 valid
    prep_stats_act_k<<<dim3(256), blk, 0, stream>>>(h2b, ps, pq, g2, be2, A);
    gemm8<1><<<dim3(9, 64), gblk, 0, stream>>>(A, Bt3, b3, fcsb, 512, 1025, 1040, nullptr, nullptr);
    // spectral filtering + window (fused), bf16 in/out
    fft_filter_kernel<<<dim3(8192), blk, 0, stream>>>(noise, fcsb, awb);
    // fused OLA + post conv + softsign
    ola_ppconv_kernel<<<dim3(1030, 16), blk, 0, stream>>>(awb, ppw, ppb, out);
    (void)in_sizes; (void)n_in; (void)out_size; (void)ws_size;
}

// Round 13
// 162.228 us; speedup vs baseline: 3.7514x; 1.0691x over previous
//
#include <hip/hip_runtime.h>
#include <hip/hip_bf16.h>
#include <math.h>

#define TARLEN 263680
#define POWEXP 2.302585092994046f  // ln(10)
#define PC(i) ((i) + ((i) >> 3))   // complex-unit LDS padding (1 per 8)

typedef __attribute__((ext_vector_type(8))) short bf16x8;
typedef __attribute__((ext_vector_type(8))) ushort u16x8;
typedef __attribute__((ext_vector_type(4))) float f32x4;

__device__ __forceinline__ void gload16(const void* g, void* l) {
    __builtin_amdgcn_global_load_lds((const __attribute__((address_space(1))) void*)g,
                                     (__attribute__((address_space(3))) void*)l, 16, 0, 0);
}

__device__ __forceinline__ float bf16f(ushort u) {
    union { uint u; float f; } v; v.u = (uint)u << 16; return v.f;
}
__device__ __forceinline__ ushort fbf16(float x) {
    __hip_bfloat16 h = __float2bfloat16(x);
    return *reinterpret_cast<ushort*>(&h);
}

// sin/cos with input in REVOLUTIONS (v_sin_f32 native domain); args are exact
// binary fractions -> no rounding, no range reduction.
__device__ __forceinline__ float vsin_rev(float rev) {
    float r; asm("v_sin_f32 %0, %1" : "=v"(r) : "v"(rev)); return r;
}
__device__ __forceinline__ float vcos_rev(float rev) {
    float r; asm("v_cos_f32 %0, %1" : "=v"(r) : "v"(rev)); return r;
}

// ============ GEMM layer 0 (no norm): 128x128 tile, 512 thr =================
// C = A @ Bt^T bf16, gload_lds both operands, 3-buffer vmcnt(2) pipeline,
// fused BN column-stat partials. (r6-verified structure, byte-identical.)
__global__ __launch_bounds__(512) void gemm8(
    const ushort* __restrict__ A, const ushort* __restrict__ Bt,
    const float* __restrict__ bias, ushort* __restrict__ C,
    int K, float* __restrict__ ps, float* __restrict__ pq)
{
    __shared__ ushort As[3][4096];
    __shared__ ushort Bs[3][4096];
    __shared__ float sred[8][2][16];
    __shared__ float qred[8][2][16];
    const int tid = threadIdx.x;
    const int lane = tid & 63;
    const int wid = tid >> 6;
    const int nwg = gridDim.x * gridDim.y;
    const int bid = blockIdx.y * gridDim.x + blockIdx.x;
    const int q8 = nwg >> 3;
    const int swzb = (bid & 7) * q8 + (bid >> 3);
    const int bx = swzb % gridDim.x;
    const int by = swzb / gridDim.x;
    const int m0 = by * 128;
    const int n0 = bx * 128;
    const int NT = K >> 5;

    f32x4 acc[4][2];
#pragma unroll
    for (int m = 0; m < 4; ++m)
#pragma unroll
        for (int n = 0; n < 2; ++n)
            acc[m][n] = (f32x4){0.f, 0.f, 0.f, 0.f};

    const int srow = tid >> 2;
    const int scol = (((tid & 3) ^ ((tid >> 3) & 3)) << 3);

    auto stage = [&](int t, int buf) {
        const int k0 = t << 5;
        gload16(A + (size_t)(m0 + srow) * K + k0 + scol, &As[buf][tid * 8]);
        gload16(Bt + (size_t)(n0 + srow) * K + k0 + scol, &Bs[buf][tid * 8]);
    };

    const int lr = lane & 15;
    const int sw8 = (((lane >> 4) ^ ((lane >> 1) & 3)) << 3);
    const int wm0 = (wid >> 2) * 64;
    const int wn0 = (wid & 3) * 32;

    stage(0, 0);
    stage(1, 1);
    for (int t = 0; t < NT; ++t) {
        const int cur = t % 3;
        if (t + 2 < NT) {
            asm volatile("s_waitcnt vmcnt(2)" ::: "memory");
            __builtin_amdgcn_s_barrier();
            stage(t + 2, (t + 2) % 3);
        } else {
            asm volatile("s_waitcnt vmcnt(0)" ::: "memory");
            __builtin_amdgcn_s_barrier();
        }
        const ushort* as = As[cur];
        const ushort* bs = Bs[cur];
        bf16x8 af[4], bfv[2];
#pragma unroll
        for (int m = 0; m < 4; ++m)
            af[m] = *reinterpret_cast<const bf16x8*>(&as[(wm0 + m * 16 + lr) * 32 + sw8]);
#pragma unroll
        for (int n = 0; n < 2; ++n)
            bfv[n] = *reinterpret_cast<const bf16x8*>(&bs[(wn0 + n * 16 + lr) * 32 + sw8]);
#pragma unroll
        for (int m = 0; m < 4; ++m)
#pragma unroll
            for (int n = 0; n < 2; ++n)
                acc[m][n] = __builtin_amdgcn_mfma_f32_16x16x32_bf16(af[m], bfv[n], acc[m][n], 0, 0, 0);
    }
    __syncthreads();

    const int cr = (lane >> 4) << 2;
    const int cc = lane & 15;
    float sacc[2] = {0.f, 0.f}, qacc[2] = {0.f, 0.f};
#pragma unroll
    for (int m = 0; m < 4; ++m) {
#pragma unroll
        for (int n = 0; n < 2; ++n) {
            int gcol = n0 + wn0 + n * 16 + cc;
            float bv = bias[gcol];
            int grow = m0 + wm0 + m * 16 + cr;
#pragma unroll
            for (int j = 0; j < 4; ++j) {
                float v = acc[m][n][j] + bv;
                sacc[n] += v;
                qacc[n] += v * v;
                C[(size_t)(grow + j) * 512 + gcol] = fbf16(v);
            }
        }
    }
#pragma unroll
    for (int n = 0; n < 2; ++n) {
        float s = sacc[n], q = qacc[n];
        s += __shfl_xor(s, 16); q += __shfl_xor(q, 16);
        s += __shfl_xor(s, 32); q += __shfl_xor(q, 32);
        if (lane < 16) { sred[wid][n][lane] = s; qred[wid][n][lane] = q; }
    }
    __syncthreads();
    if (tid < 128) {
        int wn_ = tid >> 5, n_ = (tid >> 4) & 1, cc_ = tid & 15;
        float s = sred[wn_][n_][cc_] + sred[4 + wn_][n_][cc_];
        float q = qred[wn_][n_][cc_] + qred[4 + wn_][n_][cc_];
        int col = n0 + wn_ * 32 + n_ * 16 + cc_;
        ps[(size_t)by * 512 + col] = s;
        pq[(size_t)by * 512 + col] = q;
    }
}

// ============ GEMM with fused BN (stats reduce + affine + lrelu on A) =======
// A-operand reg-staged: global->reg, affine(bf16)+lrelu+cvt, ds_write_b128.
// B via global_load_lds. Per stage exactly 2 vm ops (B,A) -> vmcnt(2) pipeline
// preserved. Stats prologue: reduce 64 partials -> packed bf16 affine in LDS.
// EPI==0: stat partials out. EPI==1: mod_sigmoid epilogue.
template<int EPI>
__global__ __launch_bounds__(512) void gemm8n(
    const ushort* __restrict__ H, const ushort* __restrict__ Bt,
    const float* __restrict__ bias,
    const float* __restrict__ psIn, const float* __restrict__ pqIn,
    const float* __restrict__ gamma, const float* __restrict__ beta,
    ushort* __restrict__ C, int K, int Nvalid, int ldc,
    float* __restrict__ psOut, float* __restrict__ pqOut)
{
    __shared__ ushort As[3][4096];
    __shared__ ushort Bs[3][4096];
    __shared__ uint sab[512];
    __shared__ float sred[8][2][16];
    __shared__ float qred[8][2][16];
    const int tid = threadIdx.x;
    const int lane = tid & 63;
    const int wid = tid >> 6;
    const int nwg = gridDim.x * gridDim.y;
    const int bid = blockIdx.y * gridDim.x + blockIdx.x;
    const int q8 = nwg >> 3;
    const int swzb = (bid & 7) * q8 + (bid >> 3);
    const int bx = swzb % gridDim.x;
    const int by = swzb / gridDim.x;
    const int m0 = by * 128;
    const int n0 = bx * 128;
    const int NT = K >> 5;  // always even (K=512)

    // ---- stats prologue: per-column affine a*x+b, packed bf16 ----
    {
        int c = tid;  // 512 threads, 512 columns
        float s = 0.f, q = 0.f;
#pragma unroll 8
        for (int rg = 0; rg < 64; ++rg) { s += psIn[rg * 512 + c]; q += pqIn[rg * 512 + c]; }
        float m = s * (1.f / 8192.f);
        float v = q * (1.f / 8192.f) - m * m;
        float a = rsqrtf(v + 1e-5f) * gamma[c];
        float b = beta[c] - m * a;
        sab[c] = (uint)fbf16(a) | ((uint)fbf16(b) << 16);
    }

    f32x4 acc[4][2];
#pragma unroll
    for (int m = 0; m < 4; ++m)
#pragma unroll
        for (int n = 0; n < 2; ++n)
            acc[m][n] = (f32x4){0.f, 0.f, 0.f, 0.f};

    const int srow = tid >> 2;
    const int scol = (((tid & 3) ^ ((tid >> 3) & 3)) << 3);
    const int lr = lane & 15;
    const int sw8 = (((lane >> 4) ^ ((lane >> 1) & 3)) << 3);
    const int wm0 = (wid >> 2) * 64;
    const int wn0 = (wid & 3) * 32;

    const size_t arow = (size_t)(m0 + srow) * K + scol;
    const size_t brow = (size_t)(n0 + srow) * K + scol;

    auto stageB = [&](int t, int buf) {
        gload16(Bt + brow + (t << 5), &Bs[buf][tid * 8]);
    };
    auto loadA = [&](int t, u16x8& dst) {
        dst = *reinterpret_cast<const u16x8*>(H + arow + (t << 5));
    };

    __syncthreads();  // sab ready

    u16x8 a0, a1;
    stageB(0, 0); loadA(0, a0);
    stageB(1, 1); loadA(1, a1);

    auto iter = [&](int t, u16x8& ar) {
        const int cur = t % 3;
        if (t + 2 < NT) asm volatile("s_waitcnt vmcnt(2)" ::: "memory");
        else            asm volatile("s_waitcnt vmcnt(0)" ::: "memory");
        // transform A-reg -> LDS (affine + leaky-relu + bf16)
        {
            const uint* pk = &sab[(t << 5) + scol];
            u16x8 o;
#pragma unroll
            for (int j = 0; j < 8; ++j) {
                uint w = pk[j];
                float a = bf16f((ushort)(w & 0xffffu));
                float b = bf16f((ushort)(w >> 16));
                float y = fmaf(bf16f(ar[j]), a, b);
                o[j] = fbf16(y >= 0.f ? y : 0.2f * y);
            }
            *reinterpret_cast<u16x8*>(&As[cur][tid * 8]) = o;
        }
        asm volatile("s_waitcnt lgkmcnt(0)" ::: "memory");
        __builtin_amdgcn_s_barrier();
        if (t + 2 < NT) { stageB(t + 2, (t + 2) % 3); loadA(t + 2, ar); }
        const ushort* as = As[cur];
        const ushort* bs = Bs[cur];
        bf16x8 af[4], bfv[2];
#pragma unroll
        for (int m = 0; m < 4; ++m)
            af[m] = *reinterpret_cast<const bf16x8*>(&as[(wm0 + m * 16 + lr) * 32 + sw8]);
#pragma unroll
        for (int n = 0; n < 2; ++n)
            bfv[n] = *reinterpret_cast<const bf16x8*>(&bs[(wn0 + n * 16 + lr) * 32 + sw8]);
#pragma unroll
        for (int m = 0; m < 4; ++m)
#pragma unroll
            for (int n = 0; n < 2; ++n)
                acc[m][n] = __builtin_amdgcn_mfma_f32_16x16x32_bf16(af[m], bfv[n], acc[m][n], 0, 0, 0);
    };

    for (int t = 0; t < NT; t += 2) { iter(t, a0); iter(t + 1, a1); }
    __syncthreads();

    // epilogue
    const int cr = (lane >> 4) << 2;
    const int cc = lane & 15;
    float sacc[2] = {0.f, 0.f}, qacc[2] = {0.f, 0.f};
#pragma unroll
    for (int m = 0; m < 4; ++m) {
#pragma unroll
        for (int n = 0; n < 2; ++n) {
            int gcol = n0 + wn0 + n * 16 + cc;
            if (EPI == 0 || gcol < Nvalid) {
                float bv = bias[gcol];
                int grow = m0 + wm0 + m * 16 + cr;
#pragma unroll
                for (int j = 0; j < 4; ++j) {
                    float v = acc[m][n][j] + bv;
                    if (EPI == 1) {
                        float sg = 1.f / (1.f + __expf(-v));
                        v = 2.f * __expf(POWEXP * __logf(sg)) + 1e-7f;
                    } else {
                        sacc[n] += v;
                        qacc[n] += v * v;
                    }
                    C[(size_t)(grow + j) * ldc + gcol] = fbf16(v);
                }
            }
        }
    }
    if (EPI == 0) {
#pragma unroll
        for (int n = 0; n < 2; ++n) {
            float s = sacc[n], q = qacc[n];
            s += __shfl_xor(s, 16); q += __shfl_xor(q, 16);
            s += __shfl_xor(s, 32); q += __shfl_xor(q, 32);
            if (lane < 16) { sred[wid][n][lane] = s; qred[wid][n][lane] = q; }
        }
        __syncthreads();
        if (tid < 128) {
            int wn_ = tid >> 5, n_ = (tid >> 4) & 1, cc_ = tid & 15;
            float s = sred[wn_][n_][cc_] + sred[4 + wn_][n_][cc_];
            float q = qred[wn_][n_][cc_] + qred[4 + wn_][n_][cc_];
            int col = n0 + wn_ * 32 + n_ * 16 + cc_;
            psOut[(size_t)by * 512 + col] = s;
            pqOut[(size_t)by * 512 + col] = q;
        }
    }
}

// ---------------- batched input prep: 4 weight transposes + z cast --------
__global__ __launch_bounds__(256) void prep_inputs(
    const float* __restrict__ w0, const float* __restrict__ w1,
    const float* __restrict__ w2, const float* __restrict__ w3,
    const float* __restrict__ z,
    ushort* __restrict__ B0, ushort* __restrict__ B1,
    ushort* __restrict__ B2, ushort* __restrict__ B3,
    ushort* __restrict__ A)
{
    if (blockIdx.z == 4) {
        int bid = blockIdx.y * gridDim.x + blockIdx.x;
        if (bid >= 512) return;
        int idx = (bid * 256 + threadIdx.x) << 3;
        float4 a = *reinterpret_cast<const float4*>(&z[idx]);
        float4 b = *reinterpret_cast<const float4*>(&z[idx + 4]);
        float x[8] = {a.x, a.y, a.z, a.w, b.x, b.y, b.z, b.w};
        u16x8 o;
#pragma unroll
        for (int j = 0; j < 8; ++j) o[j] = fbf16(x[j]);
        *reinterpret_cast<u16x8*>(&A[idx]) = o;
        return;
    }
    const float* w; ushort* Bt; int K, N, GX, GY;
    switch (blockIdx.z) {
        case 0: w = w0; Bt = B0; K = 128; N = 512;  GX = 4;  GY = 16; break;
        case 1: w = w1; Bt = B1; K = 512; N = 512;  GX = 16; GY = 16; break;
        case 2: w = w2; Bt = B2; K = 512; N = 512;  GX = 16; GY = 16; break;
        default:w = w3; Bt = B3; K = 512; N = 1025; GX = 16; GY = 36; break;
    }
    if ((int)blockIdx.x >= GX || (int)blockIdx.y >= GY) return;
    __shared__ float tile[32][33];
    int k0 = blockIdx.x * 32, n0 = blockIdx.y * 32;
    int tx = threadIdx.x & 31, ty = threadIdx.x >> 5;
#pragma unroll
    for (int r = 0; r < 4; ++r) {
        int k = k0 + ty + r * 8;
        int n = n0 + tx;
        tile[ty + r * 8][tx] = (n < N) ? w[(size_t)k * N + n] : 0.f;
    }
    __syncthreads();
#pragma unroll
    for (int r = 0; r < 4; ++r) {
        int n = n0 + ty + r * 8;
        int k = k0 + tx;
        Bt[(size_t)n * K + k] = fbf16(tile[tx][ty + r * 8]);
    }
}

// ---------------- Stockham radix-4 FFT, float2 LDS, 256 threads -----------
__device__ __forceinline__ float2 cmul(float2 a, float c, float s) {
    return make_float2(a.x * c - a.y * s, a.x * s + a.y * c);
}

template<bool INV, int L>
__device__ __forceinline__ void stk_stage(
    const float2* __restrict__ s, float2* __restrict__ d, int t)
{
    int k = t & (L - 1);
    float2 x0 = s[PC(t)];
    float2 x1 = s[PC(t + 256)];
    float2 x2 = s[PC(t + 512)];
    float2 x3 = s[PC(t + 768)];
    if (L > 1) {
        float rev = (float)k * (1.0f / (float)(4 * L));
        float s1 = vsin_rev(rev), c1 = vcos_rev(rev);
        if (!INV) s1 = -s1;
        float c2 = c1 * c1 - s1 * s1, s2 = 2.f * c1 * s1;
        float c3 = c2 * c1 - s2 * s1, s3 = s2 * c1 + c2 * s1;
        x1 = cmul(x1, c1, s1);
        x2 = cmul(x2, c2, s2);
        x3 = cmul(x3, c3, s3);
    }
    float2 a = make_float2(x0.x + x2.x, x0.y + x2.y);
    float2 b = make_float2(x0.x - x2.x, x0.y - x2.y);
    float2 c = make_float2(x1.x + x3.x, x1.y + x3.y);
    float2 e = make_float2(x1.x - x3.x, x1.y - x3.y);
    int db = ((t - k) << 2) + k;
    d[PC(db)]         = make_float2(a.x + c.x, a.y + c.y);
    d[PC(db + 2 * L)] = make_float2(a.x - c.x, a.y - c.y);
    if (!INV) {
        d[PC(db + L)]     = make_float2(b.x + e.y, b.y - e.x);
        d[PC(db + 3 * L)] = make_float2(b.x - e.y, b.y + e.x);
    } else {
        d[PC(db + L)]     = make_float2(b.x - e.y, b.y + e.x);
        d[PC(db + 3 * L)] = make_float2(b.x + e.y, b.y - e.x);
    }
}

// audio = irfft( rfft(noise_row) * H ), H[k] = (-1)^k*(0.5 fc[k]+0.25 fc[k-1]+0.25 fc[k+1])
// (analytic collapse of rfft(fftshift(irfft(fc)*FW))). 1/1024 folded into H.
__global__ __launch_bounds__(256) void fft_filter_kernel(
    const float* __restrict__ noise, const ushort* __restrict__ fcsb,
    ushort* __restrict__ awb)
{
    __shared__ float2 X[1152], Y[1152];
    __shared__ ushort Fb[1026];
    const int tid = threadIdx.x;
    const int r = blockIdx.x;

    const float2* nrow = reinterpret_cast<const float2*>(noise + ((size_t)r << 11));
    for (int i = tid; i < 1025; i += 256) Fb[i] = fcsb[(size_t)r * 1040 + i];
    {
        float2 x0 = nrow[tid], x1 = nrow[tid + 256], x2 = nrow[tid + 512], x3 = nrow[tid + 768];
        float2 a = make_float2(x0.x + x2.x, x0.y + x2.y);
        float2 b = make_float2(x0.x - x2.x, x0.y - x2.y);
        float2 c = make_float2(x1.x + x3.x, x1.y + x3.y);
        float2 e = make_float2(x1.x - x3.x, x1.y - x3.y);
        int db = tid << 2;
        Y[PC(db)]     = make_float2(a.x + c.x, a.y + c.y);
        Y[PC(db + 1)] = make_float2(b.x + e.y, b.y - e.x);
        Y[PC(db + 2)] = make_float2(a.x - c.x, a.y - c.y);
        Y[PC(db + 3)] = make_float2(b.x - e.y, b.y + e.x);
    }
    __syncthreads();
    stk_stage<false, 4>(Y, X, tid);   __syncthreads();
    stk_stage<false, 16>(X, Y, tid);  __syncthreads();
    stk_stage<false, 64>(Y, X, tid);  __syncthreads();
    stk_stage<false, 256>(X, Y, tid); __syncthreads();

    const float INV1024 = 1.0f / 1024.0f;
    auto proc = [&](int k, float c, float s) {
        int k2 = (1024 - k) & 1023;
        float2 za = Y[PC(k)], zb = Y[PC(k2)];
        float Fer = 0.5f * (za.x + zb.x), Fei = 0.5f * (za.y - zb.y);
        float For = 0.5f * (za.y + zb.y), Foi = 0.5f * (zb.x - za.x);
        float wFr = c * For - s * Foi;
        float wFi = c * Foi + s * For;
        float Xkr = Fer + wFr, Xki = Fei + wFi;
        float Xbr = Fer - wFr, Xbi = wFi - Fei;
        float Hk, Hb;
        {
            float cl = (k == 0) ? bf16f(Fb[1]) : bf16f(Fb[k - 1]);
            float crr = (k == 1024) ? bf16f(Fb[1023]) : bf16f(Fb[k + 1]);
            float h = 0.5f * bf16f(Fb[k]) + 0.25f * (cl + crr);
            Hk = ((k & 1) ? -h : h) * INV1024;
        }
        {
            int kb = 1024 - k;
            float cl = (kb == 0) ? bf16f(Fb[1]) : bf16f(Fb[kb - 1]);
            float crr = (kb == 1024) ? bf16f(Fb[1023]) : bf16f(Fb[kb + 1]);
            float h = 0.5f * bf16f(Fb[kb]) + 0.25f * (cl + crr);
            Hb = ((kb & 1) ? -h : h) * INV1024;
        }
        float Ykr = Hk * Xkr, Yki = Hk * Xki;
        float Ybr = Hb * Xbr, Ybi = Hb * Xbi;
        if (k == 0) {
            X[PC(0)] = make_float2(0.5f * (Ykr + Ybr), 0.5f * (Ykr - Ybr));
        } else {
            float Ger = 0.5f * (Ykr + Ybr), Gei = 0.5f * (Yki - Ybi);
            float Sgr = 0.5f * (Ykr - Ybr), Sgi = 0.5f * (Yki + Ybi);
            float wpr = c, wpi = -s;
            float Gor = wpr * Sgr - wpi * Sgi;
            float Goi = wpr * Sgi + wpi * Sgr;
            X[PC(k)]  = make_float2(Ger - Goi, Gei + Gor);
            X[PC(k2)] = make_float2(Ger + Goi, Gor - Gei);
        }
    };
    {
        float rev0 = (float)tid * (1.0f / 2048.0f);
        float c0 = vcos_rev(rev0), s0 = -vsin_rev(rev0);
        proc(tid, c0, s0);
        float rev1 = (float)(tid + 256) * (1.0f / 2048.0f);
        float c1 = vcos_rev(rev1), s1 = -vsin_rev(rev1);
        proc(tid + 256, c1, s1);
        if (tid == 0) proc(512, 0.f, -1.f);
    }
    __syncthreads();

    stk_stage<true, 1>(X, Y, tid);  __syncthreads();
    stk_stage<true, 4>(Y, X, tid);  __syncthreads();
    stk_stage<true, 16>(X, Y, tid); __syncthreads();
    stk_stage<true, 64>(Y, X, tid); __syncthreads();

    {
        const int g = r & 511;
        ushort2* awrow = reinterpret_cast<ushort2*>(awb + ((size_t)r << 11));
        int t = tid;
        float2 x0 = X[PC(t)], x1 = X[PC(t + 256)], x2 = X[PC(t + 512)], x3 = X[PC(t + 768)];
        float rev = (float)t * (1.0f / 1024.0f);
        float s1 = vsin_rev(rev), c1 = vcos_rev(rev);
        float c2 = c1 * c1 - s1 * s1, s2 = 2.f * c1 * s1;
        float c3 = c2 * c1 - s2 * s1, s3 = s2 * c1 + c2 * s1;
        x1 = cmul(x1, c1, s1);
        x2 = cmul(x2, c2, s2);
        x3 = cmul(x3, c3, s3);
        float2 a = make_float2(x0.x + x2.x, x0.y + x2.y);
        float2 b = make_float2(x0.x - x2.x, x0.y - x2.y);
        float2 c = make_float2(x1.x + x3.x, x1.y + x3.y);
        float2 e = make_float2(x1.x - x3.x, x1.y - x3.y);
        float2 o[4];
        o[0] = make_float2(a.x + c.x, a.y + c.y);
        o[1] = make_float2(b.x - e.y, b.y + e.x);
        o[2] = make_float2(a.x - c.x, a.y - c.y);
        o[3] = make_float2(b.x + e.y, b.y - e.x);
        float cq[4] = {c1, -s1, -c1, s1};
        float sq[4] = {s1, c1, -s1, -c1};
        const float COSD = 0.99999529380958f;
        const float SIND = 0.00306795676296f;
#pragma unroll
        for (int q = 0; q < 4; ++q) {
            int n = t + 256 * q;
            float w0, w1;
            bool edge = (g == 0 && q < 2) || (g == 511 && q >= 2);
            if (edge) { w0 = 1.f; w1 = 1.f; }
            else {
                w0 = 0.5f - 0.5f * cq[q];
                w1 = 0.5f - 0.5f * (cq[q] * COSD - sq[q] * SIND);
            }
            ushort2 ov; ov.x = fbf16(o[q].x * w0); ov.y = fbf16(o[q].y * w1);
            awrow[n] = ov;
        }
    }
}

// ---------------- fused OLA gather + 65-tap conv + softsign ---------------
__global__ __launch_bounds__(256) void ola_ppconv_kernel(
    const ushort* __restrict__ awb, const float* __restrict__ ppw,
    const float* __restrict__ ppb, float* __restrict__ out)
{
    __shared__ float tile[320];
    __shared__ float Ksh[65];
    int t0 = blockIdx.x * 256;
    int b = blockIdx.y;
    const ushort* awbase = awb + ((size_t)(b * 512) << 11);
    for (int i = threadIdx.x; i < 320; i += 256) {
        int tt = t0 - 32 + i;
        float v = 0.f;
        if (tt >= 1536 && tt < 262144) {
            int glo = (tt - 1536) >> 9;
            const ushort* p = awbase + ((size_t)glo << 11) + (tt - (glo << 9));
            float s = bf16f(p[0]) + bf16f(p[1536]) + bf16f(p[3072]) + bf16f(p[4608]);
            v = s * 0.25f;
        } else if (tt >= 0 && tt < TARLEN) {
            int ghi = min(511, tt >> 9);
            int glo = max(0, (tt - 1536) >> 9);
            float s = 0.f;
            for (int g = glo; g <= ghi; ++g) {
                int n = tt - (g << 9);
                s += bf16f(awbase[((size_t)g << 11) + n]);
            }
            v = s / (float)(ghi - glo + 1);
        }
        tile[i] = v;
    }
    if (threadIdx.x < 65) {
        float k = 0.f;
#pragma unroll
        for (int c = 0; c < 5; ++c) k += ppw[c * 65 + threadIdx.x];
        Ksh[threadIdx.x] = k;
    }
    __syncthreads();
    float y = ppb[0];
#pragma unroll
    for (int j = 0; j < 65; ++j) y = fmaf(Ksh[j], tile[threadIdx.x + j], y);
    int t = t0 + threadIdx.x;
    out[(size_t)b * TARLEN + t] = y / (1.f + fabsf(y));
}

// ---------------- launch --------------------------------------------------
extern "C" void kernel_launch(void* const* d_in, const int* in_sizes, int n_in,
                              void* d_out, int out_size, void* d_ws, size_t ws_size,
                              hipStream_t stream) {
    const float* z    = (const float*)d_in[0];
    const float* w0   = (const float*)d_in[1];
    const float* b0   = (const float*)d_in[2];
    const float* g0   = (const float*)d_in[3];
    const float* be0  = (const float*)d_in[4];
    const float* w1   = (const float*)d_in[5];
    const float* b1   = (const float*)d_in[6];
    const float* g1   = (const float*)d_in[7];
    const float* be1  = (const float*)d_in[8];
    const float* w2   = (const float*)d_in[9];
    const float* b2   = (const float*)d_in[10];
    const float* g2   = (const float*)d_in[11];
    const float* be2  = (const float*)d_in[12];
    const float* w3   = (const float*)d_in[13];
    const float* b3   = (const float*)d_in[14];
    const float* ppw  = (const float*)d_in[15];
    const float* ppb  = (const float*)d_in[16];
    const float* noise= (const float*)d_in[17];
    float* out = (float*)d_out;
    float* ws = (float*)d_ws;

    // workspace (float offsets)
    ushort* h0b = (ushort*)ws;                    // 8192*512 bf16
    ushort* h1b = (ushort*)(ws + 2097152);        // 8192*512 bf16
    float* ps0  = ws + 4194304;                   // 64*512
    float* pq0  = ps0 + 32768;
    float* ps1  = pq0 + 32768;
    float* pq1  = ps1 + 32768;
    float* base = pq1 + 32768;
    ushort* Bt0 = (ushort*)base;                  // 512*128 bf16
    ushort* Bt1 = (ushort*)(base + 32768);        // 512*512 bf16
    ushort* Bt2 = (ushort*)(base + 163840);       // 512*512 bf16
    ushort* Bt3 = (ushort*)(base + 294912);       // 1152*512 bf16
    ushort* fcsb= (ushort*)(base + 589824);       // 8192*1040 bf16
    ushort* awb = (ushort*)(base + 4849664);      // 8192*2048 bf16
    ushort* A   = (ushort*)(base + 13238272);     // 8192*128 bf16 (z cast)
    ushort* h2b = h0b;  // h0 dead after gemm1 consumed it

    dim3 blk(256);
    dim3 gblk(512);
    // input prep (4 weight transposes + z cast) in one launch
    prep_inputs<<<dim3(16, 36, 5), blk, 0, stream>>>(
        w0, w1, w2, w3, z, Bt0, Bt1, Bt2, Bt3, A);
    // layer 0: h0 = z @ w0 + b0 (+ stats -> S0); K=128
    gemm8<<<dim3(4, 64), gblk, 0, stream>>>(A, Bt0, b0, h0b, 128, ps0, pq0);
    // layer 1: fused BN(S0)+lrelu on A, gemm, stats -> S1
    gemm8n<0><<<dim3(4, 64), gblk, 0, stream>>>(
        h0b, Bt1, b1, ps0, pq0, g0, be0, h1b, 512, 512, 512, ps1, pq1);
    // layer 2: fused BN(S1), stats -> S0
    gemm8n<0><<<dim3(4, 64), gblk, 0, stream>>>(
        h1b, Bt2, b2, ps1, pq1, g1, be1, h2b, 512, 512, 512, ps0, pq0);
    // layer 3: fused BN(S0), mod_sigmoid -> fcsb [8192][1040], 1025 valid
    gemm8n<1><<<dim3(9, 64), gblk, 0, stream>>>(
        h2b, Bt3, b3, ps0, pq0, g2, be2, fcsb, 512, 1025, 1040, nullptr, nullptr);
    // spectral filtering + window (fused), bf16 in/out
    fft_filter_kernel<<<dim3(8192), blk, 0, stream>>>(noise, fcsb, awb);
    // fused OLA + post conv + softsign
    ola_ppconv_kernel<<<dim3(1030, 16), blk, 0, stream>>>(awb, ppw, ppb, out);
    (void)in_sizes; (void)n_in; (void)out_size; (void)ws_size;
}

// Round 14
// 161.676 us; speedup vs baseline: 3.7642x; 1.0034x over previous
//
#include <hip/hip_runtime.h>
#include <hip/hip_bf16.h>
#include <math.h>

#define TARLEN 263680
#define POWEXP 2.302585092994046f  // ln(10)
#define PC(i) ((i) + ((i) >> 3))   // complex-unit LDS padding (1 per 8)

typedef __attribute__((ext_vector_type(8))) short bf16x8;
typedef __attribute__((ext_vector_type(8))) ushort u16x8;
typedef __attribute__((ext_vector_type(4))) float f32x4;
typedef __attribute__((ext_vector_type(2))) float pf2;  // maps to v_pk_*_f32

__device__ __forceinline__ void gload16(const void* g, void* l) {
    __builtin_amdgcn_global_load_lds((const __attribute__((address_space(1))) void*)g,
                                     (__attribute__((address_space(3))) void*)l, 16, 0, 0);
}

__device__ __forceinline__ float bf16f(ushort u) {
    union { uint u; float f; } v; v.u = (uint)u << 16; return v.f;
}
__device__ __forceinline__ ushort fbf16(float x) {
    __hip_bfloat16 h = __float2bfloat16(x);
    return *reinterpret_cast<ushort*>(&h);
}

// sin/cos with input in REVOLUTIONS (v_sin_f32 native domain); args are exact
// binary fractions -> no rounding, no range reduction.
__device__ __forceinline__ float vsin_rev(float rev) {
    float r; asm("v_sin_f32 %0, %1" : "=v"(r) : "v"(rev)); return r;
}
__device__ __forceinline__ float vcos_rev(float rev) {
    float r; asm("v_cos_f32 %0, %1" : "=v"(r) : "v"(rev)); return r;
}

// complex mul on packed float2: (a.x*c - a.y*s, a.y*c + a.x*s)
__device__ __forceinline__ pf2 cmulp(pf2 a, float c, float s) {
    return a * c + a.yx * (pf2){-s, s};
}

// ============ GEMM layer 0 (no norm): 128x128 tile, 512 thr =================
__global__ __launch_bounds__(512) void gemm8(
    const ushort* __restrict__ A, const ushort* __restrict__ Bt,
    const float* __restrict__ bias, ushort* __restrict__ C,
    int K, float* __restrict__ ps, float* __restrict__ pq)
{
    __shared__ ushort As[3][4096];
    __shared__ ushort Bs[3][4096];
    __shared__ float sred[8][2][16];
    __shared__ float qred[8][2][16];
    const int tid = threadIdx.x;
    const int lane = tid & 63;
    const int wid = tid >> 6;
    const int nwg = gridDim.x * gridDim.y;
    const int bid = blockIdx.y * gridDim.x + blockIdx.x;
    const int q8 = nwg >> 3;
    const int swzb = (bid & 7) * q8 + (bid >> 3);
    const int bx = swzb % gridDim.x;
    const int by = swzb / gridDim.x;
    const int m0 = by * 128;
    const int n0 = bx * 128;
    const int NT = K >> 5;

    f32x4 acc[4][2];
#pragma unroll
    for (int m = 0; m < 4; ++m)
#pragma unroll
        for (int n = 0; n < 2; ++n)
            acc[m][n] = (f32x4){0.f, 0.f, 0.f, 0.f};

    const int srow = tid >> 2;
    const int scol = (((tid & 3) ^ ((tid >> 3) & 3)) << 3);

    auto stage = [&](int t, int buf) {
        const int k0 = t << 5;
        gload16(A + (size_t)(m0 + srow) * K + k0 + scol, &As[buf][tid * 8]);
        gload16(Bt + (size_t)(n0 + srow) * K + k0 + scol, &Bs[buf][tid * 8]);
    };

    const int lr = lane & 15;
    const int sw8 = (((lane >> 4) ^ ((lane >> 1) & 3)) << 3);
    const int wm0 = (wid >> 2) * 64;
    const int wn0 = (wid & 3) * 32;

    stage(0, 0);
    stage(1, 1);
    for (int t = 0; t < NT; ++t) {
        const int cur = t % 3;
        if (t + 2 < NT) {
            asm volatile("s_waitcnt vmcnt(2)" ::: "memory");
            __builtin_amdgcn_s_barrier();
            stage(t + 2, (t + 2) % 3);
        } else {
            asm volatile("s_waitcnt vmcnt(0)" ::: "memory");
            __builtin_amdgcn_s_barrier();
        }
        const ushort* as = As[cur];
        const ushort* bs = Bs[cur];
        bf16x8 af[4], bfv[2];
#pragma unroll
        for (int m = 0; m < 4; ++m)
            af[m] = *reinterpret_cast<const bf16x8*>(&as[(wm0 + m * 16 + lr) * 32 + sw8]);
#pragma unroll
        for (int n = 0; n < 2; ++n)
            bfv[n] = *reinterpret_cast<const bf16x8*>(&bs[(wn0 + n * 16 + lr) * 32 + sw8]);
#pragma unroll
        for (int m = 0; m < 4; ++m)
#pragma unroll
            for (int n = 0; n < 2; ++n)
                acc[m][n] = __builtin_amdgcn_mfma_f32_16x16x32_bf16(af[m], bfv[n], acc[m][n], 0, 0, 0);
    }
    __syncthreads();

    const int cr = (lane >> 4) << 2;
    const int cc = lane & 15;
    float sacc[2] = {0.f, 0.f}, qacc[2] = {0.f, 0.f};
#pragma unroll
    for (int m = 0; m < 4; ++m) {
#pragma unroll
        for (int n = 0; n < 2; ++n) {
            int gcol = n0 + wn0 + n * 16 + cc;
            float bv = bias[gcol];
            int grow = m0 + wm0 + m * 16 + cr;
#pragma unroll
            for (int j = 0; j < 4; ++j) {
                float v = acc[m][n][j] + bv;
                sacc[n] += v;
                qacc[n] += v * v;
                C[(size_t)(grow + j) * 512 + gcol] = fbf16(v);
            }
        }
    }
#pragma unroll
    for (int n = 0; n < 2; ++n) {
        float s = sacc[n], q = qacc[n];
        s += __shfl_xor(s, 16); q += __shfl_xor(q, 16);
        s += __shfl_xor(s, 32); q += __shfl_xor(q, 32);
        if (lane < 16) { sred[wid][n][lane] = s; qred[wid][n][lane] = q; }
    }
    __syncthreads();
    if (tid < 128) {
        int wn_ = tid >> 5, n_ = (tid >> 4) & 1, cc_ = tid & 15;
        float s = sred[wn_][n_][cc_] + sred[4 + wn_][n_][cc_];
        float q = qred[wn_][n_][cc_] + qred[4 + wn_][n_][cc_];
        int col = n0 + wn_ * 32 + n_ * 16 + cc_;
        ps[(size_t)by * 512 + col] = s;
        pq[(size_t)by * 512 + col] = q;
    }
}

// ============ GEMM with fused BN (stats reduce + affine + lrelu on A) =======
template<int EPI>
__global__ __launch_bounds__(512) void gemm8n(
    const ushort* __restrict__ H, const ushort* __restrict__ Bt,
    const float* __restrict__ bias,
    const float* __restrict__ psIn, const float* __restrict__ pqIn,
    const float* __restrict__ gamma, const float* __restrict__ beta,
    ushort* __restrict__ C, int K, int Nvalid, int ldc,
    float* __restrict__ psOut, float* __restrict__ pqOut)
{
    __shared__ ushort As[3][4096];
    __shared__ ushort Bs[3][4096];
    __shared__ uint sab[512];
    __shared__ float sred[8][2][16];
    __shared__ float qred[8][2][16];
    const int tid = threadIdx.x;
    const int lane = tid & 63;
    const int wid = tid >> 6;
    const int nwg = gridDim.x * gridDim.y;
    const int bid = blockIdx.y * gridDim.x + blockIdx.x;
    const int q8 = nwg >> 3;
    const int swzb = (bid & 7) * q8 + (bid >> 3);
    const int bx = swzb % gridDim.x;
    const int by = swzb / gridDim.x;
    const int m0 = by * 128;
    const int n0 = bx * 128;
    const int NT = K >> 5;  // even (K=512)

    {
        int c = tid;
        float s = 0.f, q = 0.f;
#pragma unroll 8
        for (int rg = 0; rg < 64; ++rg) { s += psIn[rg * 512 + c]; q += pqIn[rg * 512 + c]; }
        float m = s * (1.f / 8192.f);
        float v = q * (1.f / 8192.f) - m * m;
        float a = rsqrtf(v + 1e-5f) * gamma[c];
        float b = beta[c] - m * a;
        sab[c] = (uint)fbf16(a) | ((uint)fbf16(b) << 16);
    }

    f32x4 acc[4][2];
#pragma unroll
    for (int m = 0; m < 4; ++m)
#pragma unroll
        for (int n = 0; n < 2; ++n)
            acc[m][n] = (f32x4){0.f, 0.f, 0.f, 0.f};

    const int srow = tid >> 2;
    const int scol = (((tid & 3) ^ ((tid >> 3) & 3)) << 3);
    const int lr = lane & 15;
    const int sw8 = (((lane >> 4) ^ ((lane >> 1) & 3)) << 3);
    const int wm0 = (wid >> 2) * 64;
    const int wn0 = (wid & 3) * 32;

    const size_t arow = (size_t)(m0 + srow) * K + scol;
    const size_t brow = (size_t)(n0 + srow) * K + scol;

    auto stageB = [&](int t, int buf) {
        gload16(Bt + brow + (t << 5), &Bs[buf][tid * 8]);
    };
    auto loadA = [&](int t, u16x8& dst) {
        dst = *reinterpret_cast<const u16x8*>(H + arow + (t << 5));
    };

    __syncthreads();  // sab ready

    u16x8 a0, a1;
    stageB(0, 0); loadA(0, a0);
    stageB(1, 1); loadA(1, a1);

    auto iter = [&](int t, u16x8& ar) {
        const int cur = t % 3;
        if (t + 2 < NT) asm volatile("s_waitcnt vmcnt(2)" ::: "memory");
        else            asm volatile("s_waitcnt vmcnt(0)" ::: "memory");
        {
            const uint* pk = &sab[(t << 5) + scol];
            u16x8 o;
#pragma unroll
            for (int j = 0; j < 8; ++j) {
                uint w = pk[j];
                float a = bf16f((ushort)(w & 0xffffu));
                float b = bf16f((ushort)(w >> 16));
                float y = fmaf(bf16f(ar[j]), a, b);
                o[j] = fbf16(y >= 0.f ? y : 0.2f * y);
            }
            *reinterpret_cast<u16x8*>(&As[cur][tid * 8]) = o;
        }
        asm volatile("s_waitcnt lgkmcnt(0)" ::: "memory");
        __builtin_amdgcn_s_barrier();
        if (t + 2 < NT) { stageB(t + 2, (t + 2) % 3); loadA(t + 2, ar); }
        const ushort* as = As[cur];
        const ushort* bs = Bs[cur];
        bf16x8 af[4], bfv[2];
#pragma unroll
        for (int m = 0; m < 4; ++m)
            af[m] = *reinterpret_cast<const bf16x8*>(&as[(wm0 + m * 16 + lr) * 32 + sw8]);
#pragma unroll
        for (int n = 0; n < 2; ++n)
            bfv[n] = *reinterpret_cast<const bf16x8*>(&bs[(wn0 + n * 16 + lr) * 32 + sw8]);
#pragma unroll
        for (int m = 0; m < 4; ++m)
#pragma unroll
            for (int n = 0; n < 2; ++n)
                acc[m][n] = __builtin_amdgcn_mfma_f32_16x16x32_bf16(af[m], bfv[n], acc[m][n], 0, 0, 0);
    };

    for (int t = 0; t < NT; t += 2) { iter(t, a0); iter(t + 1, a1); }
    __syncthreads();

    const int cr = (lane >> 4) << 2;
    const int cc = lane & 15;
    float sacc[2] = {0.f, 0.f}, qacc[2] = {0.f, 0.f};
#pragma unroll
    for (int m = 0; m < 4; ++m) {
#pragma unroll
        for (int n = 0; n < 2; ++n) {
            int gcol = n0 + wn0 + n * 16 + cc;
            if (EPI == 0 || gcol < Nvalid) {
                float bv = bias[gcol];
                int grow = m0 + wm0 + m * 16 + cr;
#pragma unroll
                for (int j = 0; j < 4; ++j) {
                    float v = acc[m][n][j] + bv;
                    if (EPI == 1) {
                        float sg = 1.f / (1.f + __expf(-v));
                        v = 2.f * __expf(POWEXP * __logf(sg)) + 1e-7f;
                    } else {
                        sacc[n] += v;
                        qacc[n] += v * v;
                    }
                    C[(size_t)(grow + j) * ldc + gcol] = fbf16(v);
                }
            }
        }
    }
    if (EPI == 0) {
#pragma unroll
        for (int n = 0; n < 2; ++n) {
            float s = sacc[n], q = qacc[n];
            s += __shfl_xor(s, 16); q += __shfl_xor(q, 16);
            s += __shfl_xor(s, 32); q += __shfl_xor(q, 32);
            if (lane < 16) { sred[wid][n][lane] = s; qred[wid][n][lane] = q; }
        }
        __syncthreads();
        if (tid < 128) {
            int wn_ = tid >> 5, n_ = (tid >> 4) & 1, cc_ = tid & 15;
            float s = sred[wn_][n_][cc_] + sred[4 + wn_][n_][cc_];
            float q = qred[wn_][n_][cc_] + qred[4 + wn_][n_][cc_];
            int col = n0 + wn_ * 32 + n_ * 16 + cc_;
            psOut[(size_t)by * 512 + col] = s;
            pqOut[(size_t)by * 512 + col] = q;
        }
    }
}

// ---------------- batched input prep: 4 weight transposes + z cast --------
__global__ __launch_bounds__(256) void prep_inputs(
    const float* __restrict__ w0, const float* __restrict__ w1,
    const float* __restrict__ w2, const float* __restrict__ w3,
    const float* __restrict__ z,
    ushort* __restrict__ B0, ushort* __restrict__ B1,
    ushort* __restrict__ B2, ushort* __restrict__ B3,
    ushort* __restrict__ A)
{
    if (blockIdx.z == 4) {
        int bid = blockIdx.y * gridDim.x + blockIdx.x;
        if (bid >= 512) return;
        int idx = (bid * 256 + threadIdx.x) << 3;
        float4 a = *reinterpret_cast<const float4*>(&z[idx]);
        float4 b = *reinterpret_cast<const float4*>(&z[idx + 4]);
        float x[8] = {a.x, a.y, a.z, a.w, b.x, b.y, b.z, b.w};
        u16x8 o;
#pragma unroll
        for (int j = 0; j < 8; ++j) o[j] = fbf16(x[j]);
        *reinterpret_cast<u16x8*>(&A[idx]) = o;
        return;
    }
    const float* w; ushort* Bt; int K, N, GX, GY;
    switch (blockIdx.z) {
        case 0: w = w0; Bt = B0; K = 128; N = 512;  GX = 4;  GY = 16; break;
        case 1: w = w1; Bt = B1; K = 512; N = 512;  GX = 16; GY = 16; break;
        case 2: w = w2; Bt = B2; K = 512; N = 512;  GX = 16; GY = 16; break;
        default:w = w3; Bt = B3; K = 512; N = 1025; GX = 16; GY = 36; break;
    }
    if ((int)blockIdx.x >= GX || (int)blockIdx.y >= GY) return;
    __shared__ float tile[32][33];
    int k0 = blockIdx.x * 32, n0 = blockIdx.y * 32;
    int tx = threadIdx.x & 31, ty = threadIdx.x >> 5;
#pragma unroll
    for (int r = 0; r < 4; ++r) {
        int k = k0 + ty + r * 8;
        int n = n0 + tx;
        tile[ty + r * 8][tx] = (n < N) ? w[(size_t)k * N + n] : 0.f;
    }
    __syncthreads();
#pragma unroll
    for (int r = 0; r < 4; ++r) {
        int n = n0 + ty + r * 8;
        int k = k0 + tx;
        Bt[(size_t)n * K + k] = fbf16(tile[tx][ty + r * 8]);
    }
}

// ---------------- Stockham radix-4 FFT, packed-f32 LDS math ---------------
template<bool INV, int L>
__device__ __forceinline__ void stk_stage(
    const pf2* __restrict__ s, pf2* __restrict__ d, int t)
{
    int k = t & (L - 1);
    pf2 x0 = s[PC(t)];
    pf2 x1 = s[PC(t + 256)];
    pf2 x2 = s[PC(t + 512)];
    pf2 x3 = s[PC(t + 768)];
    if (L > 1) {
        float rev = (float)k * (1.0f / (float)(4 * L));
        float s1 = vsin_rev(rev), c1 = vcos_rev(rev);
        if (!INV) s1 = -s1;
        float c2 = c1 * c1 - s1 * s1, s2 = 2.f * c1 * s1;
        float c3 = c2 * c1 - s2 * s1, s3 = s2 * c1 + c2 * s1;
        x1 = cmulp(x1, c1, s1);
        x2 = cmulp(x2, c2, s2);
        x3 = cmulp(x3, c3, s3);
    }
    pf2 a = x0 + x2, b = x0 - x2, c = x1 + x3, e = x1 - x3;
    pf2 en = INV ? (pf2){-e.y, e.x} : (pf2){e.y, -e.x};
    int db = ((t - k) << 2) + k;
    d[PC(db)]         = a + c;
    d[PC(db + 2 * L)] = a - c;
    d[PC(db + L)]     = b + en;
    d[PC(db + 3 * L)] = b - en;
}

// audio = irfft( rfft(noise_row) * H ), H[k] = (-1)^k*(0.5 fc[k]+0.25 fc[k-1]+0.25 fc[k+1])
// (analytic collapse of rfft(fftshift(irfft(fc)*FW))). 1/1024 folded into H.
__global__ __launch_bounds__(256) void fft_filter_kernel(
    const float* __restrict__ noise, const ushort* __restrict__ fcsb,
    ushort* __restrict__ awb)
{
    __shared__ pf2 X[1152], Y[1152];
    __shared__ ushort Fb[1026];
    const int tid = threadIdx.x;
    const int r = blockIdx.x;

    const pf2* nrow = reinterpret_cast<const pf2*>(noise + ((size_t)r << 11));
    for (int i = tid; i < 1025; i += 256) Fb[i] = fcsb[(size_t)r * 1040 + i];
    {
        // forward stage L=1 fused with global load (pack z[n]=x[2n]+i x[2n+1])
        pf2 x0 = nrow[tid], x1 = nrow[tid + 256], x2 = nrow[tid + 512], x3 = nrow[tid + 768];
        pf2 a = x0 + x2, b = x0 - x2, c = x1 + x3, e = x1 - x3;
        pf2 en = (pf2){e.y, -e.x};
        int db = tid << 2;
        Y[PC(db)]     = a + c;
        Y[PC(db + 1)] = b + en;
        Y[PC(db + 2)] = a - c;
        Y[PC(db + 3)] = b - en;
    }
    __syncthreads();
    stk_stage<false, 4>(Y, X, tid);   __syncthreads();
    stk_stage<false, 16>(X, Y, tid);  __syncthreads();
    stk_stage<false, 64>(Y, X, tid);  __syncthreads();
    stk_stage<false, 256>(X, Y, tid); __syncthreads();
    // forward result in Y (natural order)

    const float INV1024 = 1.0f / 1024.0f;
    auto proc = [&](int k, float c, float s) {
        int k2 = (1024 - k) & 1023;
        pf2 za = Y[PC(k)], zb = Y[PC(k2)];
        float Fer = 0.5f * (za.x + zb.x), Fei = 0.5f * (za.y - zb.y);
        float For = 0.5f * (za.y + zb.y), Foi = 0.5f * (zb.x - za.x);
        float wFr = c * For - s * Foi;
        float wFi = c * Foi + s * For;
        float Xkr = Fer + wFr, Xki = Fei + wFi;
        float Xbr = Fer - wFr, Xbi = wFi - Fei;
        float Hk, Hb;
        {
            float cl = (k == 0) ? bf16f(Fb[1]) : bf16f(Fb[k - 1]);
            float crr = (k == 1024) ? bf16f(Fb[1023]) : bf16f(Fb[k + 1]);
            float h = 0.5f * bf16f(Fb[k]) + 0.25f * (cl + crr);
            Hk = ((k & 1) ? -h : h) * INV1024;
        }
        {
            int kb = 1024 - k;
            float cl = (kb == 0) ? bf16f(Fb[1]) : bf16f(Fb[kb - 1]);
            float crr = (kb == 1024) ? bf16f(Fb[1023]) : bf16f(Fb[kb + 1]);
            float h = 0.5f * bf16f(Fb[kb]) + 0.25f * (cl + crr);
            Hb = ((kb & 1) ? -h : h) * INV1024;
        }
        float Ykr = Hk * Xkr, Yki = Hk * Xki;
        float Ybr = Hb * Xbr, Ybi = Hb * Xbi;
        if (k == 0) {
            X[PC(0)] = (pf2){0.5f * (Ykr + Ybr), 0.5f * (Ykr - Ybr)};
        } else {
            float Ger = 0.5f * (Ykr + Ybr), Gei = 0.5f * (Yki - Ybi);
            float Sgr = 0.5f * (Ykr - Ybr), Sgi = 0.5f * (Yki + Ybi);
            float wpr = c, wpi = -s;
            float Gor = wpr * Sgr - wpi * Sgi;
            float Goi = wpr * Sgi + wpi * Sgr;
            X[PC(k)]  = (pf2){Ger - Goi, Gei + Gor};
            X[PC(k2)] = (pf2){Ger + Goi, Gor - Gei};
        }
    };
    {
        float rev0 = (float)tid * (1.0f / 2048.0f);
        float c0 = vcos_rev(rev0), s0 = -vsin_rev(rev0);
        proc(tid, c0, s0);
        float rev1 = (float)(tid + 256) * (1.0f / 2048.0f);
        float c1 = vcos_rev(rev1), s1 = -vsin_rev(rev1);
        proc(tid + 256, c1, s1);
        if (tid == 0) proc(512, 0.f, -1.f);
    }
    __syncthreads();

    stk_stage<true, 1>(X, Y, tid);  __syncthreads();
    stk_stage<true, 4>(Y, X, tid);  __syncthreads();
    stk_stage<true, 16>(X, Y, tid); __syncthreads();
    stk_stage<true, 64>(Y, X, tid); __syncthreads();

    // inverse final stage (L=256) fused with OLA window + bf16 store
    {
        const int g = r & 511;
        ushort2* awrow = reinterpret_cast<ushort2*>(awb + ((size_t)r << 11));
        int t = tid;
        pf2 x0 = X[PC(t)], x1 = X[PC(t + 256)], x2 = X[PC(t + 512)], x3 = X[PC(t + 768)];
        float rev = (float)t * (1.0f / 1024.0f);
        float s1 = vsin_rev(rev), c1 = vcos_rev(rev);
        float c2 = c1 * c1 - s1 * s1, s2 = 2.f * c1 * s1;
        float c3 = c2 * c1 - s2 * s1, s3 = s2 * c1 + c2 * s1;
        x1 = cmulp(x1, c1, s1);
        x2 = cmulp(x2, c2, s2);
        x3 = cmulp(x3, c3, s3);
        pf2 a = x0 + x2, b = x0 - x2, c = x1 + x3, e = x1 - x3;
        pf2 en = (pf2){-e.y, e.x};  // inverse
        pf2 o[4];
        o[0] = a + c;
        o[1] = b + en;
        o[2] = a - c;
        o[3] = b - en;
        float cq[4] = {c1, -s1, -c1, s1};
        float sq[4] = {s1, c1, -s1, -c1};
        const float COSD = 0.99999529380958f;   // cos(pi/1024)
        const float SIND = 0.00306795676296f;   // sin(pi/1024)
#pragma unroll
        for (int q = 0; q < 4; ++q) {
            int n = t + 256 * q;
            float w0, w1;
            bool edge = (g == 0 && q < 2) || (g == 511 && q >= 2);
            if (edge) { w0 = 1.f; w1 = 1.f; }
            else {
                w0 = 0.5f - 0.5f * cq[q];
                w1 = 0.5f - 0.5f * (cq[q] * COSD - sq[q] * SIND);
            }
            ushort2 ov; ov.x = fbf16(o[q].x * w0); ov.y = fbf16(o[q].y * w1);
            awrow[n] = ov;
        }
    }
}

// ---------------- fused OLA gather + 65-tap conv + softsign ---------------
__global__ __launch_bounds__(256) void ola_ppconv_kernel(
    const ushort* __restrict__ awb, const float* __restrict__ ppw,
    const float* __restrict__ ppb, float* __restrict__ out)
{
    __shared__ float tile[320];
    __shared__ float Ksh[65];
    int t0 = blockIdx.x * 256;
    int b = blockIdx.y;
    const ushort* awbase = awb + ((size_t)(b * 512) << 11);
    for (int i = threadIdx.x; i < 320; i += 256) {
        int tt = t0 - 32 + i;
        float v = 0.f;
        if (tt >= 1536 && tt < 262144) {
            int glo = (tt - 1536) >> 9;
            const ushort* p = awbase + ((size_t)glo << 11) + (tt - (glo << 9));
            float s = bf16f(p[0]) + bf16f(p[1536]) + bf16f(p[3072]) + bf16f(p[4608]);
            v = s * 0.25f;
        } else if (tt >= 0 && tt < TARLEN) {
            int ghi = min(511, tt >> 9);
            int glo = max(0, (tt - 1536) >> 9);
            float s = 0.f;
            for (int g = glo; g <= ghi; ++g) {
                int n = tt - (g << 9);
                s += bf16f(awbase[((size_t)g << 11) + n]);
            }
            v = s / (float)(ghi - glo + 1);
        }
        tile[i] = v;
    }
    if (threadIdx.x < 65) {
        float k = 0.f;
#pragma unroll
        for (int c = 0; c < 5; ++c) k += ppw[c * 65 + threadIdx.x];
        Ksh[threadIdx.x] = k;
    }
    __syncthreads();
    float y = ppb[0];
#pragma unroll
    for (int j = 0; j < 65; ++j) y = fmaf(Ksh[j], tile[threadIdx.x + j], y);
    int t = t0 + threadIdx.x;
    out[(size_t)b * TARLEN + t] = y / (1.f + fabsf(y));
}

// ---------------- launch --------------------------------------------------
extern "C" void kernel_launch(void* const* d_in, const int* in_sizes, int n_in,
                              void* d_out, int out_size, void* d_ws, size_t ws_size,
                              hipStream_t stream) {
    const float* z    = (const float*)d_in[0];
    const float* w0   = (const float*)d_in[1];
    const float* b0   = (const float*)d_in[2];
    const float* g0   = (const float*)d_in[3];
    const float* be0  = (const float*)d_in[4];
    const float* w1   = (const float*)d_in[5];
    const float* b1   = (const float*)d_in[6];
    const float* g1   = (const float*)d_in[7];
    const float* be1  = (const float*)d_in[8];
    const float* w2   = (const float*)d_in[9];
    const float* b2   = (const float*)d_in[10];
    const float* g2   = (const float*)d_in[11];
    const float* be2  = (const float*)d_in[12];
    const float* w3   = (const float*)d_in[13];
    const float* b3   = (const float*)d_in[14];
    const float* ppw  = (const float*)d_in[15];
    const float* ppb  = (const float*)d_in[16];
    const float* noise= (const float*)d_in[17];
    float* out = (float*)d_out;
    float* ws = (float*)d_ws;

    // workspace (float offsets)
    ushort* h0b = (ushort*)ws;                    // 8192*512 bf16
    ushort* h1b = (ushort*)(ws + 2097152);        // 8192*512 bf16
    float* ps0  = ws + 4194304;                   // 64*512
    float* pq0  = ps0 + 32768;
    float* ps1  = pq0 + 32768;
    float* pq1  = ps1 + 32768;
    float* base = pq1 + 32768;
    ushort* Bt0 = (ushort*)base;                  // 512*128 bf16
    ushort* Bt1 = (ushort*)(base + 32768);        // 512*512 bf16
    ushort* Bt2 = (ushort*)(base + 163840);       // 512*512 bf16
    ushort* Bt3 = (ushort*)(base + 294912);       // 1152*512 bf16
    ushort* fcsb= (ushort*)(base + 589824);       // 8192*1040 bf16
    ushort* awb = (ushort*)(base + 4849664);      // 8192*2048 bf16
    ushort* A   = (ushort*)(base + 13238272);     // 8192*128 bf16 (z cast)
    ushort* h2b = h0b;  // h0 dead after gemm1 consumed it

    dim3 blk(256);
    dim3 gblk(512);
    // input prep (4 weight transposes + z cast) in one launch
    prep_inputs<<<dim3(16, 36, 5), blk, 0, stream>>>(
        w0, w1, w2, w3, z, Bt0, Bt1, Bt2, Bt3, A);
    // layer 0: h0 = z @ w0 + b0 (+ stats -> S0); K=128
    gemm8<<<dim3(4, 64), gblk, 0, stream>>>(A, Bt0, b0, h0b, 128, ps0, pq0);
    // layer 1: fused BN(S0)+lrelu on A, gemm, stats -> S1
    gemm8n<0><<<dim3(4, 64), gblk, 0, stream>>>(
        h0b, Bt1, b1, ps0, pq0, g0, be0, h1b, 512, 512, 512, ps1, pq1);
    // layer 2: fused BN(S1), stats -> S0
    gemm8n<0><<<dim3(4, 64), gblk, 0, stream>>>(
        h1b, Bt2, b2, ps1, pq1, g1, be1, h2b, 512, 512, 512, ps0, pq0);
    // layer 3: fused BN(S0), mod_sigmoid -> fcsb [8192][1040], 1025 valid
    gemm8n<1><<<dim3(9, 64), gblk, 0, stream>>>(
        h2b, Bt3, b3, ps0, pq0, g2, be2, fcsb, 512, 1025, 1040, nullptr, nullptr);
    // spectral filtering + window (fused), bf16 in/out
    fft_filter_kernel<<<dim3(8192), blk, 0, stream>>>(noise, fcsb, awb);
    // fused OLA + post conv + softsign
    ola_ppconv_kernel<<<dim3(1030, 16), blk, 0, stream>>>(awb, ppw, ppb, out);
    (void)in_sizes; (void)n_in; (void)out_size; (void)ws_size;
}